// Round 2
// baseline (1578.826 us; speedup 1.0000x reference)
//
#include <hip/hip_runtime.h>

static __device__ __forceinline__ float silu_f(float x){
  return x / (1.f + __expf(-x));
}

constexpr int cB = 128, cNP = 64, cP = 128, cDIM = 512, cDIN = 1024;
constexpr int cDST = 16, cDTR = 32, cNCLS = 32;
constexpr int cBL = cB * cNP;      // 8192 (b,l) rows
constexpr int cXZ = 2 * cDIN;      // 2048

// ---------------------------------------------------------------------------
// K1: segment projection + per-pathway LayerNorm
// x0[b,n,d] = LN_d( sum_p series[b, n*128+p] * seg_w[n,p,d] + seg_b[n,d] )
// grid: n*cB + b (consecutive blocks share n -> L2 reuse of seg_w slice)
// ---------------------------------------------------------------------------
__global__ __launch_bounds__(128) void k_seg_ln(
    const float* __restrict__ series, const float* __restrict__ seg_w,
    const float* __restrict__ seg_b,  const float* __restrict__ ln_g,
    const float* __restrict__ ln_b,   float* __restrict__ x0)
{
  const int bid = blockIdx.x;
  const int n = bid / cB;
  const int b = bid % cB;
  const int tid = threadIdx.x;       // 128 threads

  __shared__ float s[cP];
  __shared__ float red[cP];

  s[tid] = series[(size_t)b * (cNP * cP) + n * cP + tid];
  __syncthreads();

  const float4* wv = (const float4*)(seg_w + (size_t)n * cP * cDIM);
  float a0 = 0.f, a1 = 0.f, a2 = 0.f, a3 = 0.f;
#pragma unroll 4
  for (int p = 0; p < cP; ++p) {
    float sp = s[p];
    float4 w = wv[p * (cDIM / 4) + tid];
    a0 += sp * w.x; a1 += sp * w.y;
    a2 += sp * w.z; a3 += sp * w.w;
  }
  const int d0 = tid * 4;
  a0 += seg_b[n * cDIM + d0 + 0];
  a1 += seg_b[n * cDIM + d0 + 1];
  a2 += seg_b[n * cDIM + d0 + 2];
  a3 += seg_b[n * cDIM + d0 + 3];

  // mean
  red[tid] = a0 + a1 + a2 + a3;
  __syncthreads();
  for (int s2 = 64; s2 > 0; s2 >>= 1) {
    if (tid < s2) red[tid] += red[tid + s2];
    __syncthreads();
  }
  const float mu = red[0] * (1.f / cDIM);
  __syncthreads();
  // var (E[x^2] - mu^2)
  red[tid] = a0*a0 + a1*a1 + a2*a2 + a3*a3;
  __syncthreads();
  for (int s2 = 64; s2 > 0; s2 >>= 1) {
    if (tid < s2) red[tid] += red[tid + s2];
    __syncthreads();
  }
  const float var = red[0] * (1.f / cDIM) - mu * mu;
  const float rstd = rsqrtf(var + 1e-5f);

  float* orow = x0 + (size_t)(b * cNP + n) * cDIM + d0;
  orow[0] = (a0 - mu) * rstd * ln_g[n*cDIM + d0+0] + ln_b[n*cDIM + d0+0];
  orow[1] = (a1 - mu) * rstd * ln_g[n*cDIM + d0+1] + ln_b[n*cDIM + d0+1];
  orow[2] = (a2 - mu) * rstd * ln_g[n*cDIM + d0+2] + ln_b[n*cDIM + d0+2];
  orow[3] = (a3 - mu) * rstd * ln_g[n*cDIM + d0+3] + ln_b[n*cDIM + d0+3];
}

// ---------------------------------------------------------------------------
// Generic tiled GEMM: C[M,N] = A[M,K] (lda) * W[N,K]^T   (all fp32)
// BK=16. 256 threads. thread tile TM x TN.
// ---------------------------------------------------------------------------
template<int BM, int BN, int TM, int TN>
__global__ __launch_bounds__(256) void k_gemm(
    const float* __restrict__ A, int lda,
    const float* __restrict__ W,
    float* __restrict__ C, int ldc,
    int M, int N, int K)
{
  constexpr int BK = 16;
  __shared__ __align__(16) float As[BK][BM + 4];
  __shared__ __align__(16) float Ws[BK][BN + 4];

  const int tid = threadIdx.x;
  const int bm = blockIdx.x * BM;
  const int bn = blockIdx.y * BN;
  const int tx = tid % (BN / TN);
  const int ty = tid / (BN / TN);

  float acc[TM][TN];
#pragma unroll
  for (int i = 0; i < TM; ++i)
#pragma unroll
    for (int j = 0; j < TN; ++j) acc[i][j] = 0.f;

  for (int k0 = 0; k0 < K; k0 += BK) {
#pragma unroll
    for (int i = tid * 4; i < BM * BK; i += 1024) {
      int m = i / BK, kk = i % BK;
      float4 v = *(const float4*)(A + (size_t)(bm + m) * lda + (k0 + kk));
      As[kk + 0][m] = v.x; As[kk + 1][m] = v.y;
      As[kk + 2][m] = v.z; As[kk + 3][m] = v.w;
    }
#pragma unroll
    for (int i = tid * 4; i < BN * BK; i += 1024) {
      int nn = i / BK, kk = i % BK;
      float4 w = *(const float4*)(W + (size_t)(bn + nn) * K + (k0 + kk));
      Ws[kk + 0][nn] = w.x; Ws[kk + 1][nn] = w.y;
      Ws[kk + 2][nn] = w.z; Ws[kk + 3][nn] = w.w;
    }
    __syncthreads();
#pragma unroll
    for (int kk = 0; kk < BK; ++kk) {
      float a[TM], bb[TN];
#pragma unroll
      for (int i = 0; i < TM; i += 4) {
        float4 v = *(const float4*)&As[kk][ty * TM + i];
        a[i] = v.x; a[i+1] = v.y; a[i+2] = v.z; a[i+3] = v.w;
      }
#pragma unroll
      for (int j = 0; j < TN; j += 4) {
        float4 v = *(const float4*)&Ws[kk][tx * TN + j];
        bb[j] = v.x; bb[j+1] = v.y; bb[j+2] = v.z; bb[j+3] = v.w;
      }
#pragma unroll
      for (int i = 0; i < TM; ++i)
#pragma unroll
        for (int j = 0; j < TN; ++j) acc[i][j] += a[i] * bb[j];
    }
    __syncthreads();
  }

#pragma unroll
  for (int i = 0; i < TM; ++i) {
    float* crow = C + (size_t)(bm + ty * TM + i) * ldc + bn + tx * TN;
#pragma unroll
    for (int j = 0; j < TN; j += 4) {
      float4 v = make_float4(acc[i][j], acc[i][j+1], acc[i][j+2], acc[i][j+3]);
      *(float4*)(crow + j) = v;
    }
  }
}

// ---------------------------------------------------------------------------
// K3: depthwise causal conv (DCONV=4) + SiLU.  u lives in xz[:, 0:1024].
// one thread per (b,d), iterates l = 0..63
// ---------------------------------------------------------------------------
__global__ __launch_bounds__(256) void k_conv(
    const float* __restrict__ xz, const float* __restrict__ cw,
    const float* __restrict__ cb, float* __restrict__ uc)
{
  const int t = blockIdx.x * 256 + threadIdx.x;   // 0..131071
  const int b = t >> 10;
  const int d = t & 1023;
  const float w0 = cw[d * 4 + 0], w1 = cw[d * 4 + 1];
  const float w2 = cw[d * 4 + 2], w3 = cw[d * 4 + 3];
  const float bias = cb[d];
  float u0 = 0.f, u1 = 0.f, u2 = 0.f;
  const float* src = xz + (size_t)b * cNP * cXZ + d;
  float* dst = uc + (size_t)b * cNP * cDIN + d;
  for (int l = 0; l < cNP; ++l) {
    float u3 = src[(size_t)l * cXZ];
    float v = w0 * u0 + w1 * u1 + w2 * u2 + w3 * u3 + bias;
    dst[(size_t)l * cDIN] = silu_f(v);
    u0 = u1; u1 = u2; u2 = u3;
  }
}

// ---------------------------------------------------------------------------
// K5: dt_proj + softplus -> delta written into xz u-half (u is dead now)
// one block per (b,l) row; thread computes 4 consecutive d
// ---------------------------------------------------------------------------
__global__ __launch_bounds__(256) void k_dtproj(
    const float* __restrict__ xdbl, const float* __restrict__ wdt,
    const float* __restrict__ bdt, float* __restrict__ xz)
{
  const int row = blockIdx.x;
  const int tid = threadIdx.x;
  __shared__ float sdt[cDTR];
  if (tid < cDTR) sdt[tid] = xdbl[(size_t)row * 64 + tid];
  __syncthreads();
  const int d0 = tid * 4;
  float* drow = xz + (size_t)row * cXZ;
#pragma unroll
  for (int j = 0; j < 4; ++j) {
    const float4* wp = (const float4*)(wdt + (size_t)(d0 + j) * cDTR);
    float a = 0.f;
#pragma unroll
    for (int r = 0; r < cDTR; r += 4) {
      float4 w = wp[r >> 2];
      a += sdt[r+0]*w.x + sdt[r+1]*w.y + sdt[r+2]*w.z + sdt[r+3]*w.w;
    }
    float v = a + bdt[d0 + j];
    // softplus, overflow-safe
    float sp = fmaxf(v, 0.f) + log1pf(__expf(-fabsf(v)));
    drow[d0 + j] = sp;
  }
}

// ---------------------------------------------------------------------------
// K6: selective scan + (y + uc*D) * silu(z); y overwrites delta slot in xz.
// grid (b, half): block covers 512 channels; thread handles 2 channels,
// h[16] per channel in registers; B_t/C_t staged in LDS per step.
// ---------------------------------------------------------------------------
__global__ __launch_bounds__(256) void k_scan(
    float* __restrict__ xz, const float* __restrict__ uc,
    const float* __restrict__ xdbl, const float* __restrict__ A_log,
    const float* __restrict__ Dp)
{
  const int b = blockIdx.x;
  const int half = blockIdx.y;
  const int tid = threadIdx.x;
  const int d0 = half * 512 + tid;
  const int d1 = d0 + 256;

  float A0[cDST], A1[cDST];
  {
    const float4* ap = (const float4*)(A_log + (size_t)d0 * cDST);
#pragma unroll
    for (int q = 0; q < 4; ++q) {
      float4 w = ap[q];
      A0[q*4+0] = -__expf(w.x); A0[q*4+1] = -__expf(w.y);
      A0[q*4+2] = -__expf(w.z); A0[q*4+3] = -__expf(w.w);
    }
    const float4* ap1 = (const float4*)(A_log + (size_t)d1 * cDST);
#pragma unroll
    for (int q = 0; q < 4; ++q) {
      float4 w = ap1[q];
      A1[q*4+0] = -__expf(w.x); A1[q*4+1] = -__expf(w.y);
      A1[q*4+2] = -__expf(w.z); A1[q*4+3] = -__expf(w.w);
    }
  }
  float h0[cDST], h1[cDST];
#pragma unroll
  for (int n = 0; n < cDST; ++n) { h0[n] = 0.f; h1[n] = 0.f; }
  const float D0 = Dp[d0], D1 = Dp[d1];

  __shared__ float sB[cDST], sC[cDST];

  for (int l = 0; l < cNP; ++l) {
    const size_t row = (size_t)b * cNP + l;
    if (tid < 32) {
      float v = xdbl[row * 64 + 32 + tid];
      if (tid < 16) sB[tid] = v; else sC[tid - 16] = v;
    }
    __syncthreads();

    const float dv0 = xz[row * cXZ + d0];
    const float dv1 = xz[row * cXZ + d1];
    const float uv0 = uc[row * cDIN + d0];
    const float uv1 = uc[row * cDIN + d1];
    const float zv0 = xz[row * cXZ + cDIN + d0];
    const float zv1 = xz[row * cXZ + cDIN + d1];
    const float du0 = dv0 * uv0;
    const float du1 = dv1 * uv1;
    float y0 = 0.f, y1 = 0.f;
#pragma unroll
    for (int n = 0; n < cDST; ++n) {
      float dA0 = __expf(dv0 * A0[n]);
      h0[n] = dA0 * h0[n] + du0 * sB[n];
      y0 += h0[n] * sC[n];
      float dA1 = __expf(dv1 * A1[n]);
      h1[n] = dA1 * h1[n] + du1 * sB[n];
      y1 += h1[n] * sC[n];
    }
    y0 = (y0 + uv0 * D0) * silu_f(zv0);
    y1 = (y1 + uv1 * D1) * silu_f(zv1);
    xz[row * cXZ + d0] = y0;
    xz[row * cXZ + d1] = y1;
    __syncthreads();
  }
}

// ---------------------------------------------------------------------------
// K7: head LayerNorm stats per batch row (32768 elems)
// ---------------------------------------------------------------------------
__global__ __launch_bounds__(256) void k_hstats(
    const float* __restrict__ x, float* __restrict__ stats)
{
  const int b = blockIdx.x;
  const int tid = threadIdx.x;
  const float4* r4 = (const float4*)(x + (size_t)b * (cNP * cDIM));
  float s = 0.f, s2 = 0.f;
  for (int i = tid; i < (cNP * cDIM) / 4; i += 256) {
    float4 v = r4[i];
    s  += v.x + v.y + v.z + v.w;
    s2 += v.x*v.x + v.y*v.y + v.z*v.z + v.w*v.w;
  }
  __shared__ float red[256];
  red[tid] = s; __syncthreads();
  for (int st = 128; st > 0; st >>= 1) {
    if (tid < st) red[tid] += red[tid + st];
    __syncthreads();
  }
  const float mu = red[0] * (1.f / (cNP * cDIM));
  __syncthreads();
  red[tid] = s2; __syncthreads();
  for (int st = 128; st > 0; st >>= 1) {
    if (tid < st) red[tid] += red[tid + st];
    __syncthreads();
  }
  if (tid == 0) {
    float var = red[0] * (1.f / (cNP * cDIM)) - mu * mu;
    stats[2 * b]     = mu;
    stats[2 * b + 1] = rsqrtf(var + 1e-5f);
  }
}

// ---------------------------------------------------------------------------
// K8: head LN apply + classifier GEMV, fp32 output
// ---------------------------------------------------------------------------
__global__ __launch_bounds__(256) void k_head(
    const float* __restrict__ x, const float* __restrict__ stats,
    const float* __restrict__ hg, const float* __restrict__ hb,
    const float* __restrict__ hw, const float* __restrict__ hbias,
    float* __restrict__ out)
{
  const int b = blockIdx.x;
  const int tid = threadIdx.x;
  const float mu = stats[2 * b], rstd = stats[2 * b + 1];
  const float* row = x + (size_t)b * (cNP * cDIM);

  float acc[cNCLS];
#pragma unroll
  for (int c = 0; c < cNCLS; ++c) acc[c] = 0.f;

  for (int i0 = tid * 2; i0 < cNP * cDIM; i0 += 512) {
    float xn0 = (row[i0]     - mu) * rstd * hg[i0]     + hb[i0];
    float xn1 = (row[i0 + 1] - mu) * rstd * hg[i0 + 1] + hb[i0 + 1];
#pragma unroll
    for (int c = 0; c < cNCLS; ++c) {
      float2 w2 = *(const float2*)(hw + (size_t)c * (cNP * cDIM) + i0);
      acc[c] += xn0 * w2.x + xn1 * w2.y;
    }
  }

  __shared__ float sred[cNCLS * 257];
#pragma unroll
  for (int c = 0; c < cNCLS; ++c) sred[c * 257 + tid] = acc[c];
  __syncthreads();
  if (tid < cNCLS) {
    float s = 0.f;
    for (int i = 0; i < 256; ++i) s += sred[tid * 257 + i];
    out[b * cNCLS + tid] = s + hbias[tid];
  }
}

// ---------------------------------------------------------------------------
extern "C" void kernel_launch(void* const* d_in, const int* in_sizes, int n_in,
                              void* d_out, int out_size, void* d_ws, size_t ws_size,
                              hipStream_t stream)
{
  (void)in_sizes; (void)n_in; (void)out_size; (void)ws_size;

  const float* series    = (const float*)d_in[0];
  const float* seg_w     = (const float*)d_in[1];
  const float* seg_b     = (const float*)d_in[2];
  const float* ln_g      = (const float*)d_in[3];
  const float* ln_b      = (const float*)d_in[4];
  const float* in_proj_w = (const float*)d_in[5];
  const float* conv_w    = (const float*)d_in[6];
  const float* conv_b    = (const float*)d_in[7];
  const float* x_proj_w  = (const float*)d_in[8];
  const float* dt_proj_w = (const float*)d_in[9];
  const float* dt_proj_b = (const float*)d_in[10];
  const float* A_log     = (const float*)d_in[11];
  const float* Dp        = (const float*)d_in[12];
  const float* out_proj_w= (const float*)d_in[13];
  const float* head_ln_g = (const float*)d_in[14];
  const float* head_ln_b = (const float*)d_in[15];
  const float* head_w    = (const float*)d_in[16];
  const float* head_b    = (const float*)d_in[17];

  float* ws   = (float*)d_ws;
  float* x0   = ws;                              // [8192, 512]
  float* xz   = x0 + (size_t)cBL * cDIM;         // [8192, 2048] u/delta/y | z
  float* ucb  = xz + (size_t)cBL * cXZ;          // [8192, 1024]
  float* xdbl = ucb + (size_t)cBL * cDIN;        // [8192, 64]
  float* stats= xdbl + (size_t)cBL * 64;         // [128, 2]

  k_seg_ln<<<cNP * cB, 128, 0, stream>>>(series, seg_w, seg_b, ln_g, ln_b, x0);

  for (int dep = 0; dep < 2; ++dep) {
    const float* wi  = in_proj_w  + (size_t)dep * (2 * cDIN) * cDIM;
    const float* cwd = conv_w     + (size_t)dep * cDIN * 4;
    const float* cbd = conv_b     + (size_t)dep * cDIN;
    const float* wx  = x_proj_w   + (size_t)dep * 64 * cDIN;
    const float* wdt = dt_proj_w  + (size_t)dep * cDIN * cDTR;
    const float* bdt = dt_proj_b  + (size_t)dep * cDIN;
    const float* Ald = A_log      + (size_t)dep * cDIN * cDST;
    const float* Dd  = Dp         + (size_t)dep * cDIN;
    const float* wo  = out_proj_w + (size_t)dep * cDIM * cDIN;

    // in_proj: xz[8192,2048] = x0[8192,512] @ wi[2048,512]^T
    k_gemm<128,128,8,8><<<dim3(cBL/128, (2*cDIN)/128), 256, 0, stream>>>(
        x0, cDIM, wi, xz, cXZ, cBL, 2*cDIN, cDIM);
    // depthwise conv + silu -> uc
    k_conv<<<(cB * cDIN) / 256, 256, 0, stream>>>(xz, cwd, cbd, ucb);
    // x_proj: xdbl[8192,64] = uc[8192,1024] @ wx[64,1024]^T
    k_gemm<64,64,4,4><<<dim3(cBL/64, 1), 256, 0, stream>>>(
        ucb, cDIN, wx, xdbl, 64, cBL, 64, cDIN);
    // dt_proj + softplus -> delta (into xz u-half)
    k_dtproj<<<cBL, 256, 0, stream>>>(xdbl, wdt, bdt, xz);
    // scan + gate -> y (into xz u-half)
    k_scan<<<dim3(cB, 2), 256, 0, stream>>>(xz, ucb, xdbl, Ald, Dd);
    // out_proj: x0[8192,512] = y[8192(,stride 2048),1024] @ wo[512,1024]^T
    k_gemm<128,128,8,8><<<dim3(cBL/128, cDIM/128), 256, 0, stream>>>(
        xz, cXZ, wo, x0, cDIM, cBL, cDIM, cDIN);
  }

  k_hstats<<<cB, 256, 0, stream>>>(x0, stats);
  k_head<<<cB, 256, 0, stream>>>(x0, stats, head_ln_g, head_ln_b,
                                 head_w, head_b, (float*)d_out);
}

// Round 3
// 938.506 us; speedup vs baseline: 1.6823x; 1.6823x over previous
//
#include <hip/hip_runtime.h>

typedef unsigned short u16;
typedef unsigned int   u32;
typedef __attribute__((ext_vector_type(8))) short short8;
typedef __attribute__((ext_vector_type(4))) float floatx4;

static __device__ __forceinline__ float silu_f(float x){
  return x / (1.f + __expf(-x));
}
static __device__ __forceinline__ u16 f2bfu(float f){
  union { float f; u32 i; } v; v.f = f;
  u32 x = v.i;
  u32 r = (x + 0x7fffu + ((x >> 16) & 1u)) >> 16;   // round-nearest-even
  return (u16)r;
}

constexpr int cB = 128, cNP = 64, cP = 128, cDIM = 512, cDIN = 1024;
constexpr int cDST = 16, cDTR = 32, cNCLS = 32;
constexpr int cBL = cB * cNP;      // 8192 (b,l) rows
constexpr int cXZ = 2 * cDIN;      // 2048

// ---------------------------------------------------------------------------
// K0: fp32 -> bf16 weight conversion (grid-stride over n/4 float4 chunks)
// ---------------------------------------------------------------------------
__global__ __launch_bounds__(256) void k_f2bf(
    const float* __restrict__ src, u16* __restrict__ dst)
{
  const int i = (blockIdx.x * 256 + threadIdx.x) * 4;
  float4 v = *(const float4*)(src + i);
  ushort4 o;
  o.x = f2bfu(v.x); o.y = f2bfu(v.y); o.z = f2bfu(v.z); o.w = f2bfu(v.w);
  *(ushort4*)(dst + i) = o;
}

// ---------------------------------------------------------------------------
// K1: segment projection + per-pathway LayerNorm -> bf16 x0b
// ---------------------------------------------------------------------------
__global__ __launch_bounds__(128) void k_seg_ln(
    const float* __restrict__ series, const float* __restrict__ seg_w,
    const float* __restrict__ seg_b,  const float* __restrict__ ln_g,
    const float* __restrict__ ln_b,   u16* __restrict__ x0b)
{
  const int bid = blockIdx.x;
  const int n = bid / cB;
  const int b = bid % cB;
  const int tid = threadIdx.x;       // 128 threads

  __shared__ float s[cP];
  __shared__ float red[cP];

  s[tid] = series[(size_t)b * (cNP * cP) + n * cP + tid];
  __syncthreads();

  const float4* wv = (const float4*)(seg_w + (size_t)n * cP * cDIM);
  float a0 = 0.f, a1 = 0.f, a2 = 0.f, a3 = 0.f;
#pragma unroll 4
  for (int p = 0; p < cP; ++p) {
    float sp = s[p];
    float4 w = wv[p * (cDIM / 4) + tid];
    a0 += sp * w.x; a1 += sp * w.y;
    a2 += sp * w.z; a3 += sp * w.w;
  }
  const int d0 = tid * 4;
  a0 += seg_b[n * cDIM + d0 + 0];
  a1 += seg_b[n * cDIM + d0 + 1];
  a2 += seg_b[n * cDIM + d0 + 2];
  a3 += seg_b[n * cDIM + d0 + 3];

  red[tid] = a0 + a1 + a2 + a3;
  __syncthreads();
  for (int s2 = 64; s2 > 0; s2 >>= 1) {
    if (tid < s2) red[tid] += red[tid + s2];
    __syncthreads();
  }
  const float mu = red[0] * (1.f / cDIM);
  __syncthreads();
  red[tid] = a0*a0 + a1*a1 + a2*a2 + a3*a3;
  __syncthreads();
  for (int s2 = 64; s2 > 0; s2 >>= 1) {
    if (tid < s2) red[tid] += red[tid + s2];
    __syncthreads();
  }
  const float var = red[0] * (1.f / cDIM) - mu * mu;
  const float rstd = rsqrtf(var + 1e-5f);

  u16* orow = x0b + (size_t)(b * cNP + n) * cDIM + d0;
  ushort4 o;
  o.x = f2bfu((a0 - mu) * rstd * ln_g[n*cDIM + d0+0] + ln_b[n*cDIM + d0+0]);
  o.y = f2bfu((a1 - mu) * rstd * ln_g[n*cDIM + d0+1] + ln_b[n*cDIM + d0+1]);
  o.z = f2bfu((a2 - mu) * rstd * ln_g[n*cDIM + d0+2] + ln_b[n*cDIM + d0+2]);
  o.w = f2bfu((a3 - mu) * rstd * ln_g[n*cDIM + d0+3] + ln_b[n*cDIM + d0+3]);
  *(ushort4*)orow = o;
}

// ---------------------------------------------------------------------------
// K2: bf16 MFMA GEMM: C[M,N] = A[M,K] * W[N,K]^T. 128x128 tile, BK=32,
// 256 thr = 4 waves (2x2 of 64x64). C fp32 (ldc); optional bf16 copy Cb.
// Fragment layouts per m89/m120: A/B lane holds [row=lane&15][k=quad*8+j];
// C/D: col=lane&15, row=quad*4+reg.
// ---------------------------------------------------------------------------
__global__ __launch_bounds__(256) void k_gemm_mfma(
    const u16* __restrict__ A, int lda,
    const u16* __restrict__ W,
    float* __restrict__ C, int ldc,
    u16* __restrict__ Cb, int ldcb,
    int K)
{
  constexpr int LDT = 40;   // 32 + 8 pad (u16) -> 80B row stride, conflict-free
  __shared__ __align__(16) u16 As[128 * LDT];
  __shared__ __align__(16) u16 Ws[128 * LDT];

  const int tid = threadIdx.x;
  const int bm = blockIdx.x * 128;
  const int bn = blockIdx.y * 128;
  const int wave = tid >> 6;
  const int lane = tid & 63;
  const int wm = (wave & 1) * 64;
  const int wn = (wave >> 1) * 64;
  const int l15 = lane & 15;
  const int quad = lane >> 4;

  floatx4 acc[4][4];
#pragma unroll
  for (int i = 0; i < 4; ++i)
#pragma unroll
    for (int j = 0; j < 4; ++j) acc[i][j] = (floatx4){0.f, 0.f, 0.f, 0.f};

  const int r0 = tid >> 2;          // 0..63
  const int c0 = (tid & 3) * 8;     // 0,8,16,24

  for (int k0 = 0; k0 < K; k0 += 32) {
    // stage A[128][32] and W[128][32] bf16 tiles (16B per lane x4)
    short8 va0 = *(const short8*)(A + (size_t)(bm + r0)      * lda + k0 + c0);
    short8 va1 = *(const short8*)(A + (size_t)(bm + r0 + 64) * lda + k0 + c0);
    short8 vw0 = *(const short8*)(W + (size_t)(bn + r0)      * K   + k0 + c0);
    short8 vw1 = *(const short8*)(W + (size_t)(bn + r0 + 64) * K   + k0 + c0);
    *(short8*)&As[r0 * LDT + c0] = va0;
    *(short8*)&As[(r0 + 64) * LDT + c0] = va1;
    *(short8*)&Ws[r0 * LDT + c0] = vw0;
    *(short8*)&Ws[(r0 + 64) * LDT + c0] = vw1;
    __syncthreads();

    short8 af[4], bf[4];
#pragma unroll
    for (int i = 0; i < 4; ++i)
      af[i] = *(const short8*)&As[(wm + i * 16 + l15) * LDT + quad * 8];
#pragma unroll
    for (int j = 0; j < 4; ++j)
      bf[j] = *(const short8*)&Ws[(wn + j * 16 + l15) * LDT + quad * 8];
#pragma unroll
    for (int i = 0; i < 4; ++i)
#pragma unroll
      for (int j = 0; j < 4; ++j)
        acc[i][j] = __builtin_amdgcn_mfma_f32_16x16x32_bf16(
            af[i], bf[j], acc[i][j], 0, 0, 0);
    __syncthreads();
  }

#pragma unroll
  for (int i = 0; i < 4; ++i) {
    const int m0 = bm + wm + i * 16 + quad * 4;
#pragma unroll
    for (int j = 0; j < 4; ++j) {
      const int n = bn + wn + j * 16 + l15;
#pragma unroll
      for (int r = 0; r < 4; ++r) {
        C[(size_t)(m0 + r) * ldc + n] = acc[i][j][r];
      }
      if (Cb) {
#pragma unroll
        for (int r = 0; r < 4; ++r)
          Cb[(size_t)(m0 + r) * ldcb + n] = f2bfu(acc[i][j][r]);
      }
    }
  }
}

// ---------------------------------------------------------------------------
// fp32 tiled GEMM (kept for x_proj): C[M,N] = A[M,K] * W[N,K]^T
// ---------------------------------------------------------------------------
template<int BM, int BN, int TM, int TN>
__global__ __launch_bounds__(256) void k_gemm(
    const float* __restrict__ A, int lda,
    const float* __restrict__ W,
    float* __restrict__ C, int ldc,
    int M, int N, int K)
{
  constexpr int BK = 16;
  __shared__ __align__(16) float As[BK][BM + 4];
  __shared__ __align__(16) float Ws[BK][BN + 4];

  const int tid = threadIdx.x;
  const int bm = blockIdx.x * BM;
  const int bn = blockIdx.y * BN;
  const int tx = tid % (BN / TN);
  const int ty = tid / (BN / TN);

  float acc[TM][TN];
#pragma unroll
  for (int i = 0; i < TM; ++i)
#pragma unroll
    for (int j = 0; j < TN; ++j) acc[i][j] = 0.f;

  for (int k0 = 0; k0 < K; k0 += BK) {
#pragma unroll
    for (int i = tid * 4; i < BM * BK; i += 1024) {
      int m = i / BK, kk = i % BK;
      float4 v = *(const float4*)(A + (size_t)(bm + m) * lda + (k0 + kk));
      As[kk + 0][m] = v.x; As[kk + 1][m] = v.y;
      As[kk + 2][m] = v.z; As[kk + 3][m] = v.w;
    }
#pragma unroll
    for (int i = tid * 4; i < BN * BK; i += 1024) {
      int nn = i / BK, kk = i % BK;
      float4 w = *(const float4*)(W + (size_t)(bn + nn) * K + (k0 + kk));
      Ws[kk + 0][nn] = w.x; Ws[kk + 1][nn] = w.y;
      Ws[kk + 2][nn] = w.z; Ws[kk + 3][nn] = w.w;
    }
    __syncthreads();
#pragma unroll
    for (int kk = 0; kk < BK; ++kk) {
      float a[TM], bb[TN];
#pragma unroll
      for (int i = 0; i < TM; i += 4) {
        float4 v = *(const float4*)&As[kk][ty * TM + i];
        a[i] = v.x; a[i+1] = v.y; a[i+2] = v.z; a[i+3] = v.w;
      }
#pragma unroll
      for (int j = 0; j < TN; j += 4) {
        float4 v = *(const float4*)&Ws[kk][tx * TN + j];
        bb[j] = v.x; bb[j+1] = v.y; bb[j+2] = v.z; bb[j+3] = v.w;
      }
#pragma unroll
      for (int i = 0; i < TM; ++i)
#pragma unroll
        for (int j = 0; j < TN; ++j) acc[i][j] += a[i] * bb[j];
    }
    __syncthreads();
  }

#pragma unroll
  for (int i = 0; i < TM; ++i) {
    float* crow = C + (size_t)(bm + ty * TM + i) * ldc + bn + tx * TN;
#pragma unroll
    for (int j = 0; j < TN; j += 4) {
      float4 v = make_float4(acc[i][j], acc[i][j+1], acc[i][j+2], acc[i][j+3]);
      *(float4*)(crow + j) = v;
    }
  }
}

// ---------------------------------------------------------------------------
// K3: depthwise causal conv (DCONV=4) + SiLU.  u lives in xz[:, 0:1024].
// ---------------------------------------------------------------------------
__global__ __launch_bounds__(256) void k_conv(
    const float* __restrict__ xz, const float* __restrict__ cw,
    const float* __restrict__ cb, float* __restrict__ uc)
{
  const int t = blockIdx.x * 256 + threadIdx.x;   // 0..131071
  const int b = t >> 10;
  const int d = t & 1023;
  const float w0 = cw[d * 4 + 0], w1 = cw[d * 4 + 1];
  const float w2 = cw[d * 4 + 2], w3 = cw[d * 4 + 3];
  const float bias = cb[d];
  float u0 = 0.f, u1 = 0.f, u2 = 0.f;
  const float* src = xz + (size_t)b * cNP * cXZ + d;
  float* dst = uc + (size_t)b * cNP * cDIN + d;
  for (int l = 0; l < cNP; ++l) {
    float u3 = src[(size_t)l * cXZ];
    float v = w0 * u0 + w1 * u1 + w2 * u2 + w3 * u3 + bias;
    dst[(size_t)l * cDIN] = silu_f(v);
    u0 = u1; u1 = u2; u2 = u3;
  }
}

// ---------------------------------------------------------------------------
// K5: dt_proj + softplus -> delta written into xz u-half (u is dead now)
// ---------------------------------------------------------------------------
__global__ __launch_bounds__(256) void k_dtproj(
    const float* __restrict__ xdbl, const float* __restrict__ wdt,
    const float* __restrict__ bdt, float* __restrict__ xz)
{
  const int row = blockIdx.x;
  const int tid = threadIdx.x;
  __shared__ float sdt[cDTR];
  if (tid < cDTR) sdt[tid] = xdbl[(size_t)row * 64 + tid];
  __syncthreads();
  const int d0 = tid * 4;
  float* drow = xz + (size_t)row * cXZ;
#pragma unroll
  for (int j = 0; j < 4; ++j) {
    const float4* wp = (const float4*)(wdt + (size_t)(d0 + j) * cDTR);
    float a = 0.f;
#pragma unroll
    for (int r = 0; r < cDTR; r += 4) {
      float4 w = wp[r >> 2];
      a += sdt[r+0]*w.x + sdt[r+1]*w.y + sdt[r+2]*w.z + sdt[r+3]*w.w;
    }
    float v = a + bdt[d0 + j];
    float sp = fmaxf(v, 0.f) + log1pf(__expf(-fabsf(v)));
    drow[d0 + j] = sp;
  }
}

// ---------------------------------------------------------------------------
// K6: selective scan + (y + uc*D) * silu(z); y written as PACKED bf16 into
// the (dead) delta region of xz: u16 index row*4096 + d, d in [0,1024).
// ONE block per batch (512 threads, 2 channels each) so the bf16 writes that
// clobber delta fp32 slots stay inside the block (barrier-protected).
// ---------------------------------------------------------------------------
__global__ __launch_bounds__(512) void k_scan(
    float* __restrict__ xz, const float* __restrict__ uc,
    const float* __restrict__ xdbl, const float* __restrict__ A_log,
    const float* __restrict__ Dp)
{
  const int b = blockIdx.x;
  const int tid = threadIdx.x;      // 0..511
  const int d0 = tid;
  const int d1 = tid + 512;

  float A0[cDST], A1[cDST];
  {
    const float4* ap = (const float4*)(A_log + (size_t)d0 * cDST);
#pragma unroll
    for (int q = 0; q < 4; ++q) {
      float4 w = ap[q];
      A0[q*4+0] = -__expf(w.x); A0[q*4+1] = -__expf(w.y);
      A0[q*4+2] = -__expf(w.z); A0[q*4+3] = -__expf(w.w);
    }
    const float4* ap1 = (const float4*)(A_log + (size_t)d1 * cDST);
#pragma unroll
    for (int q = 0; q < 4; ++q) {
      float4 w = ap1[q];
      A1[q*4+0] = -__expf(w.x); A1[q*4+1] = -__expf(w.y);
      A1[q*4+2] = -__expf(w.z); A1[q*4+3] = -__expf(w.w);
    }
  }
  float h0[cDST], h1[cDST];
#pragma unroll
  for (int n = 0; n < cDST; ++n) { h0[n] = 0.f; h1[n] = 0.f; }
  const float D0 = Dp[d0], D1 = Dp[d1];

  __shared__ float sB[cDST], sC[cDST];
  u16* yout = (u16*)xz;

  for (int l = 0; l < cNP; ++l) {
    const size_t row = (size_t)b * cNP + l;
    if (tid < 32) {
      float v = xdbl[row * 64 + 32 + tid];
      if (tid < 16) sB[tid] = v; else sC[tid - 16] = v;
    }
    const float dv0 = xz[row * cXZ + d0];
    const float dv1 = xz[row * cXZ + d1];
    const float uv0 = uc[row * cDIN + d0];
    const float uv1 = uc[row * cDIN + d1];
    const float zv0 = xz[row * cXZ + cDIN + d0];
    const float zv1 = xz[row * cXZ + cDIN + d1];
    __syncthreads();   // sB/sC staged AND all delta reads done before y writes

    const float du0 = dv0 * uv0;
    const float du1 = dv1 * uv1;
    float y0 = 0.f, y1 = 0.f;
#pragma unroll
    for (int n = 0; n < cDST; ++n) {
      float dA0 = __expf(dv0 * A0[n]);
      h0[n] = dA0 * h0[n] + du0 * sB[n];
      y0 += h0[n] * sC[n];
      float dA1 = __expf(dv1 * A1[n]);
      h1[n] = dA1 * h1[n] + du1 * sB[n];
      y1 += h1[n] * sC[n];
    }
    y0 = (y0 + uv0 * D0) * silu_f(zv0);
    y1 = (y1 + uv1 * D1) * silu_f(zv1);
    yout[row * 4096 + d0] = f2bfu(y0);
    yout[row * 4096 + d1] = f2bfu(y1);
    __syncthreads();   // y writes done before next iter's sB/sC restage
  }
}

// ---------------------------------------------------------------------------
// K7: head LayerNorm stats per batch row (32768 elems)
// ---------------------------------------------------------------------------
__global__ __launch_bounds__(256) void k_hstats(
    const float* __restrict__ x, float* __restrict__ stats)
{
  const int b = blockIdx.x;
  const int tid = threadIdx.x;
  const float4* r4 = (const float4*)(x + (size_t)b * (cNP * cDIM));
  float s = 0.f, s2 = 0.f;
  for (int i = tid; i < (cNP * cDIM) / 4; i += 256) {
    float4 v = r4[i];
    s  += v.x + v.y + v.z + v.w;
    s2 += v.x*v.x + v.y*v.y + v.z*v.z + v.w*v.w;
  }
  __shared__ float red[256];
  red[tid] = s; __syncthreads();
  for (int st = 128; st > 0; st >>= 1) {
    if (tid < st) red[tid] += red[tid + st];
    __syncthreads();
  }
  const float mu = red[0] * (1.f / (cNP * cDIM));
  __syncthreads();
  red[tid] = s2; __syncthreads();
  for (int st = 128; st > 0; st >>= 1) {
    if (tid < st) red[tid] += red[tid + st];
    __syncthreads();
  }
  if (tid == 0) {
    float var = red[0] * (1.f / (cNP * cDIM)) - mu * mu;
    stats[2 * b]     = mu;
    stats[2 * b + 1] = rsqrtf(var + 1e-5f);
  }
}

// ---------------------------------------------------------------------------
// K8: head LN apply + classifier GEMV, fp32 output
// ---------------------------------------------------------------------------
__global__ __launch_bounds__(256) void k_head(
    const float* __restrict__ x, const float* __restrict__ stats,
    const float* __restrict__ hg, const float* __restrict__ hb,
    const float* __restrict__ hw, const float* __restrict__ hbias,
    float* __restrict__ out)
{
  const int b = blockIdx.x;
  const int tid = threadIdx.x;
  const float mu = stats[2 * b], rstd = stats[2 * b + 1];
  const float* row = x + (size_t)b * (cNP * cDIM);

  float acc[cNCLS];
#pragma unroll
  for (int c = 0; c < cNCLS; ++c) acc[c] = 0.f;

  for (int i0 = tid * 2; i0 < cNP * cDIM; i0 += 512) {
    float xn0 = (row[i0]     - mu) * rstd * hg[i0]     + hb[i0];
    float xn1 = (row[i0 + 1] - mu) * rstd * hg[i0 + 1] + hb[i0 + 1];
#pragma unroll
    for (int c = 0; c < cNCLS; ++c) {
      float2 w2 = *(const float2*)(hw + (size_t)c * (cNP * cDIM) + i0);
      acc[c] += xn0 * w2.x + xn1 * w2.y;
    }
  }

  __shared__ float sred[cNCLS * 257];
#pragma unroll
  for (int c = 0; c < cNCLS; ++c) sred[c * 257 + tid] = acc[c];
  __syncthreads();
  if (tid < cNCLS) {
    float s = 0.f;
    for (int i = 0; i < 256; ++i) s += sred[tid * 257 + i];
    out[b * cNCLS + tid] = s + hbias[tid];
  }
}

// ---------------------------------------------------------------------------
extern "C" void kernel_launch(void* const* d_in, const int* in_sizes, int n_in,
                              void* d_out, int out_size, void* d_ws, size_t ws_size,
                              hipStream_t stream)
{
  (void)in_sizes; (void)n_in; (void)out_size; (void)ws_size;

  const float* series    = (const float*)d_in[0];
  const float* seg_w     = (const float*)d_in[1];
  const float* seg_b     = (const float*)d_in[2];
  const float* ln_g      = (const float*)d_in[3];
  const float* ln_b      = (const float*)d_in[4];
  const float* in_proj_w = (const float*)d_in[5];
  const float* conv_w    = (const float*)d_in[6];
  const float* conv_b    = (const float*)d_in[7];
  const float* x_proj_w  = (const float*)d_in[8];
  const float* dt_proj_w = (const float*)d_in[9];
  const float* dt_proj_b = (const float*)d_in[10];
  const float* A_log     = (const float*)d_in[11];
  const float* Dp        = (const float*)d_in[12];
  const float* out_proj_w= (const float*)d_in[13];
  const float* head_ln_g = (const float*)d_in[14];
  const float* head_ln_b = (const float*)d_in[15];
  const float* head_w    = (const float*)d_in[16];
  const float* head_b    = (const float*)d_in[17];

  // workspace layout (117.4 MB total; x0 fp32 aliases ucb's first half —
  // uc is dead when out_proj writes x0, and conv rewrites uc next layer)
  float* ws    = (float*)d_ws;
  float* ucb   = ws;                                  // [8192,1024] f32
  float* x0    = ws;                                  // alias: [8192,512] f32
  float* xz    = ws + (size_t)cBL * cDIN;             // [8192,2048] f32
  float* xdbl  = xz + (size_t)cBL * cXZ;              // [8192,64]   f32
  float* stats = xdbl + (size_t)cBL * 64;             // [256]       f32
  u16*   x0b   = (u16*)(stats + 256);                 // [8192,512]  bf16
  u16*   wib   = x0b + (size_t)cBL * cDIM;            // [2,2048,512] bf16
  u16*   wob   = wib + (size_t)2 * (2*cDIN) * cDIM;   // [2,512,1024] bf16

  // weight conversion (both depths at once)
  k_f2bf<<<(2 * (2*cDIN) * cDIM) / 1024, 256, 0, stream>>>(in_proj_w, wib);
  k_f2bf<<<(2 * cDIM * cDIN) / 1024, 256, 0, stream>>>(out_proj_w, wob);

  k_seg_ln<<<cNP * cB, 128, 0, stream>>>(series, seg_w, seg_b, ln_g, ln_b, x0b);

  for (int dep = 0; dep < 2; ++dep) {
    const u16*   wi  = wib + (size_t)dep * (2*cDIN) * cDIM;
    const u16*   wo  = wob + (size_t)dep * cDIM * cDIN;
    const float* cwd = conv_w     + (size_t)dep * cDIN * 4;
    const float* cbd = conv_b     + (size_t)dep * cDIN;
    const float* wx  = x_proj_w   + (size_t)dep * 64 * cDIN;
    const float* wdt = dt_proj_w  + (size_t)dep * cDIN * cDTR;
    const float* bdt = dt_proj_b  + (size_t)dep * cDIN;
    const float* Ald = A_log      + (size_t)dep * cDIN * cDST;
    const float* Dd  = Dp         + (size_t)dep * cDIN;

    // in_proj: xz[8192,2048] = x0b[8192,512] @ wi[2048,512]^T  (MFMA)
    k_gemm_mfma<<<dim3(cBL/128, (2*cDIN)/128), 256, 0, stream>>>(
        x0b, cDIM, wi, xz, cXZ, (u16*)nullptr, 0, cDIM);
    // depthwise conv + silu -> uc
    k_conv<<<(cB * cDIN) / 256, 256, 0, stream>>>(xz, cwd, cbd, ucb);
    // x_proj: xdbl[8192,64] = uc[8192,1024] @ wx[64,1024]^T  (fp32)
    k_gemm<64,64,4,4><<<dim3(cBL/64, 1), 256, 0, stream>>>(
        ucb, cDIN, wx, xdbl, 64, cBL, 64, cDIN);
    // dt_proj + softplus -> delta (into xz u-half, fp32)
    k_dtproj<<<cBL, 256, 0, stream>>>(xdbl, wdt, bdt, xz);
    // scan + gate -> y packed bf16 into xz u-half (u16 stride 4096)
    k_scan<<<cB, 512, 0, stream>>>(xz, ucb, xdbl, Ald, Dd);
    // out_proj: x0[8192,512](fp32) & x0b(bf16) = y[8192,1024] @ wo[512,1024]^T
    k_gemm_mfma<<<dim3(cBL/128, cDIM/128), 256, 0, stream>>>(
        (const u16*)xz, 4096, wo, x0, cDIM, x0b, cDIM, cDIN);
  }

  k_hstats<<<cB, 256, 0, stream>>>(x0, stats);
  k_head<<<cB, 256, 0, stream>>>(x0, stats, head_ln_g, head_ln_b,
                                 head_w, head_b, (float*)d_out);
}

// Round 4
// 699.443 us; speedup vs baseline: 2.2573x; 1.3418x over previous
//
#include <hip/hip_runtime.h>

typedef unsigned short u16;
typedef unsigned int   u32;
typedef __attribute__((ext_vector_type(8))) short short8;
typedef __attribute__((ext_vector_type(4))) float floatx4;

static __device__ __forceinline__ float silu_f(float x){
  return x / (1.f + __expf(-x));
}
static __device__ __forceinline__ u16 f2bfu(float f){
  union { float f; u32 i; } v; v.f = f;
  u32 x = v.i;
  u32 r = (x + 0x7fffu + ((x >> 16) & 1u)) >> 16;   // round-nearest-even
  return (u16)r;
}
static __device__ __forceinline__ float softplus_f(float v){
  return fmaxf(v, 0.f) + log1pf(__expf(-fabsf(v)));
}

constexpr int cB = 128, cNP = 64, cP = 128, cDIM = 512, cDIN = 1024;
constexpr int cDST = 16, cDTR = 32, cNCLS = 32;
constexpr int cBL = cB * cNP;      // 8192 (b,l) rows
constexpr int cXZ = 2 * cDIN;      // 2048

// ---------------------------------------------------------------------------
// K0: fp32 -> bf16 conversion (one float4 per thread)
// ---------------------------------------------------------------------------
__global__ __launch_bounds__(256) void k_f2bf(
    const float* __restrict__ src, u16* __restrict__ dst)
{
  const int i = (blockIdx.x * 256 + threadIdx.x) * 4;
  float4 v = *(const float4*)(src + i);
  ushort4 o;
  o.x = f2bfu(v.x); o.y = f2bfu(v.y); o.z = f2bfu(v.z); o.w = f2bfu(v.w);
  *(ushort4*)(dst + i) = o;
}

// ---------------------------------------------------------------------------
// K1: segment projection + per-pathway LayerNorm -> bf16 x0b
// ---------------------------------------------------------------------------
__global__ __launch_bounds__(128) void k_seg_ln(
    const float* __restrict__ series, const float* __restrict__ seg_w,
    const float* __restrict__ seg_b,  const float* __restrict__ ln_g,
    const float* __restrict__ ln_b,   u16* __restrict__ x0b)
{
  const int bid = blockIdx.x;
  const int n = bid / cB;
  const int b = bid % cB;
  const int tid = threadIdx.x;       // 128 threads

  __shared__ float s[cP];
  __shared__ float red[cP];

  s[tid] = series[(size_t)b * (cNP * cP) + n * cP + tid];
  __syncthreads();

  const float4* wv = (const float4*)(seg_w + (size_t)n * cP * cDIM);
  float a0 = 0.f, a1 = 0.f, a2 = 0.f, a3 = 0.f;
#pragma unroll 4
  for (int p = 0; p < cP; ++p) {
    float sp = s[p];
    float4 w = wv[p * (cDIM / 4) + tid];
    a0 += sp * w.x; a1 += sp * w.y;
    a2 += sp * w.z; a3 += sp * w.w;
  }
  const int d0 = tid * 4;
  a0 += seg_b[n * cDIM + d0 + 0];
  a1 += seg_b[n * cDIM + d0 + 1];
  a2 += seg_b[n * cDIM + d0 + 2];
  a3 += seg_b[n * cDIM + d0 + 3];

  red[tid] = a0 + a1 + a2 + a3;
  __syncthreads();
  for (int s2 = 64; s2 > 0; s2 >>= 1) {
    if (tid < s2) red[tid] += red[tid + s2];
    __syncthreads();
  }
  const float mu = red[0] * (1.f / cDIM);
  __syncthreads();
  red[tid] = a0*a0 + a1*a1 + a2*a2 + a3*a3;
  __syncthreads();
  for (int s2 = 64; s2 > 0; s2 >>= 1) {
    if (tid < s2) red[tid] += red[tid + s2];
    __syncthreads();
  }
  const float var = red[0] * (1.f / cDIM) - mu * mu;
  const float rstd = rsqrtf(var + 1e-5f);

  u16* orow = x0b + (size_t)(b * cNP + n) * cDIM + d0;
  ushort4 o;
  o.x = f2bfu((a0 - mu) * rstd * ln_g[n*cDIM + d0+0] + ln_b[n*cDIM + d0+0]);
  o.y = f2bfu((a1 - mu) * rstd * ln_g[n*cDIM + d0+1] + ln_b[n*cDIM + d0+1]);
  o.z = f2bfu((a2 - mu) * rstd * ln_g[n*cDIM + d0+2] + ln_b[n*cDIM + d0+2]);
  o.w = f2bfu((a3 - mu) * rstd * ln_g[n*cDIM + d0+3] + ln_b[n*cDIM + d0+3]);
  *(ushort4*)orow = o;
}

// ---------------------------------------------------------------------------
// K2: bf16 MFMA GEMM: C[M,N] = A[M,K] * W[N,K]^T. 128x128 tile, BK=32,
// 256 thr = 4 waves (2x2 of 64x64). AF32: A is fp32, converted in staging.
// EPI=1: C = softplus(acc + bias[n]). C / Cb (bf16 copy) each nullable.
// ---------------------------------------------------------------------------
template<bool AF32, int EPI>
__global__ __launch_bounds__(256) void k_gemm_mfma(
    const void* __restrict__ Av, int lda,
    const u16* __restrict__ W,
    float* __restrict__ C, int ldc,
    u16* __restrict__ Cb, int ldcb,
    const float* __restrict__ bias,
    int K)
{
  constexpr int LDT = 40;   // 32 + 8 pad (u16) -> conflict-free
  __shared__ __align__(16) u16 As[128 * LDT];
  __shared__ __align__(16) u16 Ws[128 * LDT];

  const int tid = threadIdx.x;
  const int bm = blockIdx.x * 128;
  const int bn = blockIdx.y * 128;
  const int wave = tid >> 6;
  const int lane = tid & 63;
  const int wm = (wave & 1) * 64;
  const int wn = (wave >> 1) * 64;
  const int l15 = lane & 15;
  const int quad = lane >> 4;

  floatx4 acc[4][4];
#pragma unroll
  for (int i = 0; i < 4; ++i)
#pragma unroll
    for (int j = 0; j < 4; ++j) acc[i][j] = (floatx4){0.f, 0.f, 0.f, 0.f};

  const int r0 = tid >> 2;          // 0..63
  const int c0 = (tid & 3) * 8;     // 0,8,16,24

  for (int k0 = 0; k0 < K; k0 += 32) {
    if constexpr (AF32) {
      const float* A = (const float*)Av;
#pragma unroll
      for (int h = 0; h < 2; ++h) {
        const float* p = A + (size_t)(bm + r0 + h * 64) * lda + k0 + c0;
        float4 va = *(const float4*)p;
        float4 vb = *(const float4*)(p + 4);
        short8 st;
        st[0] = (short)f2bfu(va.x); st[1] = (short)f2bfu(va.y);
        st[2] = (short)f2bfu(va.z); st[3] = (short)f2bfu(va.w);
        st[4] = (short)f2bfu(vb.x); st[5] = (short)f2bfu(vb.y);
        st[6] = (short)f2bfu(vb.z); st[7] = (short)f2bfu(vb.w);
        *(short8*)&As[(r0 + h * 64) * LDT + c0] = st;
      }
    } else {
      const u16* A = (const u16*)Av;
      short8 va0 = *(const short8*)(A + (size_t)(bm + r0)      * lda + k0 + c0);
      short8 va1 = *(const short8*)(A + (size_t)(bm + r0 + 64) * lda + k0 + c0);
      *(short8*)&As[r0 * LDT + c0] = va0;
      *(short8*)&As[(r0 + 64) * LDT + c0] = va1;
    }
    short8 vw0 = *(const short8*)(W + (size_t)(bn + r0)      * K + k0 + c0);
    short8 vw1 = *(const short8*)(W + (size_t)(bn + r0 + 64) * K + k0 + c0);
    *(short8*)&Ws[r0 * LDT + c0] = vw0;
    *(short8*)&Ws[(r0 + 64) * LDT + c0] = vw1;
    __syncthreads();

    short8 af[4], bf[4];
#pragma unroll
    for (int i = 0; i < 4; ++i)
      af[i] = *(const short8*)&As[(wm + i * 16 + l15) * LDT + quad * 8];
#pragma unroll
    for (int j = 0; j < 4; ++j)
      bf[j] = *(const short8*)&Ws[(wn + j * 16 + l15) * LDT + quad * 8];
#pragma unroll
    for (int i = 0; i < 4; ++i)
#pragma unroll
      for (int j = 0; j < 4; ++j)
        acc[i][j] = __builtin_amdgcn_mfma_f32_16x16x32_bf16(
            af[i], bf[j], acc[i][j], 0, 0, 0);
    __syncthreads();
  }

#pragma unroll
  for (int i = 0; i < 4; ++i) {
    const int m0 = bm + wm + i * 16 + quad * 4;
#pragma unroll
    for (int j = 0; j < 4; ++j) {
      const int n = bn + wn + j * 16 + l15;
      if constexpr (EPI == 1) {
        const float bs = bias[n];
#pragma unroll
        for (int r = 0; r < 4; ++r)
          C[(size_t)(m0 + r) * ldc + n] = softplus_f(acc[i][j][r] + bs);
      } else {
        if (C) {
#pragma unroll
          for (int r = 0; r < 4; ++r)
            C[(size_t)(m0 + r) * ldc + n] = acc[i][j][r];
        }
        if (Cb) {
#pragma unroll
          for (int r = 0; r < 4; ++r)
            Cb[(size_t)(m0 + r) * ldcb + n] = f2bfu(acc[i][j][r]);
        }
      }
    }
  }
}

// ---------------------------------------------------------------------------
// fp32 tiled GEMM (x_proj): C[M,N] = A[M,K] * W[N,K]^T, optional bf16 copy
// ---------------------------------------------------------------------------
template<int BM, int BN, int TM, int TN>
__global__ __launch_bounds__(256) void k_gemm(
    const float* __restrict__ A, int lda,
    const float* __restrict__ W,
    float* __restrict__ C, int ldc,
    u16* __restrict__ Cb, int ldcb,
    int M, int N, int K)
{
  constexpr int BK = 16;
  __shared__ __align__(16) float As[BK][BM + 4];
  __shared__ __align__(16) float Ws[BK][BN + 4];

  const int tid = threadIdx.x;
  const int bm = blockIdx.x * BM;
  const int bn = blockIdx.y * BN;
  const int tx = tid % (BN / TN);
  const int ty = tid / (BN / TN);

  float acc[TM][TN];
#pragma unroll
  for (int i = 0; i < TM; ++i)
#pragma unroll
    for (int j = 0; j < TN; ++j) acc[i][j] = 0.f;

  for (int k0 = 0; k0 < K; k0 += BK) {
#pragma unroll
    for (int i = tid * 4; i < BM * BK; i += 1024) {
      int m = i / BK, kk = i % BK;
      float4 v = *(const float4*)(A + (size_t)(bm + m) * lda + (k0 + kk));
      As[kk + 0][m] = v.x; As[kk + 1][m] = v.y;
      As[kk + 2][m] = v.z; As[kk + 3][m] = v.w;
    }
#pragma unroll
    for (int i = tid * 4; i < BN * BK; i += 1024) {
      int nn = i / BK, kk = i % BK;
      float4 w = *(const float4*)(W + (size_t)(bn + nn) * K + (k0 + kk));
      Ws[kk + 0][nn] = w.x; Ws[kk + 1][nn] = w.y;
      Ws[kk + 2][nn] = w.z; Ws[kk + 3][nn] = w.w;
    }
    __syncthreads();
#pragma unroll
    for (int kk = 0; kk < BK; ++kk) {
      float a[TM], bb[TN];
#pragma unroll
      for (int i = 0; i < TM; i += 4) {
        float4 v = *(const float4*)&As[kk][ty * TM + i];
        a[i] = v.x; a[i+1] = v.y; a[i+2] = v.z; a[i+3] = v.w;
      }
#pragma unroll
      for (int j = 0; j < TN; j += 4) {
        float4 v = *(const float4*)&Ws[kk][tx * TN + j];
        bb[j] = v.x; bb[j+1] = v.y; bb[j+2] = v.z; bb[j+3] = v.w;
      }
#pragma unroll
      for (int i = 0; i < TM; ++i)
#pragma unroll
        for (int j = 0; j < TN; ++j) acc[i][j] += a[i] * bb[j];
    }
    __syncthreads();
  }

#pragma unroll
  for (int i = 0; i < TM; ++i) {
    float* crow = C + (size_t)(bm + ty * TM + i) * ldc + bn + tx * TN;
#pragma unroll
    for (int j = 0; j < TN; j += 4) {
      float4 v = make_float4(acc[i][j], acc[i][j+1], acc[i][j+2], acc[i][j+3]);
      *(float4*)(crow + j) = v;
    }
    if (Cb) {
      u16* cbrow = Cb + (size_t)(bm + ty * TM + i) * ldcb + bn + tx * TN;
#pragma unroll
      for (int j = 0; j < TN; ++j) cbrow[j] = f2bfu(acc[i][j]);
    }
  }
}

// ---------------------------------------------------------------------------
// K3: depthwise causal conv (DCONV=4) + SiLU.  u lives in xz[:, 0:1024].
// ---------------------------------------------------------------------------
__global__ __launch_bounds__(256) void k_conv(
    const float* __restrict__ xz, const float* __restrict__ cw,
    const float* __restrict__ cb, float* __restrict__ uc)
{
  const int t = blockIdx.x * 256 + threadIdx.x;   // 0..131071
  const int b = t >> 10;
  const int d = t & 1023;
  const float w0 = cw[d * 4 + 0], w1 = cw[d * 4 + 1];
  const float w2 = cw[d * 4 + 2], w3 = cw[d * 4 + 3];
  const float bias = cb[d];
  float u0 = 0.f, u1 = 0.f, u2 = 0.f;
  const float* src = xz + (size_t)b * cNP * cXZ + d;
  float* dst = uc + (size_t)b * cNP * cDIN + d;
  for (int l = 0; l < cNP; ++l) {
    float u3 = src[(size_t)l * cXZ];
    float v = w0 * u0 + w1 * u1 + w2 * u2 + w3 * u3 + bias;
    dst[(size_t)l * cDIN] = silu_f(v);
    u0 = u1; u1 = u2; u2 = u3;
  }
}

// ---------------------------------------------------------------------------
// K6: selective scan + (y + uc*D) * silu(z); y (fp32) overwrites uc in place
// (thread-owned slot -> race-free). grid (b, 4): block owns 256 channels.
// All 64 steps' B/C preloaded to LDS -> no in-loop barriers.
// ---------------------------------------------------------------------------
__global__ __launch_bounds__(256) void k_scan(
    const float* __restrict__ xz, float* __restrict__ uc,
    const float* __restrict__ xdbl, const float* __restrict__ A_log,
    const float* __restrict__ Dp)
{
  const int b = blockIdx.x;
  const int tid = threadIdx.x;      // 0..255
  const int d = blockIdx.y * 256 + tid;

  __shared__ float sBC[cNP][32];    // [l][0:16]=B, [16:32]=C
  {
    const float4* src = (const float4*)xdbl;
    for (int i = tid; i < cNP * 8; i += 256) {
      int l = i >> 3, q = i & 7;
      *(float4*)&sBC[l][q * 4] = src[(size_t)(b * cNP + l) * 16 + 8 + q];
    }
  }

  float A[cDST];
  {
    const float4* ap = (const float4*)(A_log + (size_t)d * cDST);
#pragma unroll
    for (int q = 0; q < 4; ++q) {
      float4 w = ap[q];
      A[q*4+0] = -__expf(w.x); A[q*4+1] = -__expf(w.y);
      A[q*4+2] = -__expf(w.z); A[q*4+3] = -__expf(w.w);
    }
  }
  float h[cDST];
#pragma unroll
  for (int n = 0; n < cDST; ++n) h[n] = 0.f;
  const float Dv = Dp[d];
  __syncthreads();

  const float* dsrc = xz + d;            // delta at xz[row*2048 + d]
  const float* zsrc = xz + cDIN + d;     // z     at xz[row*2048 + 1024 + d]
  float* usrc = uc + d;                  // uc / y at uc[row*1024 + d]

  size_t rowf = (size_t)b * cNP;
  float dv = dsrc[rowf * cXZ];
  float zv = zsrc[rowf * cXZ];
  float uv = usrc[rowf * cDIN];

#pragma unroll 4
  for (int l = 0; l < cNP; ++l) {
    // prefetch next step
    const int ln = (l + 1 < cNP) ? (l + 1) : l;
    const size_t rown = (size_t)b * cNP + ln;
    float dv_n = dsrc[rown * cXZ];
    float zv_n = zsrc[rown * cXZ];
    float uv_n = usrc[rown * cDIN];

    const float du = dv * uv;
    float y = 0.f;
#pragma unroll
    for (int n = 0; n < cDST; ++n) {
      float dA = __expf(dv * A[n]);
      h[n] = dA * h[n] + du * sBC[l][n];
      y += h[n] * sBC[l][16 + n];
    }
    y = (y + uv * Dv) * silu_f(zv);
    usrc[((size_t)b * cNP + l) * cDIN] = y;

    dv = dv_n; zv = zv_n; uv = uv_n;
  }
}

// ---------------------------------------------------------------------------
// K7: head LayerNorm stats per batch row (32768 elems)
// ---------------------------------------------------------------------------
__global__ __launch_bounds__(256) void k_hstats(
    const float* __restrict__ x, float* __restrict__ stats)
{
  const int b = blockIdx.x;
  const int tid = threadIdx.x;
  const float4* r4 = (const float4*)(x + (size_t)b * (cNP * cDIM));
  float s = 0.f, s2 = 0.f;
  for (int i = tid; i < (cNP * cDIM) / 4; i += 256) {
    float4 v = r4[i];
    s  += v.x + v.y + v.z + v.w;
    s2 += v.x*v.x + v.y*v.y + v.z*v.z + v.w*v.w;
  }
  __shared__ float red[256];
  red[tid] = s; __syncthreads();
  for (int st = 128; st > 0; st >>= 1) {
    if (tid < st) red[tid] += red[tid + st];
    __syncthreads();
  }
  const float mu = red[0] * (1.f / (cNP * cDIM));
  __syncthreads();
  red[tid] = s2; __syncthreads();
  for (int st = 128; st > 0; st >>= 1) {
    if (tid < st) red[tid] += red[tid + st];
    __syncthreads();
  }
  if (tid == 0) {
    float var = red[0] * (1.f / (cNP * cDIM)) - mu * mu;
    stats[2 * b]     = mu;
    stats[2 * b + 1] = rsqrtf(var + 1e-5f);
  }
}

// ---------------------------------------------------------------------------
// K8: head LN apply + classifier GEMV, fp32 output
// ---------------------------------------------------------------------------
__global__ __launch_bounds__(256) void k_head(
    const float* __restrict__ x, const float* __restrict__ stats,
    const float* __restrict__ hg, const float* __restrict__ hb,
    const float* __restrict__ hw, const float* __restrict__ hbias,
    float* __restrict__ out)
{
  const int b = blockIdx.x;
  const int tid = threadIdx.x;
  const float mu = stats[2 * b], rstd = stats[2 * b + 1];
  const float* row = x + (size_t)b * (cNP * cDIM);

  float acc[cNCLS];
#pragma unroll
  for (int c = 0; c < cNCLS; ++c) acc[c] = 0.f;

  for (int i0 = tid * 2; i0 < cNP * cDIM; i0 += 512) {
    float xn0 = (row[i0]     - mu) * rstd * hg[i0]     + hb[i0];
    float xn1 = (row[i0 + 1] - mu) * rstd * hg[i0 + 1] + hb[i0 + 1];
#pragma unroll
    for (int c = 0; c < cNCLS; ++c) {
      float2 w2 = *(const float2*)(hw + (size_t)c * (cNP * cDIM) + i0);
      acc[c] += xn0 * w2.x + xn1 * w2.y;
    }
  }

  __shared__ float sred[cNCLS * 257];
#pragma unroll
  for (int c = 0; c < cNCLS; ++c) sred[c * 257 + tid] = acc[c];
  __syncthreads();
  if (tid < cNCLS) {
    float s = 0.f;
    for (int i = 0; i < 256; ++i) s += sred[tid * 257 + i];
    out[b * cNCLS + tid] = s + hbias[tid];
  }
}

// ---------------------------------------------------------------------------
extern "C" void kernel_launch(void* const* d_in, const int* in_sizes, int n_in,
                              void* d_out, int out_size, void* d_ws, size_t ws_size,
                              hipStream_t stream)
{
  (void)in_sizes; (void)n_in; (void)out_size; (void)ws_size;

  const float* series    = (const float*)d_in[0];
  const float* seg_w     = (const float*)d_in[1];
  const float* seg_b     = (const float*)d_in[2];
  const float* ln_g      = (const float*)d_in[3];
  const float* ln_b      = (const float*)d_in[4];
  const float* in_proj_w = (const float*)d_in[5];
  const float* conv_w    = (const float*)d_in[6];
  const float* conv_b    = (const float*)d_in[7];
  const float* x_proj_w  = (const float*)d_in[8];
  const float* dt_proj_w = (const float*)d_in[9];
  const float* dt_proj_b = (const float*)d_in[10];
  const float* A_log     = (const float*)d_in[11];
  const float* Dp        = (const float*)d_in[12];
  const float* out_proj_w= (const float*)d_in[13];
  const float* head_ln_g = (const float*)d_in[14];
  const float* head_ln_b = (const float*)d_in[15];
  const float* head_w    = (const float*)d_in[16];
  const float* head_b    = (const float*)d_in[17];

  // workspace layout (~124.7 MB)
  float* ws     = (float*)d_ws;
  float* ucb    = ws;                                  // [8192,1024] f32 (uc, then y)
  float* xz     = ws + (size_t)cBL * cDIN;             // [8192,2048] f32 u/delta | z
  float* x0     = xz;                                  // final fp32 x, aliases dead xz
  float* xdbl   = xz + (size_t)cBL * cXZ;              // [8192,64]   f32
  float* stats  = xdbl + (size_t)cBL * 64;             // [256]
  u16*   x0b    = (u16*)(stats + 256);                 // [8192,512]  bf16
  u16*   wib    = x0b + (size_t)cBL * cDIM;            // [2,2048,512] bf16
  u16*   wob    = wib + (size_t)2 * (2*cDIN) * cDIM;   // [2,512,1024] bf16
  u16*   wdtb   = wob + (size_t)2 * cDIM * cDIN;       // [2,1024,32]  bf16
  u16*   xdbl16 = wdtb + (size_t)2 * cDIN * cDTR;      // [8192,64]    bf16

  // weight conversion
  k_f2bf<<<(2 * (2*cDIN) * cDIM) / 1024, 256, 0, stream>>>(in_proj_w, wib);
  k_f2bf<<<(2 * cDIM * cDIN) / 1024, 256, 0, stream>>>(out_proj_w, wob);
  k_f2bf<<<(2 * cDIN * cDTR) / 1024, 256, 0, stream>>>(dt_proj_w, wdtb);

  k_seg_ln<<<cNP * cB, 128, 0, stream>>>(series, seg_w, seg_b, ln_g, ln_b, x0b);

  for (int dep = 0; dep < 2; ++dep) {
    const u16*   wi  = wib  + (size_t)dep * (2*cDIN) * cDIM;
    const u16*   wo  = wob  + (size_t)dep * cDIM * cDIN;
    const u16*   wdt = wdtb + (size_t)dep * cDIN * cDTR;
    const float* cwd = conv_w     + (size_t)dep * cDIN * 4;
    const float* cbd = conv_b     + (size_t)dep * cDIN;
    const float* wx  = x_proj_w   + (size_t)dep * 64 * cDIN;
    const float* bdt = dt_proj_b  + (size_t)dep * cDIN;
    const float* Ald = A_log      + (size_t)dep * cDIN * cDST;
    const float* Dd  = Dp         + (size_t)dep * cDIN;

    // in_proj: xz[8192,2048] = x0b @ wi^T  (MFMA)
    k_gemm_mfma<false,0><<<dim3(cBL/128, (2*cDIN)/128), 256, 0, stream>>>(
        x0b, cDIM, wi, xz, cXZ, (u16*)nullptr, 0, nullptr, cDIM);
    // depthwise conv + silu -> uc
    k_conv<<<(cB * cDIN) / 256, 256, 0, stream>>>(xz, cwd, cbd, ucb);
    // x_proj: xdbl[8192,64] (+bf16 copy) = uc @ wx^T  (fp32)
    k_gemm<64,64,4,4><<<dim3(cBL/64, 1), 256, 0, stream>>>(
        ucb, cDIN, wx, xdbl, 64, xdbl16, 64, cBL, 64, cDIN);
    // dt_proj + softplus -> delta into xz u-half  (MFMA, K=32)
    k_gemm_mfma<false,1><<<dim3(cBL/128, cDIN/128), 256, 0, stream>>>(
        xdbl16, 64, wdt, xz, cXZ, (u16*)nullptr, 0, bdt, cDTR);
    // scan + gate -> y fp32 in place into ucb
    k_scan<<<dim3(cB, 4), 256, 0, stream>>>(xz, ucb, xdbl, Ald, Dd);
    // out_proj: (dep0: bf16 x0b only) (dep1: fp32 x0 only) = y @ wo^T
    k_gemm_mfma<true,0><<<dim3(cBL/128, cDIM/128), 256, 0, stream>>>(
        ucb, cDIN, wo,
        dep ? x0 : (float*)nullptr, cDIM,
        dep ? (u16*)nullptr : x0b, cDIM,
        nullptr, cDIN);
  }

  k_hstats<<<cB, 256, 0, stream>>>(x0, stats);
  k_head<<<cB, 256, 0, stream>>>(x0, stats, head_ln_g, head_ln_b,
                                 head_w, head_b, (float*)d_out);
}

// Round 5
// 530.500 us; speedup vs baseline: 2.9761x; 1.3185x over previous
//
#include <hip/hip_runtime.h>

typedef unsigned short u16;
typedef unsigned int   u32;
typedef __attribute__((ext_vector_type(8))) short short8;
typedef __attribute__((ext_vector_type(4))) float floatx4;

static __device__ __forceinline__ float silu_f(float x){
  return x / (1.f + __expf(-x));
}
static __device__ __forceinline__ float bfu2f(u16 u){
  union { u32 i; float f; } v; v.i = ((u32)u) << 16; return v.f;
}
static __device__ __forceinline__ u16 f2bfu(float f){
  union { float f; u32 i; } v; v.f = f;
  u32 x = v.i;
  u32 r = (x + 0x7fffu + ((x >> 16) & 1u)) >> 16;   // round-nearest-even
  return (u16)r;
}
static __device__ __forceinline__ float softplus_f(float v){
  return fmaxf(v, 0.f) + log1pf(__expf(-fabsf(v)));
}

constexpr int cB = 128, cNP = 64, cP = 128, cDIM = 512, cDIN = 1024;
constexpr int cDST = 16, cDTR = 32, cNCLS = 32;
constexpr int cBL = cB * cNP;      // 8192 (b,l) rows
constexpr int cXZ = 2 * cDIN;      // 2048

// ---------------------------------------------------------------------------
// K0: fp32 -> bf16 conversion (one float4 per thread; n must be /1024)
// ---------------------------------------------------------------------------
__global__ __launch_bounds__(256) void k_f2bf(
    const float* __restrict__ src, u16* __restrict__ dst)
{
  const int i = (blockIdx.x * 256 + threadIdx.x) * 4;
  float4 v = *(const float4*)(src + i);
  ushort4 o;
  o.x = f2bfu(v.x); o.y = f2bfu(v.y); o.z = f2bfu(v.z); o.w = f2bfu(v.w);
  *(ushort4*)(dst + i) = o;
}

// ---------------------------------------------------------------------------
// K0b: seg_w[n,p,d] -> wsegT[n,d,p] (bf16). 32x32 tiles, 256 threads.
// ---------------------------------------------------------------------------
__global__ __launch_bounds__(256) void k_segT(
    const float* __restrict__ src, u16* __restrict__ dst)
{
  const int n = blockIdx.z;
  const int p0 = blockIdx.x * 32;
  const int d0 = blockIdx.y * 32;
  const int tx = threadIdx.x & 31;
  const int ty = threadIdx.x >> 5;     // 0..7
  __shared__ float t[32][33];
#pragma unroll
  for (int r = 0; r < 4; ++r)
    t[ty + r * 8][tx] = src[(size_t)n * (cP * cDIM) + (p0 + ty + r * 8) * cDIM + d0 + tx];
  __syncthreads();
#pragma unroll
  for (int r = 0; r < 4; ++r)
    dst[(size_t)n * (cDIM * cP) + (d0 + ty + r * 8) * cP + p0 + tx] =
        f2bfu(t[tx][ty + r * 8]);
}

// ---------------------------------------------------------------------------
// K2: bf16 MFMA GEMM: C[M,N] = A[M,K] * W[N,K]^T. 128x128 tile, BK=32,
// 256 thr = 4 waves (2x2 of 64x64). AF32: A fp32, converted in staging.
// EPI=1: C = softplus(acc + bias[n]). C / Cb (bf16) each nullable.
// blockIdx.z batching via element strides azs/wzs/czs.
// ---------------------------------------------------------------------------
template<bool AF32, int EPI>
__global__ __launch_bounds__(256) void k_gemm_mfma(
    const void* __restrict__ Av, int lda,
    const u16* __restrict__ W,
    float* __restrict__ C, int ldc,
    u16* __restrict__ Cb, int ldcb,
    const float* __restrict__ bias,
    int K, long azs, long wzs, long czs)
{
  constexpr int LDT = 40;   // 32 + 8 pad (u16) -> conflict-free
  __shared__ __align__(16) u16 As[128 * LDT];
  __shared__ __align__(16) u16 Ws[128 * LDT];

  const int bz = blockIdx.z;
  const u16* Wz = W + (size_t)bz * wzs;

  const int tid = threadIdx.x;
  const int bm = blockIdx.x * 128;
  const int bn = blockIdx.y * 128;
  const int wave = tid >> 6;
  const int lane = tid & 63;
  const int wm = (wave & 1) * 64;
  const int wn = (wave >> 1) * 64;
  const int l15 = lane & 15;
  const int quad = lane >> 4;

  floatx4 acc[4][4];
#pragma unroll
  for (int i = 0; i < 4; ++i)
#pragma unroll
    for (int j = 0; j < 4; ++j) acc[i][j] = (floatx4){0.f, 0.f, 0.f, 0.f};

  const int r0 = tid >> 2;          // 0..63
  const int c0 = (tid & 3) * 8;     // 0,8,16,24

  for (int k0 = 0; k0 < K; k0 += 32) {
    if constexpr (AF32) {
      const float* A = (const float*)Av + bz * azs;
#pragma unroll
      for (int h = 0; h < 2; ++h) {
        const float* p = A + (size_t)(bm + r0 + h * 64) * lda + k0 + c0;
        float4 va = *(const float4*)p;
        float4 vb = *(const float4*)(p + 4);
        short8 st;
        st[0] = (short)f2bfu(va.x); st[1] = (short)f2bfu(va.y);
        st[2] = (short)f2bfu(va.z); st[3] = (short)f2bfu(va.w);
        st[4] = (short)f2bfu(vb.x); st[5] = (short)f2bfu(vb.y);
        st[6] = (short)f2bfu(vb.z); st[7] = (short)f2bfu(vb.w);
        *(short8*)&As[(r0 + h * 64) * LDT + c0] = st;
      }
    } else {
      const u16* A = (const u16*)Av + bz * azs;
      short8 va0 = *(const short8*)(A + (size_t)(bm + r0)      * lda + k0 + c0);
      short8 va1 = *(const short8*)(A + (size_t)(bm + r0 + 64) * lda + k0 + c0);
      *(short8*)&As[r0 * LDT + c0] = va0;
      *(short8*)&As[(r0 + 64) * LDT + c0] = va1;
    }
    short8 vw0 = *(const short8*)(Wz + (size_t)(bn + r0)      * K + k0 + c0);
    short8 vw1 = *(const short8*)(Wz + (size_t)(bn + r0 + 64) * K + k0 + c0);
    *(short8*)&Ws[r0 * LDT + c0] = vw0;
    *(short8*)&Ws[(r0 + 64) * LDT + c0] = vw1;
    __syncthreads();

    short8 af[4], bf[4];
#pragma unroll
    for (int i = 0; i < 4; ++i)
      af[i] = *(const short8*)&As[(wm + i * 16 + l15) * LDT + quad * 8];
#pragma unroll
    for (int j = 0; j < 4; ++j)
      bf[j] = *(const short8*)&Ws[(wn + j * 16 + l15) * LDT + quad * 8];
#pragma unroll
    for (int i = 0; i < 4; ++i)
#pragma unroll
      for (int j = 0; j < 4; ++j)
        acc[i][j] = __builtin_amdgcn_mfma_f32_16x16x32_bf16(
            af[i], bf[j], acc[i][j], 0, 0, 0);
    __syncthreads();
  }

#pragma unroll
  for (int i = 0; i < 4; ++i) {
    const int m0 = bm + wm + i * 16 + quad * 4;
#pragma unroll
    for (int j = 0; j < 4; ++j) {
      const int n = bn + wn + j * 16 + l15;
      if constexpr (EPI == 1) {
        const float bs = bias[n];
#pragma unroll
        for (int r = 0; r < 4; ++r)
          C[(size_t)(m0 + r) * ldc + n + bz * czs] = softplus_f(acc[i][j][r] + bs);
      } else {
        if (C) {
#pragma unroll
          for (int r = 0; r < 4; ++r)
            C[(size_t)(m0 + r) * ldc + n + bz * czs] = acc[i][j][r];
        }
        if (Cb) {
#pragma unroll
          for (int r = 0; r < 4; ++r)
            Cb[(size_t)(m0 + r) * ldcb + n + bz * czs] = f2bfu(acc[i][j][r]);
        }
      }
    }
  }
}

// ---------------------------------------------------------------------------
// K1b: per-row LayerNorm (512 elems), wave per row -> bf16 out
// ---------------------------------------------------------------------------
__global__ __launch_bounds__(256) void k_ln(
    const float* __restrict__ xs, const float* __restrict__ ln_g,
    const float* __restrict__ ln_b, u16* __restrict__ x0b)
{
  const int tid = threadIdx.x;
  const int r = blockIdx.x * 4 + (tid >> 6);   // row (b*64+n)
  const int lane = tid & 63;
  const int d = lane * 8;
  const int n = r & 63;

  const float* row = xs + (size_t)r * cDIM + d;
  float4 a = *(const float4*)row;
  float4 b = *(const float4*)(row + 4);
  float s  = a.x + a.y + a.z + a.w + b.x + b.y + b.z + b.w;
  float s2 = a.x*a.x + a.y*a.y + a.z*a.z + a.w*a.w
           + b.x*b.x + b.y*b.y + b.z*b.z + b.w*b.w;
#pragma unroll
  for (int m = 1; m < 64; m <<= 1) {
    s  += __shfl_xor(s,  m, 64);
    s2 += __shfl_xor(s2, m, 64);
  }
  const float mu = s * (1.f / cDIM);
  const float var = s2 * (1.f / cDIM) - mu * mu;
  const float rstd = rsqrtf(var + 1e-5f);

  const float* g = ln_g + n * cDIM + d;
  const float* be = ln_b + n * cDIM + d;
  float4 g0 = *(const float4*)g, g1 = *(const float4*)(g + 4);
  float4 b0 = *(const float4*)be, b1 = *(const float4*)(be + 4);
  ushort4 o0, o1;
  o0.x = f2bfu((a.x - mu) * rstd * g0.x + b0.x);
  o0.y = f2bfu((a.y - mu) * rstd * g0.y + b0.y);
  o0.z = f2bfu((a.z - mu) * rstd * g0.z + b0.z);
  o0.w = f2bfu((a.w - mu) * rstd * g0.w + b0.w);
  o1.x = f2bfu((b.x - mu) * rstd * g1.x + b1.x);
  o1.y = f2bfu((b.y - mu) * rstd * g1.y + b1.y);
  o1.z = f2bfu((b.z - mu) * rstd * g1.z + b1.z);
  o1.w = f2bfu((b.w - mu) * rstd * g1.w + b1.w);
  *(ushort4*)(x0b + (size_t)r * cDIM + d) = o0;
  *(ushort4*)(x0b + (size_t)r * cDIM + d + 4) = o1;
}

// ---------------------------------------------------------------------------
// K3: depthwise causal conv (DCONV=4) + SiLU -> uc bf16
// ---------------------------------------------------------------------------
__global__ __launch_bounds__(256) void k_conv(
    const float* __restrict__ xz, const float* __restrict__ cw,
    const float* __restrict__ cb, u16* __restrict__ uc)
{
  const int t = blockIdx.x * 256 + threadIdx.x;   // 0..131071
  const int b = t >> 10;
  const int d = t & 1023;
  const float w0 = cw[d * 4 + 0], w1 = cw[d * 4 + 1];
  const float w2 = cw[d * 4 + 2], w3 = cw[d * 4 + 3];
  const float bias = cb[d];
  float u0 = 0.f, u1 = 0.f, u2 = 0.f;
  const float* src = xz + (size_t)b * cNP * cXZ + d;
  u16* dst = uc + (size_t)b * cNP * cDIN + d;
  for (int l = 0; l < cNP; ++l) {
    float u3 = src[(size_t)l * cXZ];
    float v = w0 * u0 + w1 * u1 + w2 * u2 + w3 * u3 + bias;
    dst[(size_t)l * cDIN] = f2bfu(silu_f(v));
    u0 = u1; u1 = u2; u2 = u3;
  }
}

// ---------------------------------------------------------------------------
// K4: x_proj MFMA: xdbl[8192,64] = uc(bf16)[8192,1024] @ wx(bf16)[64,1024]^T
// BM=128, BN=64, 128 threads = 2 waves (2x1 of 64x64).
// ---------------------------------------------------------------------------
__global__ __launch_bounds__(128) void k_xproj(
    const u16* __restrict__ A, const u16* __restrict__ W,
    float* __restrict__ C, u16* __restrict__ Cb)
{
  constexpr int LDT = 40;
  __shared__ __align__(16) u16 As[128 * LDT];
  __shared__ __align__(16) u16 Ws[64 * LDT];

  const int tid = threadIdx.x;
  const int bm = blockIdx.x * 128;
  const int wave = tid >> 6;
  const int lane = tid & 63;
  const int wm = wave * 64;
  const int l15 = lane & 15;
  const int quad = lane >> 4;

  floatx4 acc[4][4];
#pragma unroll
  for (int i = 0; i < 4; ++i)
#pragma unroll
    for (int j = 0; j < 4; ++j) acc[i][j] = (floatx4){0.f, 0.f, 0.f, 0.f};

  for (int k0 = 0; k0 < cDIN; k0 += 32) {
#pragma unroll
    for (int it = 0; it < 4; ++it) {
      int idx = tid + it * 128;          // 0..511
      int row = idx >> 2, c0 = (idx & 3) * 8;
      *(short8*)&As[row * LDT + c0] =
          *(const short8*)(A + (size_t)(bm + row) * cDIN + k0 + c0);
    }
#pragma unroll
    for (int it = 0; it < 2; ++it) {
      int idx = tid + it * 128;          // 0..255
      int row = idx >> 2, c0 = (idx & 3) * 8;
      *(short8*)&Ws[row * LDT + c0] =
          *(const short8*)(W + (size_t)row * cDIN + k0 + c0);
    }
    __syncthreads();

    short8 af[4], bf[4];
#pragma unroll
    for (int i = 0; i < 4; ++i)
      af[i] = *(const short8*)&As[(wm + i * 16 + l15) * LDT + quad * 8];
#pragma unroll
    for (int j = 0; j < 4; ++j)
      bf[j] = *(const short8*)&Ws[(j * 16 + l15) * LDT + quad * 8];
#pragma unroll
    for (int i = 0; i < 4; ++i)
#pragma unroll
      for (int j = 0; j < 4; ++j)
        acc[i][j] = __builtin_amdgcn_mfma_f32_16x16x32_bf16(
            af[i], bf[j], acc[i][j], 0, 0, 0);
    __syncthreads();
  }

#pragma unroll
  for (int i = 0; i < 4; ++i) {
    const int m0 = bm + wm + i * 16 + quad * 4;
#pragma unroll
    for (int j = 0; j < 4; ++j) {
      const int n = j * 16 + l15;
#pragma unroll
      for (int r = 0; r < 4; ++r) {
        C[(size_t)(m0 + r) * 64 + n] = acc[i][j][r];
        Cb[(size_t)(m0 + r) * 64 + n] = f2bfu(acc[i][j][r]);
      }
    }
  }
}

// ---------------------------------------------------------------------------
// K6: selective scan + (y + uc*D) * silu(z); uc bf16 in, y bf16 out in place.
// grid (b, 4): block owns 256 channels. B/C for all 64 steps preloaded.
// ---------------------------------------------------------------------------
__global__ __launch_bounds__(256) void k_scan(
    const float* __restrict__ xz, u16* __restrict__ uc,
    const float* __restrict__ xdbl, const float* __restrict__ A_log,
    const float* __restrict__ Dp)
{
  const int b = blockIdx.x;
  const int tid = threadIdx.x;      // 0..255
  const int d = blockIdx.y * 256 + tid;

  __shared__ float sBC[cNP][32];    // [l][0:16]=B, [16:32]=C
  {
    const float4* src = (const float4*)xdbl;
    for (int i = tid; i < cNP * 8; i += 256) {
      int l = i >> 3, q = i & 7;
      *(float4*)&sBC[l][q * 4] = src[(size_t)(b * cNP + l) * 16 + 8 + q];
    }
  }

  float A[cDST];
  {
    const float4* ap = (const float4*)(A_log + (size_t)d * cDST);
#pragma unroll
    for (int q = 0; q < 4; ++q) {
      float4 w = ap[q];
      A[q*4+0] = -__expf(w.x); A[q*4+1] = -__expf(w.y);
      A[q*4+2] = -__expf(w.z); A[q*4+3] = -__expf(w.w);
    }
  }
  float h[cDST];
#pragma unroll
  for (int n = 0; n < cDST; ++n) h[n] = 0.f;
  const float Dv = Dp[d];
  __syncthreads();

  const float* dsrc = xz + d;            // delta at xz[row*2048 + d]
  const float* zsrc = xz + cDIN + d;     // z
  u16* usrc = uc + d;                    // uc / y (bf16)

  size_t rowf = (size_t)b * cNP;
  float dv = dsrc[rowf * cXZ];
  float zv = zsrc[rowf * cXZ];
  float uv = bfu2f(usrc[rowf * cDIN]);

#pragma unroll 4
  for (int l = 0; l < cNP; ++l) {
    const int ln = (l + 1 < cNP) ? (l + 1) : l;
    const size_t rown = (size_t)b * cNP + ln;
    float dv_n = dsrc[rown * cXZ];
    float zv_n = zsrc[rown * cXZ];
    float uv_n = bfu2f(usrc[rown * cDIN]);

    const float du = dv * uv;
    float y = 0.f;
#pragma unroll
    for (int n = 0; n < cDST; ++n) {
      float dA = __expf(dv * A[n]);
      h[n] = dA * h[n] + du * sBC[l][n];
      y += h[n] * sBC[l][16 + n];
    }
    y = (y + uv * Dv) * silu_f(zv);
    usrc[((size_t)b * cNP + l) * cDIN] = f2bfu(y);

    dv = dv_n; zv = zv_n; uv = uv_n;
  }
}

// ---------------------------------------------------------------------------
// K7: head LayerNorm stats per batch row (32768 elems)
// ---------------------------------------------------------------------------
__global__ __launch_bounds__(256) void k_hstats(
    const float* __restrict__ x, float* __restrict__ stats)
{
  const int b = blockIdx.x;
  const int tid = threadIdx.x;
  const float4* r4 = (const float4*)(x + (size_t)b * (cNP * cDIM));
  float s = 0.f, s2 = 0.f;
  for (int i = tid; i < (cNP * cDIM) / 4; i += 256) {
    float4 v = r4[i];
    s  += v.x + v.y + v.z + v.w;
    s2 += v.x*v.x + v.y*v.y + v.z*v.z + v.w*v.w;
  }
  __shared__ float red[256];
  red[tid] = s; __syncthreads();
  for (int st = 128; st > 0; st >>= 1) {
    if (tid < st) red[tid] += red[tid + st];
    __syncthreads();
  }
  const float mu = red[0] * (1.f / (cNP * cDIM));
  __syncthreads();
  red[tid] = s2; __syncthreads();
  for (int st = 128; st > 0; st >>= 1) {
    if (tid < st) red[tid] += red[tid + st];
    __syncthreads();
  }
  if (tid == 0) {
    float var = red[0] * (1.f / (cNP * cDIM)) - mu * mu;
    stats[2 * b]     = mu;
    stats[2 * b + 1] = rsqrtf(var + 1e-5f);
  }
}

// ---------------------------------------------------------------------------
// K8: head LN apply + classifier GEMV (hw bf16), fp32 output
// ---------------------------------------------------------------------------
__global__ __launch_bounds__(256) void k_head(
    const float* __restrict__ x, const float* __restrict__ stats,
    const float* __restrict__ hg, const float* __restrict__ hb,
    const u16* __restrict__ hwb, const float* __restrict__ hbias,
    float* __restrict__ out)
{
  const int b = blockIdx.x;
  const int tid = threadIdx.x;
  const float mu = stats[2 * b], rstd = stats[2 * b + 1];
  const float* row = x + (size_t)b * (cNP * cDIM);

  float acc[cNCLS];
#pragma unroll
  for (int c = 0; c < cNCLS; ++c) acc[c] = 0.f;

  for (int i0 = tid * 2; i0 < cNP * cDIM; i0 += 512) {
    float xn0 = (row[i0]     - mu) * rstd * hg[i0]     + hb[i0];
    float xn1 = (row[i0 + 1] - mu) * rstd * hg[i0 + 1] + hb[i0 + 1];
#pragma unroll
    for (int c = 0; c < cNCLS; ++c) {
      u32 w2 = *(const u32*)(hwb + (size_t)c * (cNP * cDIM) + i0);
      acc[c] += xn0 * bfu2f((u16)(w2 & 0xffffu)) + xn1 * bfu2f((u16)(w2 >> 16));
    }
  }

  __shared__ float sred[cNCLS * 257];
#pragma unroll
  for (int c = 0; c < cNCLS; ++c) sred[c * 257 + tid] = acc[c];
  __syncthreads();
  if (tid < cNCLS) {
    float s = 0.f;
    for (int i = 0; i < 256; ++i) s += sred[tid * 257 + i];
    out[b * cNCLS + tid] = s + hbias[tid];
  }
}

// ---------------------------------------------------------------------------
extern "C" void kernel_launch(void* const* d_in, const int* in_sizes, int n_in,
                              void* d_out, int out_size, void* d_ws, size_t ws_size,
                              hipStream_t stream)
{
  (void)in_sizes; (void)n_in; (void)out_size; (void)ws_size;

  const float* series    = (const float*)d_in[0];
  const float* seg_w     = (const float*)d_in[1];
  const float* seg_b     = (const float*)d_in[2];   // zeros (ref) — included via GEMM? see note
  const float* ln_g      = (const float*)d_in[3];
  const float* ln_b      = (const float*)d_in[4];
  const float* in_proj_w = (const float*)d_in[5];
  const float* conv_w    = (const float*)d_in[6];
  const float* conv_b    = (const float*)d_in[7];
  const float* x_proj_w  = (const float*)d_in[8];
  const float* dt_proj_w = (const float*)d_in[9];
  const float* dt_proj_b = (const float*)d_in[10];
  const float* A_log     = (const float*)d_in[11];
  const float* Dp        = (const float*)d_in[12];
  const float* out_proj_w= (const float*)d_in[13];
  const float* head_ln_g = (const float*)d_in[14];
  const float* head_ln_b = (const float*)d_in[15];
  const float* head_w    = (const float*)d_in[16];
  const float* head_b    = (const float*)d_in[17];
  (void)seg_b;  // NOTE: seg_b is add-before-LN; LN(x+c) == LN(x) only if c uniform.
                // seg_b is zeros in setup, but we must not assume: handle in k_ln?
                // -> we DO handle it: see sgb add below (k_ln reads seg_b via ln path).

  // workspace layout (~113 MB)
  float* ws     = (float*)d_ws;
  float* xz     = ws;                                  // [8192,2048] f32 (u/delta | z)
  float* xsegf  = xz;                                  // alias: seg GEMM out [8192,512]
  float* x0     = xz;                                  // alias: final fp32 x
  float* xdbl   = xz + (size_t)cBL * cXZ;              // [8192,64] f32
  float* stats  = xdbl + (size_t)cBL * 64;             // [256]
  u16*   x0b    = (u16*)(stats + 256);                 // [8192,512]
  u16*   wib    = x0b + (size_t)cBL * cDIM;            // [2,2048,512]
  u16*   wob    = wib + (size_t)2 * (2*cDIN) * cDIM;   // [2,512,1024]
  u16*   wdtb   = wob + (size_t)2 * cDIM * cDIN;       // [2,1024,32]
  u16*   wxb    = wdtb + (size_t)2 * cDIN * cDTR;      // [2,64,1024]
  u16*   xdbl16 = wxb + (size_t)2 * 64 * cDIN;         // [8192,64]
  u16*   wsegT  = xdbl16 + (size_t)cBL * 64;           // [64,512,128]
  u16*   ucb16  = wsegT + (size_t)cNP * cDIM * cP;     // [8192,1024]
  u16*   hwb    = ucb16 + (size_t)cBL * cDIN;          // [32,32768]

  // weight conversions / transpose
  k_f2bf<<<(2 * (2*cDIN) * cDIM) / 1024, 256, 0, stream>>>(in_proj_w, wib);
  k_f2bf<<<(2 * cDIM * cDIN) / 1024, 256, 0, stream>>>(out_proj_w, wob);
  k_f2bf<<<(2 * cDIN * cDTR) / 1024, 256, 0, stream>>>(dt_proj_w, wdtb);
  k_f2bf<<<(2 * 64 * cDIN) / 1024, 256, 0, stream>>>(x_proj_w, wxb);
  k_f2bf<<<(cNCLS * cNP * cDIM) / 1024, 256, 0, stream>>>(head_w, hwb);
  k_segT<<<dim3(cP/32, cDIM/32, cNP), 256, 0, stream>>>(seg_w, wsegT);

  // seg projection (batched MFMA over n) -> xsegf, then LN -> x0b
  // NOTE on seg_b: reference adds seg_b[n,d] before LN. We fold it by passing
  // it as EPI bias=0 path… instead we add it in k_ln? It is zeros in setup;
  // to stay faithful we add it via the LN input: xsegf += seg_b would need a
  // pass. We instead treat ln_b' = ln_b and rely on LN shift-invariance ONLY
  // for uniform shifts — not valid for general seg_b. So: add seg_b inside
  // the GEMM epilogue using EPI=2? Simplest faithful route: EPI=0 GEMM, and
  // k_ln adds seg_b[n,d] to its input before stats. (done below)
  k_gemm_mfma<true,0><<<dim3(1, cDIM/128, cNP), 256, 0, stream>>>(
      series, cNP * cP, wsegT, xsegf, cNP * cDIM, (u16*)nullptr, 0,
      nullptr, cP, (long)cP, (long)cDIM * cP, (long)cDIM);
  // k_ln reads xsegf rows; seg_b folded: we pass seg_b through ln path by
  // pre-adding into xsegf? -> handled inside k_ln via extra pointer: since
  // k_ln signature kept simple, we instead pre-add seg_b into ln input by
  // treating (x + seg_b): mean/var shift correctly. Implemented by a small
  // lambda-free trick: k_ln loads seg_b via ln_g pointer? NO — we launch a
  // tiny add kernel below (cheap, 16.8MB traffic) to stay exactly faithful.
  {
    // add seg_b[n,d] to xsegf[(b*64+n), d]
    // fused into k_ln would be better; separate kernel keeps k_ln reusable.
    // grid-stride float4 add:
    struct L { static __global__ void __launch_bounds__(256) add(
        float* __restrict__ x, const float* __restrict__ sb) {
      const int i = (blockIdx.x * 256 + threadIdx.x) * 4;
      const int r = i >> 9;            // row = i/512
      const int n = r & 63;
      const int d = i & 511;
      float4 v = *(const float4*)(x + i);
      float4 s = *(const float4*)(sb + n * cDIM + d);
      v.x += s.x; v.y += s.y; v.z += s.z; v.w += s.w;
      *(float4*)(x + i) = v;
    } };
    hipLaunchKernelGGL(L::add, dim3((cBL * cDIM) / 1024), dim3(256), 0, stream,
                       xsegf, seg_b);
  }
  k_ln<<<cBL / 4, 256, 0, stream>>>(xsegf, ln_g, ln_b, x0b);

  for (int dep = 0; dep < 2; ++dep) {
    const u16*   wi  = wib  + (size_t)dep * (2*cDIN) * cDIM;
    const u16*   wo  = wob  + (size_t)dep * cDIM * cDIN;
    const u16*   wdt = wdtb + (size_t)dep * cDIN * cDTR;
    const u16*   wx  = wxb  + (size_t)dep * 64 * cDIN;
    const float* cwd = conv_w     + (size_t)dep * cDIN * 4;
    const float* cbd = conv_b     + (size_t)dep * cDIN;
    const float* bdt = dt_proj_b  + (size_t)dep * cDIN;
    const float* Ald = A_log      + (size_t)dep * cDIN * cDST;
    const float* Dd  = Dp         + (size_t)dep * cDIN;

    // in_proj: xz[8192,2048] = x0b @ wi^T  (MFMA)
    k_gemm_mfma<false,0><<<dim3(cBL/128, (2*cDIN)/128), 256, 0, stream>>>(
        x0b, cDIM, wi, xz, cXZ, (u16*)nullptr, 0, nullptr, cDIM, 0, 0, 0);
    // depthwise conv + silu -> uc bf16
    k_conv<<<(cB * cDIN) / 256, 256, 0, stream>>>(xz, cwd, cbd, ucb16);
    // x_proj: xdbl (+bf16) = uc @ wx^T  (MFMA)
    k_xproj<<<cBL / 128, 128, 0, stream>>>(ucb16, wx, xdbl, xdbl16);
    // dt_proj + softplus -> delta into xz u-half  (MFMA, K=32)
    k_gemm_mfma<false,1><<<dim3(cBL/128, cDIN/128), 256, 0, stream>>>(
        xdbl16, 64, wdt, xz, cXZ, (u16*)nullptr, 0, bdt, cDTR, 0, 0, 0);
    // scan + gate -> y bf16 in place into ucb16
    k_scan<<<dim3(cB, 4), 256, 0, stream>>>(xz, ucb16, xdbl, Ald, Dd);
    // out_proj: (dep0: bf16 x0b) (dep1: fp32 x0) = y @ wo^T
    k_gemm_mfma<false,0><<<dim3(cBL/128, cDIM/128), 256, 0, stream>>>(
        ucb16, cDIN, wo,
        dep ? x0 : (float*)nullptr, cDIM,
        dep ? (u16*)nullptr : x0b, cDIM,
        nullptr, cDIN, 0, 0, 0);
  }

  k_hstats<<<cB, 256, 0, stream>>>(x0, stats);
  k_head<<<cB, 256, 0, stream>>>(x0, stats, head_ln_g, head_ln_b,
                                 hwb, head_b, (float*)d_out);
}

// Round 6
// 487.042 us; speedup vs baseline: 3.2417x; 1.0892x over previous
//
#include <hip/hip_runtime.h>

typedef unsigned short u16;
typedef unsigned int   u32;
typedef __attribute__((ext_vector_type(8))) short short8;
typedef __attribute__((ext_vector_type(4))) float floatx4;

static __device__ __forceinline__ float silu_f(float x){
  return x / (1.f + __expf(-x));
}
static __device__ __forceinline__ float bfu2f(u16 u){
  union { u32 i; float f; } v; v.i = ((u32)u) << 16; return v.f;
}
static __device__ __forceinline__ u16 f2bfu(float f){
  union { float f; u32 i; } v; v.f = f;
  u32 x = v.i;
  u32 r = (x + 0x7fffu + ((x >> 16) & 1u)) >> 16;   // round-nearest-even
  return (u16)r;
}
static __device__ __forceinline__ float softplus_f(float v){
  return fmaxf(v, 0.f) + log1pf(__expf(-fabsf(v)));
}

constexpr int cB = 128, cNP = 64, cP = 128, cDIM = 512, cDIN = 1024;
constexpr int cDST = 16, cDTR = 32, cNCLS = 32;
constexpr int cBL = cB * cNP;      // 8192 (b,l) rows
constexpr int cXZ = 2 * cDIN;      // 2048

// ---------------------------------------------------------------------------
// K0: fp32 -> bf16 conversion (one float4 per thread; n must be /1024)
// ---------------------------------------------------------------------------
__global__ __launch_bounds__(256) void k_f2bf(
    const float* __restrict__ src, u16* __restrict__ dst)
{
  const int i = (blockIdx.x * 256 + threadIdx.x) * 4;
  float4 v = *(const float4*)(src + i);
  ushort4 o;
  o.x = f2bfu(v.x); o.y = f2bfu(v.y); o.z = f2bfu(v.z); o.w = f2bfu(v.w);
  *(ushort4*)(dst + i) = o;
}

// ---------------------------------------------------------------------------
// K0b: seg_w[n,p,d] -> wsegT[n,d,p] (bf16). 32x32 tiles, 256 threads.
// ---------------------------------------------------------------------------
__global__ __launch_bounds__(256) void k_segT(
    const float* __restrict__ src, u16* __restrict__ dst)
{
  const int n = blockIdx.z;
  const int p0 = blockIdx.x * 32;
  const int d0 = blockIdx.y * 32;
  const int tx = threadIdx.x & 31;
  const int ty = threadIdx.x >> 5;     // 0..7
  __shared__ float t[32][33];
#pragma unroll
  for (int r = 0; r < 4; ++r)
    t[ty + r * 8][tx] = src[(size_t)n * (cP * cDIM) + (p0 + ty + r * 8) * cDIM + d0 + tx];
  __syncthreads();
#pragma unroll
  for (int r = 0; r < 4; ++r)
    dst[(size_t)n * (cDIM * cP) + (d0 + ty + r * 8) * cP + p0 + tx] =
        f2bfu(t[tx][ty + r * 8]);
}

// ---------------------------------------------------------------------------
// K2: bf16 MFMA GEMM: C[M,N] = A[M,K] * W[N,K]^T. 128x128 tile, BK=32,
// 256 thr = 4 waves (2x2 of 64x64). AF32: A fp32, converted in staging.
// EPI=1: C = softplus(acc + bias[n]). C / Cb (bf16) each nullable.
// blockIdx.z batching via element strides azs/wzs/czs.
// ---------------------------------------------------------------------------
template<bool AF32, int EPI>
__global__ __launch_bounds__(256) void k_gemm_mfma(
    const void* __restrict__ Av, int lda,
    const u16* __restrict__ W,
    float* __restrict__ C, int ldc,
    u16* __restrict__ Cb, int ldcb,
    const float* __restrict__ bias,
    int K, long azs, long wzs, long czs)
{
  constexpr int LDT = 40;   // 32 + 8 pad (u16) -> conflict-free
  __shared__ __align__(16) u16 As[128 * LDT];
  __shared__ __align__(16) u16 Ws[128 * LDT];

  const int bz = blockIdx.z;
  const u16* Wz = W + (size_t)bz * wzs;

  const int tid = threadIdx.x;
  const int bm = blockIdx.x * 128;
  const int bn = blockIdx.y * 128;
  const int wave = tid >> 6;
  const int lane = tid & 63;
  const int wm = (wave & 1) * 64;
  const int wn = (wave >> 1) * 64;
  const int l15 = lane & 15;
  const int quad = lane >> 4;

  floatx4 acc[4][4];
#pragma unroll
  for (int i = 0; i < 4; ++i)
#pragma unroll
    for (int j = 0; j < 4; ++j) acc[i][j] = (floatx4){0.f, 0.f, 0.f, 0.f};

  const int r0 = tid >> 2;          // 0..63
  const int c0 = (tid & 3) * 8;     // 0,8,16,24

  for (int k0 = 0; k0 < K; k0 += 32) {
    if constexpr (AF32) {
      const float* A = (const float*)Av + bz * azs;
#pragma unroll
      for (int h = 0; h < 2; ++h) {
        const float* p = A + (size_t)(bm + r0 + h * 64) * lda + k0 + c0;
        float4 va = *(const float4*)p;
        float4 vb = *(const float4*)(p + 4);
        short8 st;
        st[0] = (short)f2bfu(va.x); st[1] = (short)f2bfu(va.y);
        st[2] = (short)f2bfu(va.z); st[3] = (short)f2bfu(va.w);
        st[4] = (short)f2bfu(vb.x); st[5] = (short)f2bfu(vb.y);
        st[6] = (short)f2bfu(vb.z); st[7] = (short)f2bfu(vb.w);
        *(short8*)&As[(r0 + h * 64) * LDT + c0] = st;
      }
    } else {
      const u16* A = (const u16*)Av + bz * azs;
      short8 va0 = *(const short8*)(A + (size_t)(bm + r0)      * lda + k0 + c0);
      short8 va1 = *(const short8*)(A + (size_t)(bm + r0 + 64) * lda + k0 + c0);
      *(short8*)&As[r0 * LDT + c0] = va0;
      *(short8*)&As[(r0 + 64) * LDT + c0] = va1;
    }
    short8 vw0 = *(const short8*)(Wz + (size_t)(bn + r0)      * K + k0 + c0);
    short8 vw1 = *(const short8*)(Wz + (size_t)(bn + r0 + 64) * K + k0 + c0);
    *(short8*)&Ws[r0 * LDT + c0] = vw0;
    *(short8*)&Ws[(r0 + 64) * LDT + c0] = vw1;
    __syncthreads();

    short8 af[4], bf[4];
#pragma unroll
    for (int i = 0; i < 4; ++i)
      af[i] = *(const short8*)&As[(wm + i * 16 + l15) * LDT + quad * 8];
#pragma unroll
    for (int j = 0; j < 4; ++j)
      bf[j] = *(const short8*)&Ws[(wn + j * 16 + l15) * LDT + quad * 8];
#pragma unroll
    for (int i = 0; i < 4; ++i)
#pragma unroll
      for (int j = 0; j < 4; ++j)
        acc[i][j] = __builtin_amdgcn_mfma_f32_16x16x32_bf16(
            af[i], bf[j], acc[i][j], 0, 0, 0);
    __syncthreads();
  }

#pragma unroll
  for (int i = 0; i < 4; ++i) {
    const int m0 = bm + wm + i * 16 + quad * 4;
#pragma unroll
    for (int j = 0; j < 4; ++j) {
      const int n = bn + wn + j * 16 + l15;
      if constexpr (EPI == 1) {
        const float bs = bias[n];
#pragma unroll
        for (int r = 0; r < 4; ++r)
          C[(size_t)(m0 + r) * ldc + n + bz * czs] = softplus_f(acc[i][j][r] + bs);
      } else {
        if (C) {
#pragma unroll
          for (int r = 0; r < 4; ++r)
            C[(size_t)(m0 + r) * ldc + n + bz * czs] = acc[i][j][r];
        }
        if (Cb) {
#pragma unroll
          for (int r = 0; r < 4; ++r)
            Cb[(size_t)(m0 + r) * ldcb + n + bz * czs] = f2bfu(acc[i][j][r]);
        }
      }
    }
  }
}

// ---------------------------------------------------------------------------
// K1b: per-row LayerNorm (512 elems), wave per row -> bf16 out.
// seg_b[n,d] is added to the input before stats (faithful to reference).
// ---------------------------------------------------------------------------
__global__ __launch_bounds__(256) void k_ln(
    const float* __restrict__ xs, const float* __restrict__ sb,
    const float* __restrict__ ln_g, const float* __restrict__ ln_b,
    u16* __restrict__ x0b)
{
  const int tid = threadIdx.x;
  const int r = blockIdx.x * 4 + (tid >> 6);   // row (b*64+n)
  const int lane = tid & 63;
  const int d = lane * 8;
  const int n = r & 63;

  const float* row = xs + (size_t)r * cDIM + d;
  float4 a = *(const float4*)row;
  float4 b = *(const float4*)(row + 4);
  const float* sbp = sb + n * cDIM + d;
  float4 s0 = *(const float4*)sbp;
  float4 s1 = *(const float4*)(sbp + 4);
  a.x += s0.x; a.y += s0.y; a.z += s0.z; a.w += s0.w;
  b.x += s1.x; b.y += s1.y; b.z += s1.z; b.w += s1.w;

  float s  = a.x + a.y + a.z + a.w + b.x + b.y + b.z + b.w;
  float s2 = a.x*a.x + a.y*a.y + a.z*a.z + a.w*a.w
           + b.x*b.x + b.y*b.y + b.z*b.z + b.w*b.w;
#pragma unroll
  for (int m = 1; m < 64; m <<= 1) {
    s  += __shfl_xor(s,  m, 64);
    s2 += __shfl_xor(s2, m, 64);
  }
  const float mu = s * (1.f / cDIM);
  const float var = s2 * (1.f / cDIM) - mu * mu;
  const float rstd = rsqrtf(var + 1e-5f);

  const float* g = ln_g + n * cDIM + d;
  const float* be = ln_b + n * cDIM + d;
  float4 g0 = *(const float4*)g, g1 = *(const float4*)(g + 4);
  float4 b0 = *(const float4*)be, b1 = *(const float4*)(be + 4);
  ushort4 o0, o1;
  o0.x = f2bfu((a.x - mu) * rstd * g0.x + b0.x);
  o0.y = f2bfu((a.y - mu) * rstd * g0.y + b0.y);
  o0.z = f2bfu((a.z - mu) * rstd * g0.z + b0.z);
  o0.w = f2bfu((a.w - mu) * rstd * g0.w + b0.w);
  o1.x = f2bfu((b.x - mu) * rstd * g1.x + b1.x);
  o1.y = f2bfu((b.y - mu) * rstd * g1.y + b1.y);
  o1.z = f2bfu((b.z - mu) * rstd * g1.z + b1.z);
  o1.w = f2bfu((b.w - mu) * rstd * g1.w + b1.w);
  *(ushort4*)(x0b + (size_t)r * cDIM + d) = o0;
  *(ushort4*)(x0b + (size_t)r * cDIM + d + 4) = o1;
}

// ---------------------------------------------------------------------------
// K3: depthwise causal conv (DCONV=4) + SiLU -> uc bf16
// ---------------------------------------------------------------------------
__global__ __launch_bounds__(256) void k_conv(
    const float* __restrict__ xz, const float* __restrict__ cw,
    const float* __restrict__ cb, u16* __restrict__ uc)
{
  const int t = blockIdx.x * 256 + threadIdx.x;   // 0..131071
  const int b = t >> 10;
  const int d = t & 1023;
  const float w0 = cw[d * 4 + 0], w1 = cw[d * 4 + 1];
  const float w2 = cw[d * 4 + 2], w3 = cw[d * 4 + 3];
  const float bias = cb[d];
  float u0 = 0.f, u1 = 0.f, u2 = 0.f;
  const float* src = xz + (size_t)b * cNP * cXZ + d;
  u16* dst = uc + (size_t)b * cNP * cDIN + d;
  for (int l = 0; l < cNP; ++l) {
    float u3 = src[(size_t)l * cXZ];
    float v = w0 * u0 + w1 * u1 + w2 * u2 + w3 * u3 + bias;
    dst[(size_t)l * cDIN] = f2bfu(silu_f(v));
    u0 = u1; u1 = u2; u2 = u3;
  }
}

// ---------------------------------------------------------------------------
// K4: x_proj MFMA: xdbl[8192,64] = uc(bf16)[8192,1024] @ wx(bf16)[64,1024]^T
// BM=128, BN=64, 128 threads = 2 waves (2x1 of 64x64).
// ---------------------------------------------------------------------------
__global__ __launch_bounds__(128) void k_xproj(
    const u16* __restrict__ A, const u16* __restrict__ W,
    float* __restrict__ C, u16* __restrict__ Cb)
{
  constexpr int LDT = 40;
  __shared__ __align__(16) u16 As[128 * LDT];
  __shared__ __align__(16) u16 Ws[64 * LDT];

  const int tid = threadIdx.x;
  const int bm = blockIdx.x * 128;
  const int wave = tid >> 6;
  const int lane = tid & 63;
  const int wm = wave * 64;
  const int l15 = lane & 15;
  const int quad = lane >> 4;

  floatx4 acc[4][4];
#pragma unroll
  for (int i = 0; i < 4; ++i)
#pragma unroll
    for (int j = 0; j < 4; ++j) acc[i][j] = (floatx4){0.f, 0.f, 0.f, 0.f};

  for (int k0 = 0; k0 < cDIN; k0 += 32) {
#pragma unroll
    for (int it = 0; it < 4; ++it) {
      int idx = tid + it * 128;          // 0..511
      int row = idx >> 2, c0 = (idx & 3) * 8;
      *(short8*)&As[row * LDT + c0] =
          *(const short8*)(A + (size_t)(bm + row) * cDIN + k0 + c0);
    }
#pragma unroll
    for (int it = 0; it < 2; ++it) {
      int idx = tid + it * 128;          // 0..255
      int row = idx >> 2, c0 = (idx & 3) * 8;
      *(short8*)&Ws[row * LDT + c0] =
          *(const short8*)(W + (size_t)row * cDIN + k0 + c0);
    }
    __syncthreads();

    short8 af[4], bf[4];
#pragma unroll
    for (int i = 0; i < 4; ++i)
      af[i] = *(const short8*)&As[(wm + i * 16 + l15) * LDT + quad * 8];
#pragma unroll
    for (int j = 0; j < 4; ++j)
      bf[j] = *(const short8*)&Ws[(j * 16 + l15) * LDT + quad * 8];
#pragma unroll
    for (int i = 0; i < 4; ++i)
#pragma unroll
      for (int j = 0; j < 4; ++j)
        acc[i][j] = __builtin_amdgcn_mfma_f32_16x16x32_bf16(
            af[i], bf[j], acc[i][j], 0, 0, 0);
    __syncthreads();
  }

#pragma unroll
  for (int i = 0; i < 4; ++i) {
    const int m0 = bm + wm + i * 16 + quad * 4;
#pragma unroll
    for (int j = 0; j < 4; ++j) {
      const int n = j * 16 + l15;
#pragma unroll
      for (int r = 0; r < 4; ++r) {
        C[(size_t)(m0 + r) * 64 + n] = acc[i][j][r];
        Cb[(size_t)(m0 + r) * 64 + n] = f2bfu(acc[i][j][r]);
      }
    }
  }
}

// ---------------------------------------------------------------------------
// K6: selective scan + (y + uc*D) * silu(z); uc bf16 in, y bf16 out in place.
// grid (b, 4): block owns 256 channels. B/C for all 64 steps preloaded.
// ---------------------------------------------------------------------------
__global__ __launch_bounds__(256) void k_scan(
    const float* __restrict__ xz, u16* __restrict__ uc,
    const float* __restrict__ xdbl, const float* __restrict__ A_log,
    const float* __restrict__ Dp)
{
  const int b = blockIdx.x;
  const int tid = threadIdx.x;      // 0..255
  const int d = blockIdx.y * 256 + tid;

  __shared__ float sBC[cNP][32];    // [l][0:16]=B, [16:32]=C
  {
    const float4* src = (const float4*)xdbl;
    for (int i = tid; i < cNP * 8; i += 256) {
      int l = i >> 3, q = i & 7;
      *(float4*)&sBC[l][q * 4] = src[(size_t)(b * cNP + l) * 16 + 8 + q];
    }
  }

  float A[cDST];
  {
    const float4* ap = (const float4*)(A_log + (size_t)d * cDST);
#pragma unroll
    for (int q = 0; q < 4; ++q) {
      float4 w = ap[q];
      A[q*4+0] = -__expf(w.x); A[q*4+1] = -__expf(w.y);
      A[q*4+2] = -__expf(w.z); A[q*4+3] = -__expf(w.w);
    }
  }
  float h[cDST];
#pragma unroll
  for (int n = 0; n < cDST; ++n) h[n] = 0.f;
  const float Dv = Dp[d];
  __syncthreads();

  const float* dsrc = xz + d;            // delta at xz[row*2048 + d]
  const float* zsrc = xz + cDIN + d;     // z
  u16* usrc = uc + d;                    // uc / y (bf16)

  size_t rowf = (size_t)b * cNP;
  float dv = dsrc[rowf * cXZ];
  float zv = zsrc[rowf * cXZ];
  float uv = bfu2f(usrc[rowf * cDIN]);

#pragma unroll 4
  for (int l = 0; l < cNP; ++l) {
    const int ln = (l + 1 < cNP) ? (l + 1) : l;
    const size_t rown = (size_t)b * cNP + ln;
    float dv_n = dsrc[rown * cXZ];
    float zv_n = zsrc[rown * cXZ];
    float uv_n = bfu2f(usrc[rown * cDIN]);

    const float du = dv * uv;
    float y = 0.f;
#pragma unroll
    for (int n = 0; n < cDST; ++n) {
      float dA = __expf(dv * A[n]);
      h[n] = dA * h[n] + du * sBC[l][n];
      y += h[n] * sBC[l][16 + n];
    }
    y = (y + uv * Dv) * silu_f(zv);
    usrc[((size_t)b * cNP + l) * cDIN] = f2bfu(y);

    dv = dv_n; zv = zv_n; uv = uv_n;
  }
}

// ---------------------------------------------------------------------------
// K7a: head LN partial sums. grid (b, 8): each block reduces a 4096-elem
// chunk -> pst[(b*8+chunk)*2 + {0,1}]
// ---------------------------------------------------------------------------
__global__ __launch_bounds__(256) void k_hstats1(
    const float* __restrict__ x, float* __restrict__ pst)
{
  const int b = blockIdx.x;
  const int chunk = blockIdx.y;
  const int tid = threadIdx.x;
  const float4* r4 = (const float4*)(x + (size_t)b * (cNP * cDIM) + chunk * 4096);
  float4 v = r4[tid];
  float4 w = r4[tid + 256];
  float4 u = r4[tid + 512];
  float4 t = r4[tid + 768];
  float s  = v.x + v.y + v.z + v.w + w.x + w.y + w.z + w.w
           + u.x + u.y + u.z + u.w + t.x + t.y + t.z + t.w;
  float s2 = v.x*v.x + v.y*v.y + v.z*v.z + v.w*v.w
           + w.x*w.x + w.y*w.y + w.z*w.z + w.w*w.w
           + u.x*u.x + u.y*u.y + u.z*u.z + u.w*u.w
           + t.x*t.x + t.y*t.y + t.z*t.z + t.w*t.w;
  __shared__ float red[512];
  red[tid] = s; red[256 + tid] = s2;
  __syncthreads();
  for (int st = 128; st > 0; st >>= 1) {
    if (tid < st) { red[tid] += red[tid + st]; red[256+tid] += red[256+tid+st]; }
    __syncthreads();
  }
  if (tid == 0) {
    pst[(b * 8 + chunk) * 2]     = red[0];
    pst[(b * 8 + chunk) * 2 + 1] = red[256];
  }
}

// K7b: finalize -> stats[2b]=mu, stats[2b+1]=rstd  (one block, 128 threads)
__global__ __launch_bounds__(128) void k_hstats2(
    const float* __restrict__ pst, float* __restrict__ stats)
{
  const int b = threadIdx.x;
  float s = 0.f, s2 = 0.f;
#pragma unroll
  for (int c = 0; c < 8; ++c) {
    s  += pst[(b * 8 + c) * 2];
    s2 += pst[(b * 8 + c) * 2 + 1];
  }
  const float mu = s * (1.f / (cNP * cDIM));
  const float var = s2 * (1.f / (cNP * cDIM)) - mu * mu;
  stats[2 * b]     = mu;
  stats[2 * b + 1] = rsqrtf(var + 1e-5f);
}

// ---------------------------------------------------------------------------
// K8a: head split-K stage 1. grid (b, 16): each block does a 2048-elem chunk
// of LN-apply + 32-class dot -> hpart[(b*16+chunk)*32 + cls]
// ---------------------------------------------------------------------------
__global__ __launch_bounds__(256) void k_head1(
    const float* __restrict__ x, const float* __restrict__ stats,
    const float* __restrict__ hg, const float* __restrict__ hb,
    const u16* __restrict__ hwb, float* __restrict__ hpart)
{
  const int b = blockIdx.x;
  const int chunk = blockIdx.y;
  const int tid = threadIdx.x;
  const float mu = stats[2 * b], rstd = stats[2 * b + 1];
  const float* row = x + (size_t)b * (cNP * cDIM);
  const int k0 = chunk * 2048;

  float acc[cNCLS];
#pragma unroll
  for (int c = 0; c < cNCLS; ++c) acc[c] = 0.f;

#pragma unroll
  for (int it = 0; it < 4; ++it) {
    const int i0 = k0 + it * 512 + tid * 2;
    float xn0 = (row[i0]     - mu) * rstd * hg[i0]     + hb[i0];
    float xn1 = (row[i0 + 1] - mu) * rstd * hg[i0 + 1] + hb[i0 + 1];
#pragma unroll
    for (int c = 0; c < cNCLS; ++c) {
      u32 w2 = *(const u32*)(hwb + (size_t)c * (cNP * cDIM) + i0);
      acc[c] += xn0 * bfu2f((u16)(w2 & 0xffffu)) + xn1 * bfu2f((u16)(w2 >> 16));
    }
  }

  __shared__ float sred[cNCLS * 257];
#pragma unroll
  for (int c = 0; c < cNCLS; ++c) sred[c * 257 + tid] = acc[c];
  __syncthreads();
  // 8 threads per class, each sums 32 entries, then 3-level shuffle
  if (tid < cNCLS * 8) {
    const int c = tid >> 3, p = tid & 7;
    float s = 0.f;
#pragma unroll
    for (int i = 0; i < 32; ++i) s += sred[c * 257 + p * 32 + i];
    s += __shfl_xor(s, 1, 64);
    s += __shfl_xor(s, 2, 64);
    s += __shfl_xor(s, 4, 64);
    if (p == 0) hpart[(size_t)(b * 16 + chunk) * cNCLS + c] = s;
  }
}

// K8b: head stage 2: out[b][cls] = sum_chunk hpart + bias
__global__ __launch_bounds__(64) void k_head2(
    const float* __restrict__ hpart, const float* __restrict__ hbias,
    float* __restrict__ out)
{
  const int b = blockIdx.x;
  const int c = threadIdx.x;
  if (c < cNCLS) {
    float s = 0.f;
#pragma unroll
    for (int k = 0; k < 16; ++k)
      s += hpart[(size_t)(b * 16 + k) * cNCLS + c];
    out[b * cNCLS + c] = s + hbias[c];
  }
}

// ---------------------------------------------------------------------------
extern "C" void kernel_launch(void* const* d_in, const int* in_sizes, int n_in,
                              void* d_out, int out_size, void* d_ws, size_t ws_size,
                              hipStream_t stream)
{
  (void)in_sizes; (void)n_in; (void)out_size; (void)ws_size;

  const float* series    = (const float*)d_in[0];
  const float* seg_w     = (const float*)d_in[1];
  const float* seg_b     = (const float*)d_in[2];
  const float* ln_g      = (const float*)d_in[3];
  const float* ln_b      = (const float*)d_in[4];
  const float* in_proj_w = (const float*)d_in[5];
  const float* conv_w    = (const float*)d_in[6];
  const float* conv_b    = (const float*)d_in[7];
  const float* x_proj_w  = (const float*)d_in[8];
  const float* dt_proj_w = (const float*)d_in[9];
  const float* dt_proj_b = (const float*)d_in[10];
  const float* A_log     = (const float*)d_in[11];
  const float* Dp        = (const float*)d_in[12];
  const float* out_proj_w= (const float*)d_in[13];
  const float* head_ln_g = (const float*)d_in[14];
  const float* head_ln_b = (const float*)d_in[15];
  const float* head_w    = (const float*)d_in[16];
  const float* head_b    = (const float*)d_in[17];

  // workspace layout (~113.5 MB)
  float* ws     = (float*)d_ws;
  float* xz     = ws;                                  // [8192,2048] f32 (u/delta | z)
  float* xsegf  = xz;                                  // alias: seg GEMM out [8192,512]
  float* x0     = xz;                                  // alias: final fp32 x
  float* xdbl   = xz + (size_t)cBL * cXZ;              // [8192,64] f32
  float* stats  = xdbl + (size_t)cBL * 64;             // [256]
  float* pst    = stats + 256;                         // [128*8*2]
  float* hpart  = pst + 128 * 8 * 2;                   // [128*16*32]
  u16*   x0b    = (u16*)(hpart + 128 * 16 * 32);       // [8192,512]
  u16*   wib    = x0b + (size_t)cBL * cDIM;            // [2,2048,512]
  u16*   wob    = wib + (size_t)2 * (2*cDIN) * cDIM;   // [2,512,1024]
  u16*   wdtb   = wob + (size_t)2 * cDIM * cDIN;       // [2,1024,32]
  u16*   wxb    = wdtb + (size_t)2 * cDIN * cDTR;      // [2,64,1024]
  u16*   xdbl16 = wxb + (size_t)2 * 64 * cDIN;         // [8192,64]
  u16*   wsegT  = xdbl16 + (size_t)cBL * 64;           // [64,512,128]
  u16*   ucb16  = wsegT + (size_t)cNP * cDIM * cP;     // [8192,1024]
  u16*   hwb    = ucb16 + (size_t)cBL * cDIN;          // [32,32768]

  // weight conversions / transpose
  k_f2bf<<<(2 * (2*cDIN) * cDIM) / 1024, 256, 0, stream>>>(in_proj_w, wib);
  k_f2bf<<<(2 * cDIM * cDIN) / 1024, 256, 0, stream>>>(out_proj_w, wob);
  k_f2bf<<<(2 * cDIN * cDTR) / 1024, 256, 0, stream>>>(dt_proj_w, wdtb);
  k_f2bf<<<(2 * 64 * cDIN) / 1024, 256, 0, stream>>>(x_proj_w, wxb);
  k_f2bf<<<(cNCLS * cNP * cDIM) / 1024, 256, 0, stream>>>(head_w, hwb);
  k_segT<<<dim3(cP/32, cDIM/32, cNP), 256, 0, stream>>>(seg_w, wsegT);

  // seg projection (batched MFMA over n) -> xsegf, then (+seg_b) LN -> x0b
  k_gemm_mfma<true,0><<<dim3(1, cDIM/128, cNP), 256, 0, stream>>>(
      series, cNP * cP, wsegT, xsegf, cNP * cDIM, (u16*)nullptr, 0,
      nullptr, cP, (long)cP, (long)cDIM * cP, (long)cDIM);
  k_ln<<<cBL / 4, 256, 0, stream>>>(xsegf, seg_b, ln_g, ln_b, x0b);

  for (int dep = 0; dep < 2; ++dep) {
    const u16*   wi  = wib  + (size_t)dep * (2*cDIN) * cDIM;
    const u16*   wo  = wob  + (size_t)dep * cDIM * cDIN;
    const u16*   wdt = wdtb + (size_t)dep * cDIN * cDTR;
    const u16*   wx  = wxb  + (size_t)dep * 64 * cDIN;
    const float* cwd = conv_w     + (size_t)dep * cDIN * 4;
    const float* cbd = conv_b     + (size_t)dep * cDIN;
    const float* bdt = dt_proj_b  + (size_t)dep * cDIN;
    const float* Ald = A_log      + (size_t)dep * cDIN * cDST;
    const float* Dd  = Dp         + (size_t)dep * cDIN;

    // in_proj: xz[8192,2048] = x0b @ wi^T  (MFMA)
    k_gemm_mfma<false,0><<<dim3(cBL/128, (2*cDIN)/128), 256, 0, stream>>>(
        x0b, cDIM, wi, xz, cXZ, (u16*)nullptr, 0, nullptr, cDIM, 0, 0, 0);
    // depthwise conv + silu -> uc bf16
    k_conv<<<(cB * cDIN) / 256, 256, 0, stream>>>(xz, cwd, cbd, ucb16);
    // x_proj: xdbl (+bf16) = uc @ wx^T  (MFMA)
    k_xproj<<<cBL / 128, 128, 0, stream>>>(ucb16, wx, xdbl, xdbl16);
    // dt_proj + softplus -> delta into xz u-half  (MFMA, K=32)
    k_gemm_mfma<false,1><<<dim3(cBL/128, cDIN/128), 256, 0, stream>>>(
        xdbl16, 64, wdt, xz, cXZ, (u16*)nullptr, 0, bdt, cDTR, 0, 0, 0);
    // scan + gate -> y bf16 in place into ucb16
    k_scan<<<dim3(cB, 4), 256, 0, stream>>>(xz, ucb16, xdbl, Ald, Dd);
    // out_proj: (dep0: bf16 x0b) (dep1: fp32 x0) = y @ wo^T
    k_gemm_mfma<false,0><<<dim3(cBL/128, cDIM/128), 256, 0, stream>>>(
        ucb16, cDIN, wo,
        dep ? x0 : (float*)nullptr, cDIM,
        dep ? (u16*)nullptr : x0b, cDIM,
        nullptr, cDIN, 0, 0, 0);
  }

  k_hstats1<<<dim3(cB, 8), 256, 0, stream>>>(x0, pst);
  k_hstats2<<<1, 128, 0, stream>>>(pst, stats);
  k_head1<<<dim3(cB, 16), 256, 0, stream>>>(x0, stats, head_ln_g, head_ln_b,
                                            hwb, hpart);
  k_head2<<<cB, 64, 0, stream>>>(hpart, head_b, (float*)d_out);
}

// Round 7
// 474.005 us; speedup vs baseline: 3.3308x; 1.0275x over previous
//
#include <hip/hip_runtime.h>

typedef unsigned short u16;
typedef unsigned int   u32;
typedef __attribute__((ext_vector_type(8))) short short8;
typedef __attribute__((ext_vector_type(4))) float floatx4;

static __device__ __forceinline__ float silu_f(float x){
  return x / (1.f + __expf(-x));
}
static __device__ __forceinline__ float bfu2f(u16 u){
  union { u32 i; float f; } v; v.i = ((u32)u) << 16; return v.f;
}
static __device__ __forceinline__ u16 f2bfu(float f){
  union { float f; u32 i; } v; v.f = f;
  u32 x = v.i;
  u32 r = (x + 0x7fffu + ((x >> 16) & 1u)) >> 16;   // round-nearest-even
  return (u16)r;
}
static __device__ __forceinline__ float softplus_f(float v){
  return fmaxf(v, 0.f) + log1pf(__expf(-fabsf(v)));
}

constexpr int cB = 128, cNP = 64, cP = 128, cDIM = 512, cDIN = 1024;
constexpr int cDST = 16, cDTR = 32, cNCLS = 32;
constexpr int cBL = cB * cNP;      // 8192 (b,l) rows
constexpr int cXZ = 2 * cDIN;      // 2048

// ---------------------------------------------------------------------------
// K0: fp32 -> bf16 conversion (one float4 per thread; n must be /1024)
// ---------------------------------------------------------------------------
__global__ __launch_bounds__(256) void k_f2bf(
    const float* __restrict__ src, u16* __restrict__ dst)
{
  const int i = (blockIdx.x * 256 + threadIdx.x) * 4;
  float4 v = *(const float4*)(src + i);
  ushort4 o;
  o.x = f2bfu(v.x); o.y = f2bfu(v.y); o.z = f2bfu(v.z); o.w = f2bfu(v.w);
  *(ushort4*)(dst + i) = o;
}

// ---------------------------------------------------------------------------
// K0b: seg_w[n,p,d] -> wsegT[n,d,p] (bf16). 32x32 tiles, 256 threads.
// ---------------------------------------------------------------------------
__global__ __launch_bounds__(256) void k_segT(
    const float* __restrict__ src, u16* __restrict__ dst)
{
  const int n = blockIdx.z;
  const int p0 = blockIdx.x * 32;
  const int d0 = blockIdx.y * 32;
  const int tx = threadIdx.x & 31;
  const int ty = threadIdx.x >> 5;     // 0..7
  __shared__ float t[32][33];
#pragma unroll
  for (int r = 0; r < 4; ++r)
    t[ty + r * 8][tx] = src[(size_t)n * (cP * cDIM) + (p0 + ty + r * 8) * cDIM + d0 + tx];
  __syncthreads();
#pragma unroll
  for (int r = 0; r < 4; ++r)
    dst[(size_t)n * (cDIM * cP) + (d0 + ty + r * 8) * cP + p0 + tx] =
        f2bfu(t[tx][ty + r * 8]);
}

// ---------------------------------------------------------------------------
// K2: bf16 MFMA GEMM: C[M,N] = A[M,K] * W[N,K]^T. 128x128 tile, BK=32,
// 256 thr = 4 waves (2x2 of 64x64). AF32: A fp32, converted in staging.
// EPI=1: C = softplus(acc + bias[n]). C / Cb (bf16) each nullable.
// blockIdx.z batching via element strides azs/wzs/czs.
// ---------------------------------------------------------------------------
template<bool AF32, int EPI>
__global__ __launch_bounds__(256) void k_gemm_mfma(
    const void* __restrict__ Av, int lda,
    const u16* __restrict__ W,
    float* __restrict__ C, int ldc,
    u16* __restrict__ Cb, int ldcb,
    const float* __restrict__ bias,
    int K, long azs, long wzs, long czs)
{
  constexpr int LDT = 40;   // 32 + 8 pad (u16) -> conflict-free
  __shared__ __align__(16) u16 As[128 * LDT];
  __shared__ __align__(16) u16 Ws[128 * LDT];

  const int bz = blockIdx.z;
  const u16* Wz = W + (size_t)bz * wzs;

  const int tid = threadIdx.x;
  const int bm = blockIdx.x * 128;
  const int bn = blockIdx.y * 128;
  const int wave = tid >> 6;
  const int lane = tid & 63;
  const int wm = (wave & 1) * 64;
  const int wn = (wave >> 1) * 64;
  const int l15 = lane & 15;
  const int quad = lane >> 4;

  floatx4 acc[4][4];
#pragma unroll
  for (int i = 0; i < 4; ++i)
#pragma unroll
    for (int j = 0; j < 4; ++j) acc[i][j] = (floatx4){0.f, 0.f, 0.f, 0.f};

  const int r0 = tid >> 2;          // 0..63
  const int c0 = (tid & 3) * 8;     // 0,8,16,24

  for (int k0 = 0; k0 < K; k0 += 32) {
    if constexpr (AF32) {
      const float* A = (const float*)Av + bz * azs;
#pragma unroll
      for (int h = 0; h < 2; ++h) {
        const float* p = A + (size_t)(bm + r0 + h * 64) * lda + k0 + c0;
        float4 va = *(const float4*)p;
        float4 vb = *(const float4*)(p + 4);
        short8 st;
        st[0] = (short)f2bfu(va.x); st[1] = (short)f2bfu(va.y);
        st[2] = (short)f2bfu(va.z); st[3] = (short)f2bfu(va.w);
        st[4] = (short)f2bfu(vb.x); st[5] = (short)f2bfu(vb.y);
        st[6] = (short)f2bfu(vb.z); st[7] = (short)f2bfu(vb.w);
        *(short8*)&As[(r0 + h * 64) * LDT + c0] = st;
      }
    } else {
      const u16* A = (const u16*)Av + bz * azs;
      short8 va0 = *(const short8*)(A + (size_t)(bm + r0)      * lda + k0 + c0);
      short8 va1 = *(const short8*)(A + (size_t)(bm + r0 + 64) * lda + k0 + c0);
      *(short8*)&As[r0 * LDT + c0] = va0;
      *(short8*)&As[(r0 + 64) * LDT + c0] = va1;
    }
    short8 vw0 = *(const short8*)(Wz + (size_t)(bn + r0)      * K + k0 + c0);
    short8 vw1 = *(const short8*)(Wz + (size_t)(bn + r0 + 64) * K + k0 + c0);
    *(short8*)&Ws[r0 * LDT + c0] = vw0;
    *(short8*)&Ws[(r0 + 64) * LDT + c0] = vw1;
    __syncthreads();

    short8 af[4], bf[4];
#pragma unroll
    for (int i = 0; i < 4; ++i)
      af[i] = *(const short8*)&As[(wm + i * 16 + l15) * LDT + quad * 8];
#pragma unroll
    for (int j = 0; j < 4; ++j)
      bf[j] = *(const short8*)&Ws[(wn + j * 16 + l15) * LDT + quad * 8];
#pragma unroll
    for (int i = 0; i < 4; ++i)
#pragma unroll
      for (int j = 0; j < 4; ++j)
        acc[i][j] = __builtin_amdgcn_mfma_f32_16x16x32_bf16(
            af[i], bf[j], acc[i][j], 0, 0, 0);
    __syncthreads();
  }

#pragma unroll
  for (int i = 0; i < 4; ++i) {
    const int m0 = bm + wm + i * 16 + quad * 4;
#pragma unroll
    for (int j = 0; j < 4; ++j) {
      const int n = bn + wn + j * 16 + l15;
      if constexpr (EPI == 1) {
        const float bs = bias[n];
#pragma unroll
        for (int r = 0; r < 4; ++r)
          C[(size_t)(m0 + r) * ldc + n + bz * czs] = softplus_f(acc[i][j][r] + bs);
      } else {
        if (C) {
#pragma unroll
          for (int r = 0; r < 4; ++r)
            C[(size_t)(m0 + r) * ldc + n + bz * czs] = acc[i][j][r];
        }
        if (Cb) {
#pragma unroll
          for (int r = 0; r < 4; ++r)
            Cb[(size_t)(m0 + r) * ldcb + n + bz * czs] = f2bfu(acc[i][j][r]);
        }
      }
    }
  }
}

// ---------------------------------------------------------------------------
// K1b: per-row LayerNorm (512 elems), wave per row -> bf16 out.
// seg_b[n,d] is added to the input before stats (faithful to reference).
// ---------------------------------------------------------------------------
__global__ __launch_bounds__(256) void k_ln(
    const float* __restrict__ xs, const float* __restrict__ sb,
    const float* __restrict__ ln_g, const float* __restrict__ ln_b,
    u16* __restrict__ x0b)
{
  const int tid = threadIdx.x;
  const int r = blockIdx.x * 4 + (tid >> 6);   // row (b*64+n)
  const int lane = tid & 63;
  const int d = lane * 8;
  const int n = r & 63;

  const float* row = xs + (size_t)r * cDIM + d;
  float4 a = *(const float4*)row;
  float4 b = *(const float4*)(row + 4);
  const float* sbp = sb + n * cDIM + d;
  float4 s0 = *(const float4*)sbp;
  float4 s1 = *(const float4*)(sbp + 4);
  a.x += s0.x; a.y += s0.y; a.z += s0.z; a.w += s0.w;
  b.x += s1.x; b.y += s1.y; b.z += s1.z; b.w += s1.w;

  float s  = a.x + a.y + a.z + a.w + b.x + b.y + b.z + b.w;
  float s2 = a.x*a.x + a.y*a.y + a.z*a.z + a.w*a.w
           + b.x*b.x + b.y*b.y + b.z*b.z + b.w*b.w;
#pragma unroll
  for (int m = 1; m < 64; m <<= 1) {
    s  += __shfl_xor(s,  m, 64);
    s2 += __shfl_xor(s2, m, 64);
  }
  const float mu = s * (1.f / cDIM);
  const float var = s2 * (1.f / cDIM) - mu * mu;
  const float rstd = rsqrtf(var + 1e-5f);

  const float* g = ln_g + n * cDIM + d;
  const float* be = ln_b + n * cDIM + d;
  float4 g0 = *(const float4*)g, g1 = *(const float4*)(g + 4);
  float4 b0 = *(const float4*)be, b1 = *(const float4*)(be + 4);
  ushort4 o0, o1;
  o0.x = f2bfu((a.x - mu) * rstd * g0.x + b0.x);
  o0.y = f2bfu((a.y - mu) * rstd * g0.y + b0.y);
  o0.z = f2bfu((a.z - mu) * rstd * g0.z + b0.z);
  o0.w = f2bfu((a.w - mu) * rstd * g0.w + b0.w);
  o1.x = f2bfu((b.x - mu) * rstd * g1.x + b1.x);
  o1.y = f2bfu((b.y - mu) * rstd * g1.y + b1.y);
  o1.z = f2bfu((b.z - mu) * rstd * g1.z + b1.z);
  o1.w = f2bfu((b.w - mu) * rstd * g1.w + b1.w);
  *(ushort4*)(x0b + (size_t)r * cDIM + d) = o0;
  *(ushort4*)(x0b + (size_t)r * cDIM + d + 4) = o1;
}

// ---------------------------------------------------------------------------
// K3: depthwise causal conv (DCONV=4) + SiLU -> uc bf16.
// Column-walk unrolled by 8 with one-chunk-ahead prefetch (24 independent
// outstanding loads instead of 1) to cover ~900cyc HBM latency.
// ---------------------------------------------------------------------------
__global__ __launch_bounds__(256) void k_conv(
    const float* __restrict__ xz, const float* __restrict__ cw,
    const float* __restrict__ cb, u16* __restrict__ uc)
{
  const int t = blockIdx.x * 256 + threadIdx.x;   // 0..131071
  const int b = t >> 10;
  const int d = t & 1023;
  const float w0 = cw[d * 4 + 0], w1 = cw[d * 4 + 1];
  const float w2 = cw[d * 4 + 2], w3 = cw[d * 4 + 3];
  const float bias = cb[d];
  const float* src = xz + (size_t)b * cNP * cXZ + d;
  u16* dst = uc + (size_t)b * cNP * cDIN + d;

  float u0 = 0.f, u1 = 0.f, u2 = 0.f;
  float cur[8];
#pragma unroll
  for (int i = 0; i < 8; ++i) cur[i] = src[(size_t)i * cXZ];

  for (int c = 0; c < 8; ++c) {
    float nxt[8];
    if (c < 7) {
#pragma unroll
      for (int i = 0; i < 8; ++i) nxt[i] = src[(size_t)((c + 1) * 8 + i) * cXZ];
    }
    u16 o[8];
#pragma unroll
    for (int i = 0; i < 8; ++i) {
      float v = w0 * u0 + w1 * u1 + w2 * u2 + w3 * cur[i] + bias;
      o[i] = f2bfu(silu_f(v));
      u0 = u1; u1 = u2; u2 = cur[i];
    }
#pragma unroll
    for (int i = 0; i < 8; ++i) dst[(size_t)(c * 8 + i) * cDIN] = o[i];
    if (c < 7) {
#pragma unroll
      for (int i = 0; i < 8; ++i) cur[i] = nxt[i];
    }
  }
}

// ---------------------------------------------------------------------------
// K4a: x_proj MFMA split-K. grid (M/128, 4): K chunk of 256 each ->
// xpart[kc][8192][64] fp32. BM=128, BN=64, 128 threads = 2 waves.
// ---------------------------------------------------------------------------
__global__ __launch_bounds__(128) void k_xproj(
    const u16* __restrict__ A, const u16* __restrict__ W,
    float* __restrict__ xpart)
{
  constexpr int LDT = 40;
  __shared__ __align__(16) u16 As[128 * LDT];
  __shared__ __align__(16) u16 Ws[64 * LDT];

  const int tid = threadIdx.x;
  const int bm = blockIdx.x * 128;
  const int kbase = blockIdx.y * 256;
  const int wave = tid >> 6;
  const int lane = tid & 63;
  const int wm = wave * 64;
  const int l15 = lane & 15;
  const int quad = lane >> 4;

  floatx4 acc[4][4];
#pragma unroll
  for (int i = 0; i < 4; ++i)
#pragma unroll
    for (int j = 0; j < 4; ++j) acc[i][j] = (floatx4){0.f, 0.f, 0.f, 0.f};

  for (int kk = 0; kk < 256; kk += 32) {
    const int k0 = kbase + kk;
#pragma unroll
    for (int it = 0; it < 4; ++it) {
      int idx = tid + it * 128;          // 0..511
      int row = idx >> 2, c0 = (idx & 3) * 8;
      *(short8*)&As[row * LDT + c0] =
          *(const short8*)(A + (size_t)(bm + row) * cDIN + k0 + c0);
    }
#pragma unroll
    for (int it = 0; it < 2; ++it) {
      int idx = tid + it * 128;          // 0..255
      int row = idx >> 2, c0 = (idx & 3) * 8;
      *(short8*)&Ws[row * LDT + c0] =
          *(const short8*)(W + (size_t)row * cDIN + k0 + c0);
    }
    __syncthreads();

    short8 af[4], bf[4];
#pragma unroll
    for (int i = 0; i < 4; ++i)
      af[i] = *(const short8*)&As[(wm + i * 16 + l15) * LDT + quad * 8];
#pragma unroll
    for (int j = 0; j < 4; ++j)
      bf[j] = *(const short8*)&Ws[(j * 16 + l15) * LDT + quad * 8];
#pragma unroll
    for (int i = 0; i < 4; ++i)
#pragma unroll
      for (int j = 0; j < 4; ++j)
        acc[i][j] = __builtin_amdgcn_mfma_f32_16x16x32_bf16(
            af[i], bf[j], acc[i][j], 0, 0, 0);
    __syncthreads();
  }

  float* out = xpart + (size_t)blockIdx.y * cBL * 64;
#pragma unroll
  for (int i = 0; i < 4; ++i) {
    const int m0 = bm + wm + i * 16 + quad * 4;
#pragma unroll
    for (int j = 0; j < 4; ++j) {
      const int n = j * 16 + l15;
#pragma unroll
      for (int r = 0; r < 4; ++r)
        out[(size_t)(m0 + r) * 64 + n] = acc[i][j][r];
    }
  }
}

// K4b: reduce 4 K-partials -> xdbl fp32 + xdbl16 bf16
__global__ __launch_bounds__(256) void k_xred(
    const float* __restrict__ xpart, float* __restrict__ C,
    u16* __restrict__ Cb)
{
  const int i = (blockIdx.x * 256 + threadIdx.x) * 4;
  float4 s = *(const float4*)(xpart + i);
#pragma unroll
  for (int k = 1; k < 4; ++k) {
    float4 v = *(const float4*)(xpart + (size_t)k * cBL * 64 + i);
    s.x += v.x; s.y += v.y; s.z += v.z; s.w += v.w;
  }
  *(float4*)(C + i) = s;
  ushort4 o;
  o.x = f2bfu(s.x); o.y = f2bfu(s.y); o.z = f2bfu(s.z); o.w = f2bfu(s.w);
  *(ushort4*)(Cb + i) = o;
}

// ---------------------------------------------------------------------------
// K6: selective scan + (y + uc*D) * silu(z); uc bf16 in, y bf16 out in place.
// grid (b, 4): block owns 256 channels. B/C for all 64 steps in LDS.
// l-loop chunked by 8: 24 independent loads per chunk, pipelined one chunk
// ahead in registers (thread owns its column -> no barriers needed).
// ---------------------------------------------------------------------------
__global__ __launch_bounds__(256) void k_scan(
    const float* __restrict__ xz, u16* __restrict__ uc,
    const float* __restrict__ xdbl, const float* __restrict__ A_log,
    const float* __restrict__ Dp)
{
  const int b = blockIdx.x;
  const int tid = threadIdx.x;      // 0..255
  const int d = blockIdx.y * 256 + tid;

  __shared__ float sBC[cNP][32];    // [l][0:16]=B, [16:32]=C
  {
    const float4* src = (const float4*)xdbl;
    for (int i = tid; i < cNP * 8; i += 256) {
      int l = i >> 3, q = i & 7;
      *(float4*)&sBC[l][q * 4] = src[(size_t)(b * cNP + l) * 16 + 8 + q];
    }
  }

  float A[cDST];
  {
    const float4* ap = (const float4*)(A_log + (size_t)d * cDST);
#pragma unroll
    for (int q = 0; q < 4; ++q) {
      float4 w = ap[q];
      A[q*4+0] = -__expf(w.x); A[q*4+1] = -__expf(w.y);
      A[q*4+2] = -__expf(w.z); A[q*4+3] = -__expf(w.w);
    }
  }
  float h[cDST];
#pragma unroll
  for (int n = 0; n < cDST; ++n) h[n] = 0.f;
  const float Dv = Dp[d];
  __syncthreads();

  const float* dsrc = xz + d;            // delta at xz[row*2048 + d]
  const float* zsrc = xz + cDIN + d;     // z
  u16* usrc = uc + d;                    // uc / y (bf16)
  const size_t rb = (size_t)b * cNP;

  float dvc[8], zvc[8], uvc[8];
#pragma unroll
  for (int i = 0; i < 8; ++i) {
    dvc[i] = dsrc[(rb + i) * cXZ];
    zvc[i] = zsrc[(rb + i) * cXZ];
    uvc[i] = bfu2f(usrc[(rb + i) * cDIN]);
  }

  for (int c = 0; c < 8; ++c) {
    float dvn[8], zvn[8], uvn[8];
    if (c < 7) {
#pragma unroll
      for (int i = 0; i < 8; ++i) {
        const size_t row = rb + (c + 1) * 8 + i;
        dvn[i] = dsrc[row * cXZ];
        zvn[i] = zsrc[row * cXZ];
        uvn[i] = bfu2f(usrc[row * cDIN]);
      }
    }
    u16 yo[8];
#pragma unroll
    for (int i = 0; i < 8; ++i) {
      const int l = c * 8 + i;
      const float dv = dvc[i], zv = zvc[i], uv = uvc[i];
      const float du = dv * uv;
      float y = 0.f;
#pragma unroll
      for (int n = 0; n < cDST; ++n) {
        float dA = __expf(dv * A[n]);
        h[n] = dA * h[n] + du * sBC[l][n];
        y += h[n] * sBC[l][16 + n];
      }
      y = (y + uv * Dv) * silu_f(zv);
      yo[i] = f2bfu(y);
    }
#pragma unroll
    for (int i = 0; i < 8; ++i)
      usrc[(rb + c * 8 + i) * cDIN] = yo[i];
    if (c < 7) {
#pragma unroll
      for (int i = 0; i < 8; ++i) {
        dvc[i] = dvn[i]; zvc[i] = zvn[i]; uvc[i] = uvn[i];
      }
    }
  }
}

// ---------------------------------------------------------------------------
// K7a: head LN partial sums. grid (b, 8): each block reduces a 4096-elem
// chunk -> pst[(b*8+chunk)*2 + {0,1}]
// ---------------------------------------------------------------------------
__global__ __launch_bounds__(256) void k_hstats1(
    const float* __restrict__ x, float* __restrict__ pst)
{
  const int b = blockIdx.x;
  const int chunk = blockIdx.y;
  const int tid = threadIdx.x;
  const float4* r4 = (const float4*)(x + (size_t)b * (cNP * cDIM) + chunk * 4096);
  float4 v = r4[tid];
  float4 w = r4[tid + 256];
  float4 u = r4[tid + 512];
  float4 t = r4[tid + 768];
  float s  = v.x + v.y + v.z + v.w + w.x + w.y + w.z + w.w
           + u.x + u.y + u.z + u.w + t.x + t.y + t.z + t.w;
  float s2 = v.x*v.x + v.y*v.y + v.z*v.z + v.w*v.w
           + w.x*w.x + w.y*w.y + w.z*w.z + w.w*w.w
           + u.x*u.x + u.y*u.y + u.z*u.z + u.w*u.w
           + t.x*t.x + t.y*t.y + t.z*t.z + t.w*t.w;
  __shared__ float red[512];
  red[tid] = s; red[256 + tid] = s2;
  __syncthreads();
  for (int st = 128; st > 0; st >>= 1) {
    if (tid < st) { red[tid] += red[tid + st]; red[256+tid] += red[256+tid+st]; }
    __syncthreads();
  }
  if (tid == 0) {
    pst[(b * 8 + chunk) * 2]     = red[0];
    pst[(b * 8 + chunk) * 2 + 1] = red[256];
  }
}

// K7b: finalize -> stats[2b]=mu, stats[2b+1]=rstd  (one block, 128 threads)
__global__ __launch_bounds__(128) void k_hstats2(
    const float* __restrict__ pst, float* __restrict__ stats)
{
  const int b = threadIdx.x;
  float s = 0.f, s2 = 0.f;
#pragma unroll
  for (int c = 0; c < 8; ++c) {
    s  += pst[(b * 8 + c) * 2];
    s2 += pst[(b * 8 + c) * 2 + 1];
  }
  const float mu = s * (1.f / (cNP * cDIM));
  const float var = s2 * (1.f / (cNP * cDIM)) - mu * mu;
  stats[2 * b]     = mu;
  stats[2 * b + 1] = rsqrtf(var + 1e-5f);
}

// ---------------------------------------------------------------------------
// K8a: head split-K stage 1. grid (b, 16): each block does a 2048-elem chunk
// of LN-apply + 32-class dot -> hpart[(b*16+chunk)*32 + cls]
// ---------------------------------------------------------------------------
__global__ __launch_bounds__(256) void k_head1(
    const float* __restrict__ x, const float* __restrict__ stats,
    const float* __restrict__ hg, const float* __restrict__ hb,
    const u16* __restrict__ hwb, float* __restrict__ hpart)
{
  const int b = blockIdx.x;
  const int chunk = blockIdx.y;
  const int tid = threadIdx.x;
  const float mu = stats[2 * b], rstd = stats[2 * b + 1];
  const float* row = x + (size_t)b * (cNP * cDIM);
  const int k0 = chunk * 2048;

  float acc[cNCLS];
#pragma unroll
  for (int c = 0; c < cNCLS; ++c) acc[c] = 0.f;

#pragma unroll
  for (int it = 0; it < 4; ++it) {
    const int i0 = k0 + it * 512 + tid * 2;
    float xn0 = (row[i0]     - mu) * rstd * hg[i0]     + hb[i0];
    float xn1 = (row[i0 + 1] - mu) * rstd * hg[i0 + 1] + hb[i0 + 1];
#pragma unroll
    for (int c = 0; c < cNCLS; ++c) {
      u32 w2 = *(const u32*)(hwb + (size_t)c * (cNP * cDIM) + i0);
      acc[c] += xn0 * bfu2f((u16)(w2 & 0xffffu)) + xn1 * bfu2f((u16)(w2 >> 16));
    }
  }

  __shared__ float sred[cNCLS * 257];
#pragma unroll
  for (int c = 0; c < cNCLS; ++c) sred[c * 257 + tid] = acc[c];
  __syncthreads();
  // 8 threads per class, each sums 32 entries, then 3-level shuffle
  if (tid < cNCLS * 8) {
    const int c = tid >> 3, p = tid & 7;
    float s = 0.f;
#pragma unroll
    for (int i = 0; i < 32; ++i) s += sred[c * 257 + p * 32 + i];
    s += __shfl_xor(s, 1, 64);
    s += __shfl_xor(s, 2, 64);
    s += __shfl_xor(s, 4, 64);
    if (p == 0) hpart[(size_t)(b * 16 + chunk) * cNCLS + c] = s;
  }
}

// K8b: head stage 2: out[b][cls] = sum_chunk hpart + bias
__global__ __launch_bounds__(64) void k_head2(
    const float* __restrict__ hpart, const float* __restrict__ hbias,
    float* __restrict__ out)
{
  const int b = blockIdx.x;
  const int c = threadIdx.x;
  if (c < cNCLS) {
    float s = 0.f;
#pragma unroll
    for (int k = 0; k < 16; ++k)
      s += hpart[(size_t)(b * 16 + k) * cNCLS + c];
    out[b * cNCLS + c] = s + hbias[c];
  }
}

// ---------------------------------------------------------------------------
extern "C" void kernel_launch(void* const* d_in, const int* in_sizes, int n_in,
                              void* d_out, int out_size, void* d_ws, size_t ws_size,
                              hipStream_t stream)
{
  (void)in_sizes; (void)n_in; (void)out_size; (void)ws_size;

  const float* series    = (const float*)d_in[0];
  const float* seg_w     = (const float*)d_in[1];
  const float* seg_b     = (const float*)d_in[2];
  const float* ln_g      = (const float*)d_in[3];
  const float* ln_b      = (const float*)d_in[4];
  const float* in_proj_w = (const float*)d_in[5];
  const float* conv_w    = (const float*)d_in[6];
  const float* conv_b    = (const float*)d_in[7];
  const float* x_proj_w  = (const float*)d_in[8];
  const float* dt_proj_w = (const float*)d_in[9];
  const float* dt_proj_b = (const float*)d_in[10];
  const float* A_log     = (const float*)d_in[11];
  const float* Dp        = (const float*)d_in[12];
  const float* out_proj_w= (const float*)d_in[13];
  const float* head_ln_g = (const float*)d_in[14];
  const float* head_ln_b = (const float*)d_in[15];
  const float* head_w    = (const float*)d_in[16];
  const float* head_b    = (const float*)d_in[17];

  // workspace layout (~113.5 MB)
  float* ws     = (float*)d_ws;
  float* xz     = ws;                                  // [8192,2048] f32 (u/delta | z)
  float* xsegf  = xz;                                  // alias: seg GEMM out [8192,512]
  float* x0     = xz;                                  // alias: final fp32 x
  float* xdbl   = xz + (size_t)cBL * cXZ;              // [8192,64] f32
  float* stats  = xdbl + (size_t)cBL * 64;             // [256]
  float* pst    = stats + 256;                         // [128*8*2]
  float* hpart  = pst + 128 * 8 * 2;                   // [128*16*32]
  u16*   x0b    = (u16*)(hpart + 128 * 16 * 32);       // [8192,512]
  u16*   wib    = x0b + (size_t)cBL * cDIM;            // [2,2048,512]
  u16*   wob    = wib + (size_t)2 * (2*cDIN) * cDIM;   // [2,512,1024]
  u16*   wdtb   = wob + (size_t)2 * cDIM * cDIN;       // [2,1024,32]
  u16*   wxb    = wdtb + (size_t)2 * cDIN * cDTR;      // [2,64,1024]
  u16*   xdbl16 = wxb + (size_t)2 * 64 * cDIN;         // [8192,64]
  u16*   wsegT  = xdbl16 + (size_t)cBL * 64;           // [64,512,128]
  u16*   ucb16  = wsegT + (size_t)cNP * cDIM * cP;     // [8192,1024]
  u16*   hwb    = ucb16 + (size_t)cBL * cDIN;          // [32,32768]
  // xpart aliases x0b: x0b is dead between in_proj (reads it) and out_proj
  // (rewrites it) within each depth; xproj/xred run exactly in that window.
  // sizes match: 8192*512*2B == 4*8192*64*4B == 8.39 MB.
  float* xpart  = (float*)x0b;

  // weight conversions / transpose
  k_f2bf<<<(2 * (2*cDIN) * cDIM) / 1024, 256, 0, stream>>>(in_proj_w, wib);
  k_f2bf<<<(2 * cDIM * cDIN) / 1024, 256, 0, stream>>>(out_proj_w, wob);
  k_f2bf<<<(2 * cDIN * cDTR) / 1024, 256, 0, stream>>>(dt_proj_w, wdtb);
  k_f2bf<<<(2 * 64 * cDIN) / 1024, 256, 0, stream>>>(x_proj_w, wxb);
  k_f2bf<<<(cNCLS * cNP * cDIM) / 1024, 256, 0, stream>>>(head_w, hwb);
  k_segT<<<dim3(cP/32, cDIM/32, cNP), 256, 0, stream>>>(seg_w, wsegT);

  // seg projection (batched MFMA over n) -> xsegf, then (+seg_b) LN -> x0b
  k_gemm_mfma<true,0><<<dim3(1, cDIM/128, cNP), 256, 0, stream>>>(
      series, cNP * cP, wsegT, xsegf, cNP * cDIM, (u16*)nullptr, 0,
      nullptr, cP, (long)cP, (long)cDIM * cP, (long)cDIM);
  k_ln<<<cBL / 4, 256, 0, stream>>>(xsegf, seg_b, ln_g, ln_b, x0b);

  for (int dep = 0; dep < 2; ++dep) {
    const u16*   wi  = wib  + (size_t)dep * (2*cDIN) * cDIM;
    const u16*   wo  = wob  + (size_t)dep * cDIM * cDIN;
    const u16*   wdt = wdtb + (size_t)dep * cDIN * cDTR;
    const u16*   wx  = wxb  + (size_t)dep * 64 * cDIN;
    const float* cwd = conv_w     + (size_t)dep * cDIN * 4;
    const float* cbd = conv_b     + (size_t)dep * cDIN;
    const float* bdt = dt_proj_b  + (size_t)dep * cDIN;
    const float* Ald = A_log      + (size_t)dep * cDIN * cDST;
    const float* Dd  = Dp         + (size_t)dep * cDIN;

    // in_proj: xz[8192,2048] = x0b @ wi^T  (MFMA)
    k_gemm_mfma<false,0><<<dim3(cBL/128, (2*cDIN)/128), 256, 0, stream>>>(
        x0b, cDIM, wi, xz, cXZ, (u16*)nullptr, 0, nullptr, cDIM, 0, 0, 0);
    // depthwise conv + silu -> uc bf16
    k_conv<<<(cB * cDIN) / 256, 256, 0, stream>>>(xz, cwd, cbd, ucb16);
    // x_proj split-K: xpart = uc @ wx^T (4 K-chunks), then reduce
    k_xproj<<<dim3(cBL / 128, 4), 128, 0, stream>>>(ucb16, wx, xpart);
    k_xred<<<(cBL * 64) / 1024, 256, 0, stream>>>(xpart, xdbl, xdbl16);
    // dt_proj + softplus -> delta into xz u-half  (MFMA, K=32)
    k_gemm_mfma<false,1><<<dim3(cBL/128, cDIN/128), 256, 0, stream>>>(
        xdbl16, 64, wdt, xz, cXZ, (u16*)nullptr, 0, bdt, cDTR, 0, 0, 0);
    // scan + gate -> y bf16 in place into ucb16
    k_scan<<<dim3(cB, 4), 256, 0, stream>>>(xz, ucb16, xdbl, Ald, Dd);
    // out_proj: (dep0: bf16 x0b) (dep1: fp32 x0) = y @ wo^T
    k_gemm_mfma<false,0><<<dim3(cBL/128, cDIM/128), 256, 0, stream>>>(
        ucb16, cDIN, wo,
        dep ? x0 : (float*)nullptr, cDIM,
        dep ? (u16*)nullptr : x0b, cDIM,
        nullptr, cDIN, 0, 0, 0);
  }

  k_hstats1<<<dim3(cB, 8), 256, 0, stream>>>(x0, pst);
  k_hstats2<<<1, 128, 0, stream>>>(pst, stats);
  k_head1<<<dim3(cB, 16), 256, 0, stream>>>(x0, stats, head_ln_g, head_ln_b,
                                            hwb, hpart);
  k_head2<<<cB, 64, 0, stream>>>(hpart, head_b, (float*)d_out);
}

// Round 8
// 438.604 us; speedup vs baseline: 3.5997x; 1.0807x over previous
//
#include <hip/hip_runtime.h>

typedef unsigned short u16;
typedef unsigned int   u32;
typedef __attribute__((ext_vector_type(8))) short short8;
typedef __attribute__((ext_vector_type(4))) float floatx4;

static __device__ __forceinline__ float silu_f(float x){
  return x / (1.f + __expf(-x));
}
static __device__ __forceinline__ float bfu2f(u16 u){
  union { u32 i; float f; } v; v.i = ((u32)u) << 16; return v.f;
}
static __device__ __forceinline__ u16 f2bfu(float f){
  union { float f; u32 i; } v; v.f = f;
  u32 x = v.i;
  u32 r = (x + 0x7fffu + ((x >> 16) & 1u)) >> 16;   // round-nearest-even
  return (u16)r;
}
static __device__ __forceinline__ float softplus_f(float v){
  return fmaxf(v, 0.f) + log1pf(__expf(-fabsf(v)));
}

constexpr int cB = 128, cNP = 64, cP = 128, cDIM = 512, cDIN = 1024;
constexpr int cDST = 16, cDTR = 32, cNCLS = 32;
constexpr int cBL = cB * cNP;      // 8192 (b,l) rows
constexpr int cXZ = 2 * cDIN;      // 2048

// ---------------------------------------------------------------------------
// K0: fp32 -> bf16 conversion
// ---------------------------------------------------------------------------
__global__ __launch_bounds__(256) void k_f2bf(
    const float* __restrict__ src, u16* __restrict__ dst)
{
  const int i = (blockIdx.x * 256 + threadIdx.x) * 4;
  float4 v = *(const float4*)(src + i);
  ushort4 o;
  o.x = f2bfu(v.x); o.y = f2bfu(v.y); o.z = f2bfu(v.z); o.w = f2bfu(v.w);
  *(ushort4*)(dst + i) = o;
}

// ---------------------------------------------------------------------------
// K0b: seg_w[n,p,d] -> wsegT[n,d,p] (bf16). 32x32 tiles, 256 threads.
// ---------------------------------------------------------------------------
__global__ __launch_bounds__(256) void k_segT(
    const float* __restrict__ src, u16* __restrict__ dst)
{
  const int n = blockIdx.z;
  const int p0 = blockIdx.x * 32;
  const int d0 = blockIdx.y * 32;
  const int tx = threadIdx.x & 31;
  const int ty = threadIdx.x >> 5;     // 0..7
  __shared__ float t[32][33];
#pragma unroll
  for (int r = 0; r < 4; ++r)
    t[ty + r * 8][tx] = src[(size_t)n * (cP * cDIM) + (p0 + ty + r * 8) * cDIM + d0 + tx];
  __syncthreads();
#pragma unroll
  for (int r = 0; r < 4; ++r)
    dst[(size_t)n * (cDIM * cP) + (d0 + ty + r * 8) * cP + p0 + tx] =
        f2bfu(t[tx][ty + r * 8]);
}

// ---------------------------------------------------------------------------
// K2: bf16 MFMA GEMM, software-pipelined (register double-buffer): tile k+1
// global loads issue right after the barrier and overlap tile k's
// ds_read+MFMA; ds_write consumes them at the next loop top.
// C[M,N] = A[M,K] * W[N,K]^T. 128x128 tile, BK=32, 4 waves (2x2 of 64x64).
// AF32: A fp32, converted in staging. EPI=1: Cb = bf16(softplus(acc+bias)).
// blockIdx.z batching via element strides azs/wzs/czs.
// ---------------------------------------------------------------------------
template<bool AF32, int EPI>
__global__ __launch_bounds__(256) void k_gemm_mfma(
    const void* __restrict__ Av, int lda,
    const u16* __restrict__ W,
    float* __restrict__ C, int ldc,
    u16* __restrict__ Cb, int ldcb,
    const float* __restrict__ bias,
    int K, long azs, long wzs, long czs)
{
  constexpr int LDT = 40;   // 32 + 8 pad (u16) -> conflict-free
  __shared__ __align__(16) u16 As[128 * LDT];
  __shared__ __align__(16) u16 Ws[128 * LDT];

  const int bz = blockIdx.z;
  const u16* Wz = W + (size_t)bz * wzs;

  const int tid = threadIdx.x;
  const int bm = blockIdx.x * 128;
  const int bn = blockIdx.y * 128;
  const int wave = tid >> 6;
  const int lane = tid & 63;
  const int wm = (wave & 1) * 64;
  const int wn = (wave >> 1) * 64;
  const int l15 = lane & 15;
  const int quad = lane >> 4;

  floatx4 acc[4][4];
#pragma unroll
  for (int i = 0; i < 4; ++i)
#pragma unroll
    for (int j = 0; j < 4; ++j) acc[i][j] = (floatx4){0.f, 0.f, 0.f, 0.f};

  const int r0 = tid >> 2;          // 0..63
  const int c0 = (tid & 3) * 8;     // 0,8,16,24

  const float* Af = (const float*)Av + (AF32 ? (size_t)bz * azs : 0);
  const u16*   Ab = (const u16*)Av + (AF32 ? 0 : (size_t)bz * azs);

  float4 fa0, fb0, fa1, fb1;        // AF32 staging regs
  short8 ra0, ra1, rw0, rw1;        // bf16 staging regs

  // prologue: load tile 0
  if constexpr (AF32) {
    const float* p0 = Af + (size_t)(bm + r0) * lda + c0;
    const float* p1 = Af + (size_t)(bm + r0 + 64) * lda + c0;
    fa0 = *(const float4*)p0; fb0 = *(const float4*)(p0 + 4);
    fa1 = *(const float4*)p1; fb1 = *(const float4*)(p1 + 4);
  } else {
    ra0 = *(const short8*)(Ab + (size_t)(bm + r0)      * lda + c0);
    ra1 = *(const short8*)(Ab + (size_t)(bm + r0 + 64) * lda + c0);
  }
  rw0 = *(const short8*)(Wz + (size_t)(bn + r0)      * K + c0);
  rw1 = *(const short8*)(Wz + (size_t)(bn + r0 + 64) * K + c0);

  for (int k0 = 0; k0 < K; k0 += 32) {
    // stage regs -> LDS
    if constexpr (AF32) {
      short8 s0, s1;
      s0[0] = (short)f2bfu(fa0.x); s0[1] = (short)f2bfu(fa0.y);
      s0[2] = (short)f2bfu(fa0.z); s0[3] = (short)f2bfu(fa0.w);
      s0[4] = (short)f2bfu(fb0.x); s0[5] = (short)f2bfu(fb0.y);
      s0[6] = (short)f2bfu(fb0.z); s0[7] = (short)f2bfu(fb0.w);
      s1[0] = (short)f2bfu(fa1.x); s1[1] = (short)f2bfu(fa1.y);
      s1[2] = (short)f2bfu(fa1.z); s1[3] = (short)f2bfu(fa1.w);
      s1[4] = (short)f2bfu(fb1.x); s1[5] = (short)f2bfu(fb1.y);
      s1[6] = (short)f2bfu(fb1.z); s1[7] = (short)f2bfu(fb1.w);
      *(short8*)&As[r0 * LDT + c0] = s0;
      *(short8*)&As[(r0 + 64) * LDT + c0] = s1;
    } else {
      *(short8*)&As[r0 * LDT + c0] = ra0;
      *(short8*)&As[(r0 + 64) * LDT + c0] = ra1;
    }
    *(short8*)&Ws[r0 * LDT + c0] = rw0;
    *(short8*)&Ws[(r0 + 64) * LDT + c0] = rw1;
    __syncthreads();

    // issue next tile's global loads (overlap with ds_read + MFMA below)
    const int kn = k0 + 32;
    if (kn < K) {
      if constexpr (AF32) {
        const float* p0 = Af + (size_t)(bm + r0) * lda + kn + c0;
        const float* p1 = Af + (size_t)(bm + r0 + 64) * lda + kn + c0;
        fa0 = *(const float4*)p0; fb0 = *(const float4*)(p0 + 4);
        fa1 = *(const float4*)p1; fb1 = *(const float4*)(p1 + 4);
      } else {
        ra0 = *(const short8*)(Ab + (size_t)(bm + r0)      * lda + kn + c0);
        ra1 = *(const short8*)(Ab + (size_t)(bm + r0 + 64) * lda + kn + c0);
      }
      rw0 = *(const short8*)(Wz + (size_t)(bn + r0)      * K + kn + c0);
      rw1 = *(const short8*)(Wz + (size_t)(bn + r0 + 64) * K + kn + c0);
    }

    short8 af[4], bf[4];
#pragma unroll
    for (int i = 0; i < 4; ++i)
      af[i] = *(const short8*)&As[(wm + i * 16 + l15) * LDT + quad * 8];
#pragma unroll
    for (int j = 0; j < 4; ++j)
      bf[j] = *(const short8*)&Ws[(wn + j * 16 + l15) * LDT + quad * 8];
#pragma unroll
    for (int i = 0; i < 4; ++i)
#pragma unroll
      for (int j = 0; j < 4; ++j)
        acc[i][j] = __builtin_amdgcn_mfma_f32_16x16x32_bf16(
            af[i], bf[j], acc[i][j], 0, 0, 0);
    __syncthreads();
  }

#pragma unroll
  for (int i = 0; i < 4; ++i) {
    const int m0 = bm + wm + i * 16 + quad * 4;
#pragma unroll
    for (int j = 0; j < 4; ++j) {
      const int n = bn + wn + j * 16 + l15;
      if constexpr (EPI == 1) {
        const float bs = bias[n];
#pragma unroll
        for (int r = 0; r < 4; ++r)
          Cb[(size_t)(m0 + r) * ldcb + n + bz * czs] =
              f2bfu(softplus_f(acc[i][j][r] + bs));
      } else {
        if (C) {
#pragma unroll
          for (int r = 0; r < 4; ++r)
            C[(size_t)(m0 + r) * ldc + n + bz * czs] = acc[i][j][r];
        }
        if (Cb) {
#pragma unroll
          for (int r = 0; r < 4; ++r)
            Cb[(size_t)(m0 + r) * ldcb + n + bz * czs] = f2bfu(acc[i][j][r]);
        }
      }
    }
  }
}

// ---------------------------------------------------------------------------
// K1b: per-row LayerNorm (512 elems), wave per row -> bf16 out.
// seg_b[n,d] added before stats (faithful to reference).
// ---------------------------------------------------------------------------
__global__ __launch_bounds__(256) void k_ln(
    const float* __restrict__ xs, const float* __restrict__ sb,
    const float* __restrict__ ln_g, const float* __restrict__ ln_b,
    u16* __restrict__ x0b)
{
  const int tid = threadIdx.x;
  const int r = blockIdx.x * 4 + (tid >> 6);   // row (b*64+n)
  const int lane = tid & 63;
  const int d = lane * 8;
  const int n = r & 63;

  const float* row = xs + (size_t)r * cDIM + d;
  float4 a = *(const float4*)row;
  float4 b = *(const float4*)(row + 4);
  const float* sbp = sb + n * cDIM + d;
  float4 s0 = *(const float4*)sbp;
  float4 s1 = *(const float4*)(sbp + 4);
  a.x += s0.x; a.y += s0.y; a.z += s0.z; a.w += s0.w;
  b.x += s1.x; b.y += s1.y; b.z += s1.z; b.w += s1.w;

  float s  = a.x + a.y + a.z + a.w + b.x + b.y + b.z + b.w;
  float s2 = a.x*a.x + a.y*a.y + a.z*a.z + a.w*a.w
           + b.x*b.x + b.y*b.y + b.z*b.z + b.w*b.w;
#pragma unroll
  for (int m = 1; m < 64; m <<= 1) {
    s  += __shfl_xor(s,  m, 64);
    s2 += __shfl_xor(s2, m, 64);
  }
  const float mu = s * (1.f / cDIM);
  const float var = s2 * (1.f / cDIM) - mu * mu;
  const float rstd = rsqrtf(var + 1e-5f);

  const float* g = ln_g + n * cDIM + d;
  const float* be = ln_b + n * cDIM + d;
  float4 g0 = *(const float4*)g, g1 = *(const float4*)(g + 4);
  float4 b0 = *(const float4*)be, b1 = *(const float4*)(be + 4);
  ushort4 o0, o1;
  o0.x = f2bfu((a.x - mu) * rstd * g0.x + b0.x);
  o0.y = f2bfu((a.y - mu) * rstd * g0.y + b0.y);
  o0.z = f2bfu((a.z - mu) * rstd * g0.z + b0.z);
  o0.w = f2bfu((a.w - mu) * rstd * g0.w + b0.w);
  o1.x = f2bfu((b.x - mu) * rstd * g1.x + b1.x);
  o1.y = f2bfu((b.y - mu) * rstd * g1.y + b1.y);
  o1.z = f2bfu((b.z - mu) * rstd * g1.z + b1.z);
  o1.w = f2bfu((b.w - mu) * rstd * g1.w + b1.w);
  *(ushort4*)(x0b + (size_t)r * cDIM + d) = o0;
  *(ushort4*)(x0b + (size_t)r * cDIM + d + 4) = o1;
}

// ---------------------------------------------------------------------------
// K3: depthwise causal conv (DCONV=4) + SiLU. u now bf16 in xz16[:, 0:1024].
// Column-walk unrolled by 8 with one-chunk-ahead prefetch.
// ---------------------------------------------------------------------------
__global__ __launch_bounds__(256) void k_conv(
    const u16* __restrict__ xz16, const float* __restrict__ cw,
    const float* __restrict__ cb, u16* __restrict__ uc)
{
  const int t = blockIdx.x * 256 + threadIdx.x;   // 0..131071
  const int b = t >> 10;
  const int d = t & 1023;
  const float w0 = cw[d * 4 + 0], w1 = cw[d * 4 + 1];
  const float w2 = cw[d * 4 + 2], w3 = cw[d * 4 + 3];
  const float bias = cb[d];
  const u16* src = xz16 + (size_t)b * cNP * cXZ + d;
  u16* dst = uc + (size_t)b * cNP * cDIN + d;

  float u0 = 0.f, u1 = 0.f, u2 = 0.f;
  float cur[8];
#pragma unroll
  for (int i = 0; i < 8; ++i) cur[i] = bfu2f(src[(size_t)i * cXZ]);

  for (int c = 0; c < 8; ++c) {
    float nxt[8];
    if (c < 7) {
#pragma unroll
      for (int i = 0; i < 8; ++i)
        nxt[i] = bfu2f(src[(size_t)((c + 1) * 8 + i) * cXZ]);
    }
    u16 o[8];
#pragma unroll
    for (int i = 0; i < 8; ++i) {
      float v = w0 * u0 + w1 * u1 + w2 * u2 + w3 * cur[i] + bias;
      o[i] = f2bfu(silu_f(v));
      u0 = u1; u1 = u2; u2 = cur[i];
    }
#pragma unroll
    for (int i = 0; i < 8; ++i) dst[(size_t)(c * 8 + i) * cDIN] = o[i];
    if (c < 7) {
#pragma unroll
      for (int i = 0; i < 8; ++i) cur[i] = nxt[i];
    }
  }
}

// ---------------------------------------------------------------------------
// K4a: x_proj MFMA split-K, pipelined. grid (M/128, 4): K chunks of 256 ->
// xpart[kc][8192][64] fp32. BM=128, BN=64, 128 threads = 2 waves.
// ---------------------------------------------------------------------------
__global__ __launch_bounds__(128) void k_xproj(
    const u16* __restrict__ A, const u16* __restrict__ W,
    float* __restrict__ xpart)
{
  constexpr int LDT = 40;
  __shared__ __align__(16) u16 As[128 * LDT];
  __shared__ __align__(16) u16 Ws[64 * LDT];

  const int tid = threadIdx.x;
  const int bm = blockIdx.x * 128;
  const int kbase = blockIdx.y * 256;
  const int wave = tid >> 6;
  const int lane = tid & 63;
  const int wm = wave * 64;
  const int l15 = lane & 15;
  const int quad = lane >> 4;

  floatx4 acc[4][4];
#pragma unroll
  for (int i = 0; i < 4; ++i)
#pragma unroll
    for (int j = 0; j < 4; ++j) acc[i][j] = (floatx4){0.f, 0.f, 0.f, 0.f};

  short8 rA[4], rW[2];
#pragma unroll
  for (int it = 0; it < 4; ++it) {
    int idx = tid + it * 128, row = idx >> 2, cc = (idx & 3) * 8;
    rA[it] = *(const short8*)(A + (size_t)(bm + row) * cDIN + kbase + cc);
  }
#pragma unroll
  for (int it = 0; it < 2; ++it) {
    int idx = tid + it * 128, row = idx >> 2, cc = (idx & 3) * 8;
    rW[it] = *(const short8*)(W + (size_t)row * cDIN + kbase + cc);
  }

  for (int kk = 0; kk < 256; kk += 32) {
#pragma unroll
    for (int it = 0; it < 4; ++it) {
      int idx = tid + it * 128, row = idx >> 2, cc = (idx & 3) * 8;
      *(short8*)&As[row * LDT + cc] = rA[it];
    }
#pragma unroll
    for (int it = 0; it < 2; ++it) {
      int idx = tid + it * 128, row = idx >> 2, cc = (idx & 3) * 8;
      *(short8*)&Ws[row * LDT + cc] = rW[it];
    }
    __syncthreads();

    if (kk + 32 < 256) {
      const int k0 = kbase + kk + 32;
#pragma unroll
      for (int it = 0; it < 4; ++it) {
        int idx = tid + it * 128, row = idx >> 2, cc = (idx & 3) * 8;
        rA[it] = *(const short8*)(A + (size_t)(bm + row) * cDIN + k0 + cc);
      }
#pragma unroll
      for (int it = 0; it < 2; ++it) {
        int idx = tid + it * 128, row = idx >> 2, cc = (idx & 3) * 8;
        rW[it] = *(const short8*)(W + (size_t)row * cDIN + k0 + cc);
      }
    }

    short8 af[4], bf[4];
#pragma unroll
    for (int i = 0; i < 4; ++i)
      af[i] = *(const short8*)&As[(wm + i * 16 + l15) * LDT + quad * 8];
#pragma unroll
    for (int j = 0; j < 4; ++j)
      bf[j] = *(const short8*)&Ws[(j * 16 + l15) * LDT + quad * 8];
#pragma unroll
    for (int i = 0; i < 4; ++i)
#pragma unroll
      for (int j = 0; j < 4; ++j)
        acc[i][j] = __builtin_amdgcn_mfma_f32_16x16x32_bf16(
            af[i], bf[j], acc[i][j], 0, 0, 0);
    __syncthreads();
  }

  float* out = xpart + (size_t)blockIdx.y * cBL * 64;
#pragma unroll
  for (int i = 0; i < 4; ++i) {
    const int m0 = bm + wm + i * 16 + quad * 4;
#pragma unroll
    for (int j = 0; j < 4; ++j) {
      const int n = j * 16 + l15;
#pragma unroll
      for (int r = 0; r < 4; ++r)
        out[(size_t)(m0 + r) * 64 + n] = acc[i][j][r];
    }
  }
}

// K4b: reduce 4 K-partials -> xdbl fp32 + xdbl16 bf16
__global__ __launch_bounds__(256) void k_xred(
    const float* __restrict__ xpart, float* __restrict__ C,
    u16* __restrict__ Cb)
{
  const int i = (blockIdx.x * 256 + threadIdx.x) * 4;
  float4 s = *(const float4*)(xpart + i);
#pragma unroll
  for (int k = 1; k < 4; ++k) {
    float4 v = *(const float4*)(xpart + (size_t)k * cBL * 64 + i);
    s.x += v.x; s.y += v.y; s.z += v.z; s.w += v.w;
  }
  *(float4*)(C + i) = s;
  ushort4 o;
  o.x = f2bfu(s.x); o.y = f2bfu(s.y); o.z = f2bfu(s.z); o.w = f2bfu(s.w);
  *(ushort4*)(Cb + i) = o;
}

// ---------------------------------------------------------------------------
// K6: selective scan + (y + uc*D) * silu(z); delta/z bf16 from xz16, uc bf16,
// y bf16 out in place. grid (b, 4). l-loop chunked by 8, pipelined.
// ---------------------------------------------------------------------------
__global__ __launch_bounds__(256) void k_scan(
    const u16* __restrict__ xz16, u16* __restrict__ uc,
    const float* __restrict__ xdbl, const float* __restrict__ A_log,
    const float* __restrict__ Dp)
{
  const int b = blockIdx.x;
  const int tid = threadIdx.x;      // 0..255
  const int d = blockIdx.y * 256 + tid;

  __shared__ float sBC[cNP][32];    // [l][0:16]=B, [16:32]=C
  {
    const float4* src = (const float4*)xdbl;
    for (int i = tid; i < cNP * 8; i += 256) {
      int l = i >> 3, q = i & 7;
      *(float4*)&sBC[l][q * 4] = src[(size_t)(b * cNP + l) * 16 + 8 + q];
    }
  }

  float A[cDST];
  {
    const float4* ap = (const float4*)(A_log + (size_t)d * cDST);
#pragma unroll
    for (int q = 0; q < 4; ++q) {
      float4 w = ap[q];
      A[q*4+0] = -__expf(w.x); A[q*4+1] = -__expf(w.y);
      A[q*4+2] = -__expf(w.z); A[q*4+3] = -__expf(w.w);
    }
  }
  float h[cDST];
#pragma unroll
  for (int n = 0; n < cDST; ++n) h[n] = 0.f;
  const float Dv = Dp[d];
  __syncthreads();

  const u16* dsrc = xz16 + d;            // delta at xz16[row*2048 + d]
  const u16* zsrc = xz16 + cDIN + d;     // z
  u16* usrc = uc + d;                    // uc / y (bf16)
  const size_t rb = (size_t)b * cNP;

  float dvc[8], zvc[8], uvc[8];
#pragma unroll
  for (int i = 0; i < 8; ++i) {
    dvc[i] = bfu2f(dsrc[(rb + i) * cXZ]);
    zvc[i] = bfu2f(zsrc[(rb + i) * cXZ]);
    uvc[i] = bfu2f(usrc[(rb + i) * cDIN]);
  }

  for (int c = 0; c < 8; ++c) {
    float dvn[8], zvn[8], uvn[8];
    if (c < 7) {
#pragma unroll
      for (int i = 0; i < 8; ++i) {
        const size_t row = rb + (c + 1) * 8 + i;
        dvn[i] = bfu2f(dsrc[row * cXZ]);
        zvn[i] = bfu2f(zsrc[row * cXZ]);
        uvn[i] = bfu2f(usrc[row * cDIN]);
      }
    }
    u16 yo[8];
#pragma unroll
    for (int i = 0; i < 8; ++i) {
      const int l = c * 8 + i;
      const float dv = dvc[i], zv = zvc[i], uv = uvc[i];
      const float du = dv * uv;
      float y = 0.f;
#pragma unroll
      for (int n = 0; n < cDST; ++n) {
        float dA = __expf(dv * A[n]);
        h[n] = dA * h[n] + du * sBC[l][n];
        y += h[n] * sBC[l][16 + n];
      }
      y = (y + uv * Dv) * silu_f(zv);
      yo[i] = f2bfu(y);
    }
#pragma unroll
    for (int i = 0; i < 8; ++i)
      usrc[(rb + c * 8 + i) * cDIN] = yo[i];
    if (c < 7) {
#pragma unroll
      for (int i = 0; i < 8; ++i) {
        dvc[i] = dvn[i]; zvc[i] = zvn[i]; uvc[i] = uvn[i];
      }
    }
  }
}

// ---------------------------------------------------------------------------
// K7a: head LN partial sums. grid (b, 8) -> pst[(b*8+chunk)*2 + {0,1}]
// ---------------------------------------------------------------------------
__global__ __launch_bounds__(256) void k_hstats1(
    const float* __restrict__ x, float* __restrict__ pst)
{
  const int b = blockIdx.x;
  const int chunk = blockIdx.y;
  const int tid = threadIdx.x;
  const float4* r4 = (const float4*)(x + (size_t)b * (cNP * cDIM) + chunk * 4096);
  float4 v = r4[tid];
  float4 w = r4[tid + 256];
  float4 u = r4[tid + 512];
  float4 t = r4[tid + 768];
  float s  = v.x + v.y + v.z + v.w + w.x + w.y + w.z + w.w
           + u.x + u.y + u.z + u.w + t.x + t.y + t.z + t.w;
  float s2 = v.x*v.x + v.y*v.y + v.z*v.z + v.w*v.w
           + w.x*w.x + w.y*w.y + w.z*w.z + w.w*w.w
           + u.x*u.x + u.y*u.y + u.z*u.z + u.w*u.w
           + t.x*t.x + t.y*t.y + t.z*t.z + t.w*t.w;
  __shared__ float red[512];
  red[tid] = s; red[256 + tid] = s2;
  __syncthreads();
  for (int st = 128; st > 0; st >>= 1) {
    if (tid < st) { red[tid] += red[tid + st]; red[256+tid] += red[256+tid+st]; }
    __syncthreads();
  }
  if (tid == 0) {
    pst[(b * 8 + chunk) * 2]     = red[0];
    pst[(b * 8 + chunk) * 2 + 1] = red[256];
  }
}

// K7b: finalize -> stats
__global__ __launch_bounds__(128) void k_hstats2(
    const float* __restrict__ pst, float* __restrict__ stats)
{
  const int b = threadIdx.x;
  float s = 0.f, s2 = 0.f;
#pragma unroll
  for (int c = 0; c < 8; ++c) {
    s  += pst[(b * 8 + c) * 2];
    s2 += pst[(b * 8 + c) * 2 + 1];
  }
  const float mu = s * (1.f / (cNP * cDIM));
  const float var = s2 * (1.f / (cNP * cDIM)) - mu * mu;
  stats[2 * b]     = mu;
  stats[2 * b + 1] = rsqrtf(var + 1e-5f);
}

// ---------------------------------------------------------------------------
// K8a: head split-K stage 1. grid (b, 16) -> hpart[(b*16+chunk)*32 + cls]
// ---------------------------------------------------------------------------
__global__ __launch_bounds__(256) void k_head1(
    const float* __restrict__ x, const float* __restrict__ stats,
    const float* __restrict__ hg, const float* __restrict__ hb,
    const u16* __restrict__ hwb, float* __restrict__ hpart)
{
  const int b = blockIdx.x;
  const int chunk = blockIdx.y;
  const int tid = threadIdx.x;
  const float mu = stats[2 * b], rstd = stats[2 * b + 1];
  const float* row = x + (size_t)b * (cNP * cDIM);
  const int k0 = chunk * 2048;

  float acc[cNCLS];
#pragma unroll
  for (int c = 0; c < cNCLS; ++c) acc[c] = 0.f;

#pragma unroll
  for (int it = 0; it < 4; ++it) {
    const int i0 = k0 + it * 512 + tid * 2;
    float xn0 = (row[i0]     - mu) * rstd * hg[i0]     + hb[i0];
    float xn1 = (row[i0 + 1] - mu) * rstd * hg[i0 + 1] + hb[i0 + 1];
#pragma unroll
    for (int c = 0; c < cNCLS; ++c) {
      u32 w2 = *(const u32*)(hwb + (size_t)c * (cNP * cDIM) + i0);
      acc[c] += xn0 * bfu2f((u16)(w2 & 0xffffu)) + xn1 * bfu2f((u16)(w2 >> 16));
    }
  }

  __shared__ float sred[cNCLS * 257];
#pragma unroll
  for (int c = 0; c < cNCLS; ++c) sred[c * 257 + tid] = acc[c];
  __syncthreads();
  if (tid < cNCLS * 8) {
    const int c = tid >> 3, p = tid & 7;
    float s = 0.f;
#pragma unroll
    for (int i = 0; i < 32; ++i) s += sred[c * 257 + p * 32 + i];
    s += __shfl_xor(s, 1, 64);
    s += __shfl_xor(s, 2, 64);
    s += __shfl_xor(s, 4, 64);
    if (p == 0) hpart[(size_t)(b * 16 + chunk) * cNCLS + c] = s;
  }
}

// K8b: head stage 2
__global__ __launch_bounds__(64) void k_head2(
    const float* __restrict__ hpart, const float* __restrict__ hbias,
    float* __restrict__ out)
{
  const int b = blockIdx.x;
  const int c = threadIdx.x;
  if (c < cNCLS) {
    float s = 0.f;
#pragma unroll
    for (int k = 0; k < 16; ++k)
      s += hpart[(size_t)(b * 16 + k) * cNCLS + c];
    out[b * cNCLS + c] = s + hbias[c];
  }
}

// ---------------------------------------------------------------------------
extern "C" void kernel_launch(void* const* d_in, const int* in_sizes, int n_in,
                              void* d_out, int out_size, void* d_ws, size_t ws_size,
                              hipStream_t stream)
{
  (void)in_sizes; (void)n_in; (void)out_size; (void)ws_size;

  const float* series    = (const float*)d_in[0];
  const float* seg_w     = (const float*)d_in[1];
  const float* seg_b     = (const float*)d_in[2];
  const float* ln_g      = (const float*)d_in[3];
  const float* ln_b      = (const float*)d_in[4];
  const float* in_proj_w = (const float*)d_in[5];
  const float* conv_w    = (const float*)d_in[6];
  const float* conv_b    = (const float*)d_in[7];
  const float* x_proj_w  = (const float*)d_in[8];
  const float* dt_proj_w = (const float*)d_in[9];
  const float* dt_proj_b = (const float*)d_in[10];
  const float* A_log     = (const float*)d_in[11];
  const float* Dp        = (const float*)d_in[12];
  const float* out_proj_w= (const float*)d_in[13];
  const float* head_ln_g = (const float*)d_in[14];
  const float* head_ln_b = (const float*)d_in[15];
  const float* head_w    = (const float*)d_in[16];
  const float* head_b    = (const float*)d_in[17];

  // workspace layout (~96 MB)
  u16*   xz16   = (u16*)d_ws;                          // [8192,2048] bf16 u/delta | z
  float* x0     = (float*)(xz16 + (size_t)cBL * cXZ);  // [8192,512] f32 (xsegf alias)
  float* xsegf  = x0;
  float* xdbl   = x0 + (size_t)cBL * cDIM;             // [8192,64] f32
  float* stats  = xdbl + (size_t)cBL * 64;             // [256]
  float* pst    = stats + 256;                         // [2048]
  float* hpart  = pst + 128 * 8 * 2;                   // [65536]
  u16*   x0b    = (u16*)(hpart + 128 * 16 * 32);       // [8192,512]
  u16*   wib    = x0b + (size_t)cBL * cDIM;            // [2,2048,512]
  u16*   wob    = wib + (size_t)2 * (2*cDIN) * cDIM;   // [2,512,1024]
  u16*   wdtb   = wob + (size_t)2 * cDIM * cDIN;       // [2,1024,32]
  u16*   wxb    = wdtb + (size_t)2 * cDIN * cDTR;      // [2,64,1024]
  u16*   xdbl16 = wxb + (size_t)2 * 64 * cDIN;         // [8192,64]
  u16*   wsegT  = xdbl16 + (size_t)cBL * 64;           // [64,512,128]
  u16*   ucb16  = wsegT + (size_t)cNP * cDIM * cP;     // [8192,1024]
  u16*   hwb    = ucb16 + (size_t)cBL * cDIN;          // [32,32768]
  // xpart aliases x0b (dead between in_proj read and out_proj write;
  // 8192*512*2B == 4*8192*64*4B == 8.39 MB)
  float* xpart  = (float*)x0b;

  // weight conversions / transpose
  k_f2bf<<<(2 * (2*cDIN) * cDIM) / 1024, 256, 0, stream>>>(in_proj_w, wib);
  k_f2bf<<<(2 * cDIM * cDIN) / 1024, 256, 0, stream>>>(out_proj_w, wob);
  k_f2bf<<<(2 * cDIN * cDTR) / 1024, 256, 0, stream>>>(dt_proj_w, wdtb);
  k_f2bf<<<(2 * 64 * cDIN) / 1024, 256, 0, stream>>>(x_proj_w, wxb);
  k_f2bf<<<(cNCLS * cNP * cDIM) / 1024, 256, 0, stream>>>(head_w, hwb);
  k_segT<<<dim3(cP/32, cDIM/32, cNP), 256, 0, stream>>>(seg_w, wsegT);

  // seg projection (batched MFMA over n) -> xsegf, then (+seg_b) LN -> x0b
  k_gemm_mfma<true,0><<<dim3(1, cDIM/128, cNP), 256, 0, stream>>>(
      series, cNP * cP, wsegT, xsegf, cNP * cDIM, (u16*)nullptr, 0,
      nullptr, cP, (long)cP, (long)cDIM * cP, (long)cDIM);
  k_ln<<<cBL / 4, 256, 0, stream>>>(xsegf, seg_b, ln_g, ln_b, x0b);

  for (int dep = 0; dep < 2; ++dep) {
    const u16*   wi  = wib  + (size_t)dep * (2*cDIN) * cDIM;
    const u16*   wo  = wob  + (size_t)dep * cDIM * cDIN;
    const u16*   wdt = wdtb + (size_t)dep * cDIN * cDTR;
    const u16*   wx  = wxb  + (size_t)dep * 64 * cDIN;
    const float* cwd = conv_w     + (size_t)dep * cDIN * 4;
    const float* cbd = conv_b     + (size_t)dep * cDIN;
    const float* bdt = dt_proj_b  + (size_t)dep * cDIN;
    const float* Ald = A_log      + (size_t)dep * cDIN * cDST;
    const float* Dd  = Dp         + (size_t)dep * cDIN;

    // in_proj: xz16[8192,2048] (bf16) = x0b @ wi^T  (MFMA, pipelined)
    k_gemm_mfma<false,0><<<dim3(cBL/128, (2*cDIN)/128), 256, 0, stream>>>(
        x0b, cDIM, wi, (float*)nullptr, 0, xz16, cXZ, nullptr, cDIM, 0, 0, 0);
    // depthwise conv + silu -> uc bf16
    k_conv<<<(cB * cDIN) / 256, 256, 0, stream>>>(xz16, cwd, cbd, ucb16);
    // x_proj split-K: xpart = uc @ wx^T (4 K-chunks), then reduce
    k_xproj<<<dim3(cBL / 128, 4), 128, 0, stream>>>(ucb16, wx, xpart);
    k_xred<<<(cBL * 64) / 1024, 256, 0, stream>>>(xpart, xdbl, xdbl16);
    // dt_proj + softplus -> delta bf16 into xz16 u-half  (MFMA, K=32)
    k_gemm_mfma<false,1><<<dim3(cBL/128, cDIN/128), 256, 0, stream>>>(
        xdbl16, 64, wdt, (float*)nullptr, 0, xz16, cXZ, bdt, cDTR, 0, 0, 0);
    // scan + gate -> y bf16 in place into ucb16
    k_scan<<<dim3(cB, 4), 256, 0, stream>>>(xz16, ucb16, xdbl, Ald, Dd);
    // out_proj: (dep0: bf16 x0b) (dep1: fp32 x0) = y @ wo^T
    k_gemm_mfma<false,0><<<dim3(cBL/128, cDIM/128), 256, 0, stream>>>(
        ucb16, cDIN, wo,
        dep ? x0 : (float*)nullptr, cDIM,
        dep ? (u16*)nullptr : x0b, cDIM,
        nullptr, cDIN, 0, 0, 0);
  }

  k_hstats1<<<dim3(cB, 8), 256, 0, stream>>>(x0, pst);
  k_hstats2<<<1, 128, 0, stream>>>(pst, stats);
  k_head1<<<dim3(cB, 16), 256, 0, stream>>>(x0, stats, head_ln_g, head_ln_b,
                                            hwb, hpart);
  k_head2<<<cB, 64, 0, stream>>>(hpart, head_b, (float*)d_out);
}

// Round 9
// 401.164 us; speedup vs baseline: 3.9356x; 1.0933x over previous
//
#include <hip/hip_runtime.h>

typedef unsigned short u16;
typedef unsigned int   u32;
typedef __attribute__((ext_vector_type(8))) short short8;
typedef __attribute__((ext_vector_type(4))) float floatx4;

static __device__ __forceinline__ float silu_f(float x){
  return x / (1.f + __expf(-x));
}
static __device__ __forceinline__ float bfu2f(u16 u){
  union { u32 i; float f; } v; v.i = ((u32)u) << 16; return v.f;
}
static __device__ __forceinline__ u16 f2bfu(float f){
  union { float f; u32 i; } v; v.f = f;
  u32 x = v.i;
  u32 r = (x + 0x7fffu + ((x >> 16) & 1u)) >> 16;   // round-nearest-even
  return (u16)r;
}
static __device__ __forceinline__ float softplus_f(float v){
  return fmaxf(v, 0.f) + log1pf(__expf(-fabsf(v)));
}

constexpr int cB = 128, cNP = 64, cP = 128, cDIM = 512, cDIN = 1024;
constexpr int cDST = 16, cDTR = 32, cNCLS = 32;
constexpr int cBL = cB * cNP;      // 8192 (b,l) rows
constexpr int cXZ = 2 * cDIN;      // 2048

// ---------------------------------------------------------------------------
// K0: fp32 -> bf16 conversion
// ---------------------------------------------------------------------------
__global__ __launch_bounds__(256) void k_f2bf(
    const float* __restrict__ src, u16* __restrict__ dst)
{
  const int i = (blockIdx.x * 256 + threadIdx.x) * 4;
  float4 v = *(const float4*)(src + i);
  ushort4 o;
  o.x = f2bfu(v.x); o.y = f2bfu(v.y); o.z = f2bfu(v.z); o.w = f2bfu(v.w);
  *(ushort4*)(dst + i) = o;
}

// ---------------------------------------------------------------------------
// K0b: seg_w[n,p,d] -> wsegT[n,d,p] (bf16). 32x32 tiles, 256 threads.
// ---------------------------------------------------------------------------
__global__ __launch_bounds__(256) void k_segT(
    const float* __restrict__ src, u16* __restrict__ dst)
{
  const int n = blockIdx.z;
  const int p0 = blockIdx.x * 32;
  const int d0 = blockIdx.y * 32;
  const int tx = threadIdx.x & 31;
  const int ty = threadIdx.x >> 5;     // 0..7
  __shared__ float t[32][33];
#pragma unroll
  for (int r = 0; r < 4; ++r)
    t[ty + r * 8][tx] = src[(size_t)n * (cP * cDIM) + (p0 + ty + r * 8) * cDIM + d0 + tx];
  __syncthreads();
#pragma unroll
  for (int r = 0; r < 4; ++r)
    dst[(size_t)n * (cDIM * cP) + (d0 + ty + r * 8) * cP + p0 + tx] =
        f2bfu(t[tx][ty + r * 8]);
}

// ---------------------------------------------------------------------------
// K2: bf16 MFMA GEMM, software-pipelined (register double-buffer).
// C[M,N] = A[M,K] * W[N,K]^T. 128x128 tile, BK=32, 4 waves (2x2 of 64x64).
// AF32: A fp32, converted in staging. EPI=1: Cb = bf16(softplus(acc+bias)).
// EPI=2 (in_proj+conv fusion): u-half tiles (bn<1024) go acc -> LDS -> causal
// depthwise conv (each M-tile holds exactly 2 complete l-sequences) + SiLU ->
// ucp; z-half tiles write Cb as usual. blockIdx.z batching via azs/wzs/czs.
// ---------------------------------------------------------------------------
template<bool AF32, int EPI>
__global__ __launch_bounds__(256) void k_gemm_mfma(
    const void* __restrict__ Av, int lda,
    const u16* __restrict__ W,
    float* __restrict__ C, int ldc,
    u16* __restrict__ Cb, int ldcb,
    const float* __restrict__ bias,
    int K, long azs, long wzs, long czs,
    const float* __restrict__ cwp, const float* __restrict__ cbp,
    u16* __restrict__ ucp)
{
  constexpr int LDT = 40;   // 32 + 8 pad (u16) -> conflict-free
  __shared__ __align__(16) u16 As[128 * LDT];
  __shared__ __align__(16) u16 Ws[128 * LDT];
  __shared__ __align__(16) u16 sU[(EPI == 2) ? 128 * 128 : 1];

  const int bz = blockIdx.z;
  const u16* Wz = W + (size_t)bz * wzs;

  const int tid = threadIdx.x;
  const int bm = blockIdx.x * 128;
  const int bn = blockIdx.y * 128;
  const int wave = tid >> 6;
  const int lane = tid & 63;
  const int wm = (wave & 1) * 64;
  const int wn = (wave >> 1) * 64;
  const int l15 = lane & 15;
  const int quad = lane >> 4;

  floatx4 acc[4][4];
#pragma unroll
  for (int i = 0; i < 4; ++i)
#pragma unroll
    for (int j = 0; j < 4; ++j) acc[i][j] = (floatx4){0.f, 0.f, 0.f, 0.f};

  const int r0 = tid >> 2;          // 0..63
  const int c0 = (tid & 3) * 8;     // 0,8,16,24

  const float* Af = (const float*)Av + (AF32 ? (size_t)bz * azs : 0);
  const u16*   Ab = (const u16*)Av + (AF32 ? 0 : (size_t)bz * azs);

  float4 fa0, fb0, fa1, fb1;        // AF32 staging regs
  short8 ra0, ra1, rw0, rw1;        // bf16 staging regs

  // prologue: load tile 0
  if constexpr (AF32) {
    const float* p0 = Af + (size_t)(bm + r0) * lda + c0;
    const float* p1 = Af + (size_t)(bm + r0 + 64) * lda + c0;
    fa0 = *(const float4*)p0; fb0 = *(const float4*)(p0 + 4);
    fa1 = *(const float4*)p1; fb1 = *(const float4*)(p1 + 4);
  } else {
    ra0 = *(const short8*)(Ab + (size_t)(bm + r0)      * lda + c0);
    ra1 = *(const short8*)(Ab + (size_t)(bm + r0 + 64) * lda + c0);
  }
  rw0 = *(const short8*)(Wz + (size_t)(bn + r0)      * K + c0);
  rw1 = *(const short8*)(Wz + (size_t)(bn + r0 + 64) * K + c0);

  for (int k0 = 0; k0 < K; k0 += 32) {
    // stage regs -> LDS
    if constexpr (AF32) {
      short8 s0, s1;
      s0[0] = (short)f2bfu(fa0.x); s0[1] = (short)f2bfu(fa0.y);
      s0[2] = (short)f2bfu(fa0.z); s0[3] = (short)f2bfu(fa0.w);
      s0[4] = (short)f2bfu(fb0.x); s0[5] = (short)f2bfu(fb0.y);
      s0[6] = (short)f2bfu(fb0.z); s0[7] = (short)f2bfu(fb0.w);
      s1[0] = (short)f2bfu(fa1.x); s1[1] = (short)f2bfu(fa1.y);
      s1[2] = (short)f2bfu(fa1.z); s1[3] = (short)f2bfu(fa1.w);
      s1[4] = (short)f2bfu(fb1.x); s1[5] = (short)f2bfu(fb1.y);
      s1[6] = (short)f2bfu(fb1.z); s1[7] = (short)f2bfu(fb1.w);
      *(short8*)&As[r0 * LDT + c0] = s0;
      *(short8*)&As[(r0 + 64) * LDT + c0] = s1;
    } else {
      *(short8*)&As[r0 * LDT + c0] = ra0;
      *(short8*)&As[(r0 + 64) * LDT + c0] = ra1;
    }
    *(short8*)&Ws[r0 * LDT + c0] = rw0;
    *(short8*)&Ws[(r0 + 64) * LDT + c0] = rw1;
    __syncthreads();

    // issue next tile's global loads (overlap with ds_read + MFMA below)
    const int kn = k0 + 32;
    if (kn < K) {
      if constexpr (AF32) {
        const float* p0 = Af + (size_t)(bm + r0) * lda + kn + c0;
        const float* p1 = Af + (size_t)(bm + r0 + 64) * lda + kn + c0;
        fa0 = *(const float4*)p0; fb0 = *(const float4*)(p0 + 4);
        fa1 = *(const float4*)p1; fb1 = *(const float4*)(p1 + 4);
      } else {
        ra0 = *(const short8*)(Ab + (size_t)(bm + r0)      * lda + kn + c0);
        ra1 = *(const short8*)(Ab + (size_t)(bm + r0 + 64) * lda + kn + c0);
      }
      rw0 = *(const short8*)(Wz + (size_t)(bn + r0)      * K + kn + c0);
      rw1 = *(const short8*)(Wz + (size_t)(bn + r0 + 64) * K + kn + c0);
    }

    short8 af[4], bf[4];
#pragma unroll
    for (int i = 0; i < 4; ++i)
      af[i] = *(const short8*)&As[(wm + i * 16 + l15) * LDT + quad * 8];
#pragma unroll
    for (int j = 0; j < 4; ++j)
      bf[j] = *(const short8*)&Ws[(wn + j * 16 + l15) * LDT + quad * 8];
#pragma unroll
    for (int i = 0; i < 4; ++i)
#pragma unroll
      for (int j = 0; j < 4; ++j)
        acc[i][j] = __builtin_amdgcn_mfma_f32_16x16x32_bf16(
            af[i], bf[j], acc[i][j], 0, 0, 0);
    __syncthreads();
  }

  if constexpr (EPI == 2) {
    if (bn < cDIN) {
      // u-half tile: acc -> LDS (bf16), then per-column causal conv + SiLU
#pragma unroll
      for (int i = 0; i < 4; ++i) {
        const int mi = wm + i * 16 + quad * 4;
#pragma unroll
        for (int j = 0; j < 4; ++j) {
          const int nj = wn + j * 16 + l15;
#pragma unroll
          for (int r = 0; r < 4; ++r)
            sU[(mi + r) * 128 + nj] = f2bfu(acc[i][j][r]);
        }
      }
      __syncthreads();
      const int c = tid & 127;          // tile column
      const int s = tid >> 7;           // sequence 0/1 within tile
      const int b = (bm >> 6) + s;      // global batch
      const int d = bn + c;             // global channel
      const float w0 = cwp[d * 4 + 0], w1 = cwp[d * 4 + 1];
      const float w2 = cwp[d * 4 + 2], w3 = cwp[d * 4 + 3];
      const float cbias = cbp[d];
      u16* dst = ucp + (size_t)b * cNP * cDIN + d;
      float u0 = 0.f, u1 = 0.f, u2 = 0.f;
#pragma unroll 8
      for (int l = 0; l < cNP; ++l) {
        float u3 = bfu2f(sU[(s * 64 + l) * 128 + c]);
        float v = w0 * u0 + w1 * u1 + w2 * u2 + w3 * u3 + cbias;
        dst[(size_t)l * cDIN] = f2bfu(silu_f(v));
        u0 = u1; u1 = u2; u2 = u3;
      }
      return;
    }
    // z-half tile: fall through to normal Cb write below
  }

#pragma unroll
  for (int i = 0; i < 4; ++i) {
    const int m0 = bm + wm + i * 16 + quad * 4;
#pragma unroll
    for (int j = 0; j < 4; ++j) {
      const int n = bn + wn + j * 16 + l15;
      if constexpr (EPI == 1) {
        const float bs = bias[n];
#pragma unroll
        for (int r = 0; r < 4; ++r)
          Cb[(size_t)(m0 + r) * ldcb + n + bz * czs] =
              f2bfu(softplus_f(acc[i][j][r] + bs));
      } else {
        if (C) {
#pragma unroll
          for (int r = 0; r < 4; ++r)
            C[(size_t)(m0 + r) * ldc + n + bz * czs] = acc[i][j][r];
        }
        if (Cb) {
#pragma unroll
          for (int r = 0; r < 4; ++r)
            Cb[(size_t)(m0 + r) * ldcb + n + bz * czs] = f2bfu(acc[i][j][r]);
        }
      }
    }
  }
}

// ---------------------------------------------------------------------------
// K1b: per-row LayerNorm (512 elems), wave per row -> bf16 out.
// seg_b[n,d] added before stats (faithful to reference).
// ---------------------------------------------------------------------------
__global__ __launch_bounds__(256) void k_ln(
    const float* __restrict__ xs, const float* __restrict__ sb,
    const float* __restrict__ ln_g, const float* __restrict__ ln_b,
    u16* __restrict__ x0b)
{
  const int tid = threadIdx.x;
  const int r = blockIdx.x * 4 + (tid >> 6);   // row (b*64+n)
  const int lane = tid & 63;
  const int d = lane * 8;
  const int n = r & 63;

  const float* row = xs + (size_t)r * cDIM + d;
  float4 a = *(const float4*)row;
  float4 b = *(const float4*)(row + 4);
  const float* sbp = sb + n * cDIM + d;
  float4 s0 = *(const float4*)sbp;
  float4 s1 = *(const float4*)(sbp + 4);
  a.x += s0.x; a.y += s0.y; a.z += s0.z; a.w += s0.w;
  b.x += s1.x; b.y += s1.y; b.z += s1.z; b.w += s1.w;

  float s  = a.x + a.y + a.z + a.w + b.x + b.y + b.z + b.w;
  float s2 = a.x*a.x + a.y*a.y + a.z*a.z + a.w*a.w
           + b.x*b.x + b.y*b.y + b.z*b.z + b.w*b.w;
#pragma unroll
  for (int m = 1; m < 64; m <<= 1) {
    s  += __shfl_xor(s,  m, 64);
    s2 += __shfl_xor(s2, m, 64);
  }
  const float mu = s * (1.f / cDIM);
  const float var = s2 * (1.f / cDIM) - mu * mu;
  const float rstd = rsqrtf(var + 1e-5f);

  const float* g = ln_g + n * cDIM + d;
  const float* be = ln_b + n * cDIM + d;
  float4 g0 = *(const float4*)g, g1 = *(const float4*)(g + 4);
  float4 b0 = *(const float4*)be, b1 = *(const float4*)(be + 4);
  ushort4 o0, o1;
  o0.x = f2bfu((a.x - mu) * rstd * g0.x + b0.x);
  o0.y = f2bfu((a.y - mu) * rstd * g0.y + b0.y);
  o0.z = f2bfu((a.z - mu) * rstd * g0.z + b0.z);
  o0.w = f2bfu((a.w - mu) * rstd * g0.w + b0.w);
  o1.x = f2bfu((b.x - mu) * rstd * g1.x + b1.x);
  o1.y = f2bfu((b.y - mu) * rstd * g1.y + b1.y);
  o1.z = f2bfu((b.z - mu) * rstd * g1.z + b1.z);
  o1.w = f2bfu((b.w - mu) * rstd * g1.w + b1.w);
  *(ushort4*)(x0b + (size_t)r * cDIM + d) = o0;
  *(ushort4*)(x0b + (size_t)r * cDIM + d + 4) = o1;
}

// ---------------------------------------------------------------------------
// K4a: x_proj MFMA split-K, pipelined. grid (M/128, 4): K chunks of 256 ->
// xpart[kc][8192][64] fp32. BM=128, BN=64, 128 threads = 2 waves.
// ---------------------------------------------------------------------------
__global__ __launch_bounds__(128) void k_xproj(
    const u16* __restrict__ A, const u16* __restrict__ W,
    float* __restrict__ xpart)
{
  constexpr int LDT = 40;
  __shared__ __align__(16) u16 As[128 * LDT];
  __shared__ __align__(16) u16 Ws[64 * LDT];

  const int tid = threadIdx.x;
  const int bm = blockIdx.x * 128;
  const int kbase = blockIdx.y * 256;
  const int wave = tid >> 6;
  const int lane = tid & 63;
  const int wm = wave * 64;
  const int l15 = lane & 15;
  const int quad = lane >> 4;

  floatx4 acc[4][4];
#pragma unroll
  for (int i = 0; i < 4; ++i)
#pragma unroll
    for (int j = 0; j < 4; ++j) acc[i][j] = (floatx4){0.f, 0.f, 0.f, 0.f};

  short8 rA[4], rW[2];
#pragma unroll
  for (int it = 0; it < 4; ++it) {
    int idx = tid + it * 128, row = idx >> 2, cc = (idx & 3) * 8;
    rA[it] = *(const short8*)(A + (size_t)(bm + row) * cDIN + kbase + cc);
  }
#pragma unroll
  for (int it = 0; it < 2; ++it) {
    int idx = tid + it * 128, row = idx >> 2, cc = (idx & 3) * 8;
    rW[it] = *(const short8*)(W + (size_t)row * cDIN + kbase + cc);
  }

  for (int kk = 0; kk < 256; kk += 32) {
#pragma unroll
    for (int it = 0; it < 4; ++it) {
      int idx = tid + it * 128, row = idx >> 2, cc = (idx & 3) * 8;
      *(short8*)&As[row * LDT + cc] = rA[it];
    }
#pragma unroll
    for (int it = 0; it < 2; ++it) {
      int idx = tid + it * 128, row = idx >> 2, cc = (idx & 3) * 8;
      *(short8*)&Ws[row * LDT + cc] = rW[it];
    }
    __syncthreads();

    if (kk + 32 < 256) {
      const int k0 = kbase + kk + 32;
#pragma unroll
      for (int it = 0; it < 4; ++it) {
        int idx = tid + it * 128, row = idx >> 2, cc = (idx & 3) * 8;
        rA[it] = *(const short8*)(A + (size_t)(bm + row) * cDIN + k0 + cc);
      }
#pragma unroll
      for (int it = 0; it < 2; ++it) {
        int idx = tid + it * 128, row = idx >> 2, cc = (idx & 3) * 8;
        rW[it] = *(const short8*)(W + (size_t)row * cDIN + k0 + cc);
      }
    }

    short8 af[4], bf[4];
#pragma unroll
    for (int i = 0; i < 4; ++i)
      af[i] = *(const short8*)&As[(wm + i * 16 + l15) * LDT + quad * 8];
#pragma unroll
    for (int j = 0; j < 4; ++j)
      bf[j] = *(const short8*)&Ws[(j * 16 + l15) * LDT + quad * 8];
#pragma unroll
    for (int i = 0; i < 4; ++i)
#pragma unroll
      for (int j = 0; j < 4; ++j)
        acc[i][j] = __builtin_amdgcn_mfma_f32_16x16x32_bf16(
            af[i], bf[j], acc[i][j], 0, 0, 0);
    __syncthreads();
  }

  float* out = xpart + (size_t)blockIdx.y * cBL * 64;
#pragma unroll
  for (int i = 0; i < 4; ++i) {
    const int m0 = bm + wm + i * 16 + quad * 4;
#pragma unroll
    for (int j = 0; j < 4; ++j) {
      const int n = j * 16 + l15;
#pragma unroll
      for (int r = 0; r < 4; ++r)
        out[(size_t)(m0 + r) * 64 + n] = acc[i][j][r];
    }
  }
}

// K4b: reduce 4 K-partials -> xdbl fp32 + xdbl16 bf16
__global__ __launch_bounds__(256) void k_xred(
    const float* __restrict__ xpart, float* __restrict__ C,
    u16* __restrict__ Cb)
{
  const int i = (blockIdx.x * 256 + threadIdx.x) * 4;
  float4 s = *(const float4*)(xpart + i);
#pragma unroll
  for (int k = 1; k < 4; ++k) {
    float4 v = *(const float4*)(xpart + (size_t)k * cBL * 64 + i);
    s.x += v.x; s.y += v.y; s.z += v.z; s.w += v.w;
  }
  *(float4*)(C + i) = s;
  ushort4 o;
  o.x = f2bfu(s.x); o.y = f2bfu(s.y); o.z = f2bfu(s.z); o.w = f2bfu(s.w);
  *(ushort4*)(Cb + i) = o;
}

// ---------------------------------------------------------------------------
// K6: selective scan + (y + uc*D) * silu(z). delta/z bf16 from xz16, uc bf16,
// y bf16 in place. grid (b, 4). l-loop chunked by 8, pipelined.
// Fast path: when A[n] == (n+1)*A[0] (S4D-real init, verified per channel at
// runtime), dA[n] = e1^(n+1) with e1 = exp(dv*A[0]) — 1 exp + 15 muls/step
// instead of 16 exps. Generic-exp fallback otherwise.
// ---------------------------------------------------------------------------
__global__ __launch_bounds__(256) void k_scan(
    const u16* __restrict__ xz16, u16* __restrict__ uc,
    const float* __restrict__ xdbl, const float* __restrict__ A_log,
    const float* __restrict__ Dp)
{
  const int b = blockIdx.x;
  const int tid = threadIdx.x;      // 0..255
  const int d = blockIdx.y * 256 + tid;

  __shared__ float sBC[cNP][32];    // [l][0:16]=B, [16:32]=C
  {
    const float4* src = (const float4*)xdbl;
    for (int i = tid; i < cNP * 8; i += 256) {
      int l = i >> 3, q = i & 7;
      *(float4*)&sBC[l][q * 4] = src[(size_t)(b * cNP + l) * 16 + 8 + q];
    }
  }

  float A[cDST];
  {
    const float4* ap = (const float4*)(A_log + (size_t)d * cDST);
#pragma unroll
    for (int q = 0; q < 4; ++q) {
      float4 w = ap[q];
      A[q*4+0] = -__expf(w.x); A[q*4+1] = -__expf(w.y);
      A[q*4+2] = -__expf(w.z); A[q*4+3] = -__expf(w.w);
    }
  }
  const float a1 = A[0];
  bool geom = true;
#pragma unroll
  for (int n = 1; n < cDST; ++n)
    geom = geom && (fabsf(A[n] - (float)(n + 1) * a1) <= 1e-4f * fabsf(A[n]));

  float h[cDST];
#pragma unroll
  for (int n = 0; n < cDST; ++n) h[n] = 0.f;
  const float Dv = Dp[d];
  __syncthreads();

  const u16* dsrc = xz16 + d;            // delta at xz16[row*2048 + d]
  const u16* zsrc = xz16 + cDIN + d;     // z
  u16* usrc = uc + d;                    // uc / y (bf16)
  const size_t rb = (size_t)b * cNP;

  float dvc[8], zvc[8], uvc[8];
#pragma unroll
  for (int i = 0; i < 8; ++i) {
    dvc[i] = bfu2f(dsrc[(rb + i) * cXZ]);
    zvc[i] = bfu2f(zsrc[(rb + i) * cXZ]);
    uvc[i] = bfu2f(usrc[(rb + i) * cDIN]);
  }

  if (geom) {
    for (int c = 0; c < 8; ++c) {
      float dvn[8], zvn[8], uvn[8];
      if (c < 7) {
#pragma unroll
        for (int i = 0; i < 8; ++i) {
          const size_t row = rb + (c + 1) * 8 + i;
          dvn[i] = bfu2f(dsrc[row * cXZ]);
          zvn[i] = bfu2f(zsrc[row * cXZ]);
          uvn[i] = bfu2f(usrc[row * cDIN]);
        }
      }
      u16 yo[8];
#pragma unroll
      for (int i = 0; i < 8; ++i) {
        const int l = c * 8 + i;
        const float dv = dvc[i], zv = zvc[i], uv = uvc[i];
        const float du = dv * uv;
        const float e1 = __expf(dv * a1);
        float dA = e1;
        float y = 0.f;
#pragma unroll
        for (int n = 0; n < cDST; ++n) {
          h[n] = dA * h[n] + du * sBC[l][n];
          y += h[n] * sBC[l][16 + n];
          dA *= e1;
        }
        y = (y + uv * Dv) * silu_f(zv);
        yo[i] = f2bfu(y);
      }
#pragma unroll
      for (int i = 0; i < 8; ++i)
        usrc[(rb + c * 8 + i) * cDIN] = yo[i];
      if (c < 7) {
#pragma unroll
        for (int i = 0; i < 8; ++i) {
          dvc[i] = dvn[i]; zvc[i] = zvn[i]; uvc[i] = uvn[i];
        }
      }
    }
  } else {
    for (int c = 0; c < 8; ++c) {
      float dvn[8], zvn[8], uvn[8];
      if (c < 7) {
#pragma unroll
        for (int i = 0; i < 8; ++i) {
          const size_t row = rb + (c + 1) * 8 + i;
          dvn[i] = bfu2f(dsrc[row * cXZ]);
          zvn[i] = bfu2f(zsrc[row * cXZ]);
          uvn[i] = bfu2f(usrc[row * cDIN]);
        }
      }
      u16 yo[8];
#pragma unroll
      for (int i = 0; i < 8; ++i) {
        const int l = c * 8 + i;
        const float dv = dvc[i], zv = zvc[i], uv = uvc[i];
        const float du = dv * uv;
        float y = 0.f;
#pragma unroll
        for (int n = 0; n < cDST; ++n) {
          float dA = __expf(dv * A[n]);
          h[n] = dA * h[n] + du * sBC[l][n];
          y += h[n] * sBC[l][16 + n];
        }
        y = (y + uv * Dv) * silu_f(zv);
        yo[i] = f2bfu(y);
      }
#pragma unroll
      for (int i = 0; i < 8; ++i)
        usrc[(rb + c * 8 + i) * cDIN] = yo[i];
      if (c < 7) {
#pragma unroll
        for (int i = 0; i < 8; ++i) {
          dvc[i] = dvn[i]; zvc[i] = zvn[i]; uvc[i] = uvn[i];
        }
      }
    }
  }
}

// ---------------------------------------------------------------------------
// K7a: head LN partial sums. grid (b, 8) -> pst[(b*8+chunk)*2 + {0,1}]
// ---------------------------------------------------------------------------
__global__ __launch_bounds__(256) void k_hstats1(
    const float* __restrict__ x, float* __restrict__ pst)
{
  const int b = blockIdx.x;
  const int chunk = blockIdx.y;
  const int tid = threadIdx.x;
  const float4* r4 = (const float4*)(x + (size_t)b * (cNP * cDIM) + chunk * 4096);
  float4 v = r4[tid];
  float4 w = r4[tid + 256];
  float4 u = r4[tid + 512];
  float4 t = r4[tid + 768];
  float s  = v.x + v.y + v.z + v.w + w.x + w.y + w.z + w.w
           + u.x + u.y + u.z + u.w + t.x + t.y + t.z + t.w;
  float s2 = v.x*v.x + v.y*v.y + v.z*v.z + v.w*v.w
           + w.x*w.x + w.y*w.y + w.z*w.z + w.w*w.w
           + u.x*u.x + u.y*u.y + u.z*u.z + u.w*u.w
           + t.x*t.x + t.y*t.y + t.z*t.z + t.w*t.w;
  __shared__ float red[512];
  red[tid] = s; red[256 + tid] = s2;
  __syncthreads();
  for (int st = 128; st > 0; st >>= 1) {
    if (tid < st) { red[tid] += red[tid + st]; red[256+tid] += red[256+tid+st]; }
    __syncthreads();
  }
  if (tid == 0) {
    pst[(b * 8 + chunk) * 2]     = red[0];
    pst[(b * 8 + chunk) * 2 + 1] = red[256];
  }
}

// K7b: finalize -> stats
__global__ __launch_bounds__(128) void k_hstats2(
    const float* __restrict__ pst, float* __restrict__ stats)
{
  const int b = threadIdx.x;
  float s = 0.f, s2 = 0.f;
#pragma unroll
  for (int c = 0; c < 8; ++c) {
    s  += pst[(b * 8 + c) * 2];
    s2 += pst[(b * 8 + c) * 2 + 1];
  }
  const float mu = s * (1.f / (cNP * cDIM));
  const float var = s2 * (1.f / (cNP * cDIM)) - mu * mu;
  stats[2 * b]     = mu;
  stats[2 * b + 1] = rsqrtf(var + 1e-5f);
}

// ---------------------------------------------------------------------------
// K8a: head split-K stage 1. grid (b, 16) -> hpart[(b*16+chunk)*32 + cls]
// ---------------------------------------------------------------------------
__global__ __launch_bounds__(256) void k_head1(
    const float* __restrict__ x, const float* __restrict__ stats,
    const float* __restrict__ hg, const float* __restrict__ hb,
    const u16* __restrict__ hwb, float* __restrict__ hpart)
{
  const int b = blockIdx.x;
  const int chunk = blockIdx.y;
  const int tid = threadIdx.x;
  const float mu = stats[2 * b], rstd = stats[2 * b + 1];
  const float* row = x + (size_t)b * (cNP * cDIM);
  const int k0 = chunk * 2048;

  float acc[cNCLS];
#pragma unroll
  for (int c = 0; c < cNCLS; ++c) acc[c] = 0.f;

#pragma unroll
  for (int it = 0; it < 4; ++it) {
    const int i0 = k0 + it * 512 + tid * 2;
    float xn0 = (row[i0]     - mu) * rstd * hg[i0]     + hb[i0];
    float xn1 = (row[i0 + 1] - mu) * rstd * hg[i0 + 1] + hb[i0 + 1];
#pragma unroll
    for (int c = 0; c < cNCLS; ++c) {
      u32 w2 = *(const u32*)(hwb + (size_t)c * (cNP * cDIM) + i0);
      acc[c] += xn0 * bfu2f((u16)(w2 & 0xffffu)) + xn1 * bfu2f((u16)(w2 >> 16));
    }
  }

  __shared__ float sred[cNCLS * 257];
#pragma unroll
  for (int c = 0; c < cNCLS; ++c) sred[c * 257 + tid] = acc[c];
  __syncthreads();
  if (tid < cNCLS * 8) {
    const int c = tid >> 3, p = tid & 7;
    float s = 0.f;
#pragma unroll
    for (int i = 0; i < 32; ++i) s += sred[c * 257 + p * 32 + i];
    s += __shfl_xor(s, 1, 64);
    s += __shfl_xor(s, 2, 64);
    s += __shfl_xor(s, 4, 64);
    if (p == 0) hpart[(size_t)(b * 16 + chunk) * cNCLS + c] = s;
  }
}

// K8b: head stage 2
__global__ __launch_bounds__(64) void k_head2(
    const float* __restrict__ hpart, const float* __restrict__ hbias,
    float* __restrict__ out)
{
  const int b = blockIdx.x;
  const int c = threadIdx.x;
  if (c < cNCLS) {
    float s = 0.f;
#pragma unroll
    for (int k = 0; k < 16; ++k)
      s += hpart[(size_t)(b * 16 + k) * cNCLS + c];
    out[b * cNCLS + c] = s + hbias[c];
  }
}

// ---------------------------------------------------------------------------
extern "C" void kernel_launch(void* const* d_in, const int* in_sizes, int n_in,
                              void* d_out, int out_size, void* d_ws, size_t ws_size,
                              hipStream_t stream)
{
  (void)in_sizes; (void)n_in; (void)out_size; (void)ws_size;

  const float* series    = (const float*)d_in[0];
  const float* seg_w     = (const float*)d_in[1];
  const float* seg_b     = (const float*)d_in[2];
  const float* ln_g      = (const float*)d_in[3];
  const float* ln_b      = (const float*)d_in[4];
  const float* in_proj_w = (const float*)d_in[5];
  const float* conv_w    = (const float*)d_in[6];
  const float* conv_b    = (const float*)d_in[7];
  const float* x_proj_w  = (const float*)d_in[8];
  const float* dt_proj_w = (const float*)d_in[9];
  const float* dt_proj_b = (const float*)d_in[10];
  const float* A_log     = (const float*)d_in[11];
  const float* Dp        = (const float*)d_in[12];
  const float* out_proj_w= (const float*)d_in[13];
  const float* head_ln_g = (const float*)d_in[14];
  const float* head_ln_b = (const float*)d_in[15];
  const float* head_w    = (const float*)d_in[16];
  const float* head_b    = (const float*)d_in[17];

  // workspace layout (~96 MB)
  u16*   xz16   = (u16*)d_ws;                          // [8192,2048] bf16 (delta | z)
  float* x0     = (float*)(xz16 + (size_t)cBL * cXZ);  // [8192,512] f32 (xsegf alias)
  float* xsegf  = x0;
  float* xdbl   = x0 + (size_t)cBL * cDIM;             // [8192,64] f32
  float* stats  = xdbl + (size_t)cBL * 64;             // [256]
  float* pst    = stats + 256;                         // [2048]
  float* hpart  = pst + 128 * 8 * 2;                   // [65536]
  u16*   x0b    = (u16*)(hpart + 128 * 16 * 32);       // [8192,512]
  u16*   wib    = x0b + (size_t)cBL * cDIM;            // [2,2048,512]
  u16*   wob    = wib + (size_t)2 * (2*cDIN) * cDIM;   // [2,512,1024]
  u16*   wdtb   = wob + (size_t)2 * cDIM * cDIN;       // [2,1024,32]
  u16*   wxb    = wdtb + (size_t)2 * cDIN * cDTR;      // [2,64,1024]
  u16*   xdbl16 = wxb + (size_t)2 * 64 * cDIN;         // [8192,64]
  u16*   wsegT  = xdbl16 + (size_t)cBL * 64;           // [64,512,128]
  u16*   ucb16  = wsegT + (size_t)cNP * cDIM * cP;     // [8192,1024]
  u16*   hwb    = ucb16 + (size_t)cBL * cDIN;          // [32,32768]
  // xpart aliases x0b (dead between in_proj read and out_proj write)
  float* xpart  = (float*)x0b;

  // weight conversions / transpose
  k_f2bf<<<(2 * (2*cDIN) * cDIM) / 1024, 256, 0, stream>>>(in_proj_w, wib);
  k_f2bf<<<(2 * cDIM * cDIN) / 1024, 256, 0, stream>>>(out_proj_w, wob);
  k_f2bf<<<(2 * cDIN * cDTR) / 1024, 256, 0, stream>>>(dt_proj_w, wdtb);
  k_f2bf<<<(2 * 64 * cDIN) / 1024, 256, 0, stream>>>(x_proj_w, wxb);
  k_f2bf<<<(cNCLS * cNP * cDIM) / 1024, 256, 0, stream>>>(head_w, hwb);
  k_segT<<<dim3(cP/32, cDIM/32, cNP), 256, 0, stream>>>(seg_w, wsegT);

  // seg projection (batched MFMA over n) -> xsegf, then (+seg_b) LN -> x0b
  k_gemm_mfma<true,0><<<dim3(1, cDIM/128, cNP), 256, 0, stream>>>(
      series, cNP * cP, wsegT, xsegf, cNP * cDIM, (u16*)nullptr, 0,
      nullptr, cP, (long)cP, (long)cDIM * cP, (long)cDIM,
      nullptr, nullptr, nullptr);
  k_ln<<<cBL / 4, 256, 0, stream>>>(xsegf, seg_b, ln_g, ln_b, x0b);

  for (int dep = 0; dep < 2; ++dep) {
    const u16*   wi  = wib  + (size_t)dep * (2*cDIN) * cDIM;
    const u16*   wo  = wob  + (size_t)dep * cDIM * cDIN;
    const u16*   wdt = wdtb + (size_t)dep * cDIN * cDTR;
    const u16*   wx  = wxb  + (size_t)dep * 64 * cDIN;
    const float* cwd = conv_w     + (size_t)dep * cDIN * 4;
    const float* cbd = conv_b     + (size_t)dep * cDIN;
    const float* bdt = dt_proj_b  + (size_t)dep * cDIN;
    const float* Ald = A_log      + (size_t)dep * cDIN * cDST;
    const float* Dd  = Dp         + (size_t)dep * cDIN;

    // in_proj + fused conv/SiLU: u-tiles -> ucb16, z-tiles -> xz16
    k_gemm_mfma<false,2><<<dim3(cBL/128, (2*cDIN)/128), 256, 0, stream>>>(
        x0b, cDIM, wi, (float*)nullptr, 0, xz16, cXZ, nullptr, cDIM, 0, 0, 0,
        cwd, cbd, ucb16);
    // x_proj split-K: xpart = uc @ wx^T (4 K-chunks), then reduce
    k_xproj<<<dim3(cBL / 128, 4), 128, 0, stream>>>(ucb16, wx, xpart);
    k_xred<<<(cBL * 64) / 1024, 256, 0, stream>>>(xpart, xdbl, xdbl16);
    // dt_proj + softplus -> delta bf16 into xz16 u-half  (MFMA, K=32)
    k_gemm_mfma<false,1><<<dim3(cBL/128, cDIN/128), 256, 0, stream>>>(
        xdbl16, 64, wdt, (float*)nullptr, 0, xz16, cXZ, bdt, cDTR, 0, 0, 0,
        nullptr, nullptr, nullptr);
    // scan + gate -> y bf16 in place into ucb16
    k_scan<<<dim3(cB, 4), 256, 0, stream>>>(xz16, ucb16, xdbl, Ald, Dd);
    // out_proj: (dep0: bf16 x0b) (dep1: fp32 x0) = y @ wo^T
    k_gemm_mfma<false,0><<<dim3(cBL/128, cDIM/128), 256, 0, stream>>>(
        ucb16, cDIN, wo,
        dep ? x0 : (float*)nullptr, cDIM,
        dep ? (u16*)nullptr : x0b, cDIM,
        nullptr, cDIN, 0, 0, 0,
        nullptr, nullptr, nullptr);
  }

  k_hstats1<<<dim3(cB, 8), 256, 0, stream>>>(x0, pst);
  k_hstats2<<<1, 128, 0, stream>>>(pst, stats);
  k_head1<<<dim3(cB, 16), 256, 0, stream>>>(x0, stats, head_ln_g, head_ln_b,
                                            hwb, hpart);
  k_head2<<<cB, 64, 0, stream>>>(hpart, head_b, (float*)d_out);
}

// Round 10
// 398.135 us; speedup vs baseline: 3.9656x; 1.0076x over previous
//
#include <hip/hip_runtime.h>

typedef unsigned short u16;
typedef unsigned int   u32;
typedef __attribute__((ext_vector_type(8))) short short8;
typedef __attribute__((ext_vector_type(4))) float floatx4;

static __device__ __forceinline__ float silu_f(float x){
  return x / (1.f + __expf(-x));
}
static __device__ __forceinline__ float bfu2f(u16 u){
  union { u32 i; float f; } v; v.i = ((u32)u) << 16; return v.f;
}
static __device__ __forceinline__ u16 f2bfu(float f){
  union { float f; u32 i; } v; v.f = f;
  u32 x = v.i;
  u32 r = (x + 0x7fffu + ((x >> 16) & 1u)) >> 16;   // round-nearest-even
  return (u16)r;
}
static __device__ __forceinline__ float softplus_f(float v){
  return fmaxf(v, 0.f) + log1pf(__expf(-fabsf(v)));
}

constexpr int cB = 128, cNP = 64, cP = 128, cDIM = 512, cDIN = 1024;
constexpr int cDST = 16, cDTR = 32, cNCLS = 32;
constexpr int cBL = cB * cNP;      // 8192 (b,l) rows
constexpr int cXZ = 2 * cDIN;      // 2048
constexpr long cPSTR = (long)cBL * 64;   // xpart chunk stride (floats)

// ---------------------------------------------------------------------------
// K0: merged fp32 -> bf16 conversion for all 5 weight tensors.
// Counts are in float4 units; total grid covers the concatenation.
// ---------------------------------------------------------------------------
__global__ __launch_bounds__(256) void k_f2bf_all(
    const float* __restrict__ s0, u16* __restrict__ d0, int n0,
    const float* __restrict__ s1, u16* __restrict__ d1, int n1,
    const float* __restrict__ s2, u16* __restrict__ d2, int n2,
    const float* __restrict__ s3, u16* __restrict__ d3, int n3,
    const float* __restrict__ s4, u16* __restrict__ d4, int n4)
{
  int i = blockIdx.x * 256 + threadIdx.x;
  const float* s; u16* d;
  if (i < n0) { s = s0; d = d0; }
  else {
    i -= n0;
    if (i < n1) { s = s1; d = d1; }
    else {
      i -= n1;
      if (i < n2) { s = s2; d = d2; }
      else {
        i -= n2;
        if (i < n3) { s = s3; d = d3; }
        else {
          i -= n3;
          if (i >= n4) return;
          s = s4; d = d4;
        }
      }
    }
  }
  const size_t off = (size_t)i * 4;
  float4 v = *(const float4*)(s + off);
  ushort4 o;
  o.x = f2bfu(v.x); o.y = f2bfu(v.y); o.z = f2bfu(v.z); o.w = f2bfu(v.w);
  *(ushort4*)(d + off) = o;
}

// ---------------------------------------------------------------------------
// K0b: seg_w[n,p,d] -> wsegT[n,d,p] (bf16). 32x32 tiles, 256 threads.
// ---------------------------------------------------------------------------
__global__ __launch_bounds__(256) void k_segT(
    const float* __restrict__ src, u16* __restrict__ dst)
{
  const int n = blockIdx.z;
  const int p0 = blockIdx.x * 32;
  const int d0 = blockIdx.y * 32;
  const int tx = threadIdx.x & 31;
  const int ty = threadIdx.x >> 5;     // 0..7
  __shared__ float t[32][33];
#pragma unroll
  for (int r = 0; r < 4; ++r)
    t[ty + r * 8][tx] = src[(size_t)n * (cP * cDIM) + (p0 + ty + r * 8) * cDIM + d0 + tx];
  __syncthreads();
#pragma unroll
  for (int r = 0; r < 4; ++r)
    dst[(size_t)n * (cDIM * cP) + (d0 + ty + r * 8) * cP + p0 + tx] =
        f2bfu(t[tx][ty + r * 8]);
}

// ---------------------------------------------------------------------------
// K2: bf16 MFMA GEMM, software-pipelined (register double-buffer).
// C[M,N] = A[M,K] * W[N,K]^T. 128x128 tile, BK=32, 4 waves (2x2 of 64x64).
// AMODE: 0 = A bf16; 1 = A fp32 (converted in staging);
//        2 = A is 4 split-K fp32 partials (rows 64 wide, chunk stride azs,
//            summed in staging — bit-identical to the old xred order; K=32).
// EPI=1: Cb = bf16(softplus(acc + bias[n])).
// EPI=2 (in_proj+conv fusion): u-half tiles (bn<1024) -> LDS -> causal conv
// + SiLU -> ucp; z-half tiles write Cb as usual. bz batching via azs/wzs/czs.
// ---------------------------------------------------------------------------
template<int AMODE, int EPI>
__global__ __launch_bounds__(256) void k_gemm_mfma(
    const void* __restrict__ Av, int lda,
    const u16* __restrict__ W,
    float* __restrict__ C, int ldc,
    u16* __restrict__ Cb, int ldcb,
    const float* __restrict__ bias,
    int K, long azs, long wzs, long czs,
    const float* __restrict__ cwp, const float* __restrict__ cbp,
    u16* __restrict__ ucp)
{
  constexpr int LDT = 40;   // 32 + 8 pad (u16) -> conflict-free
  __shared__ __align__(16) u16 As[128 * LDT];
  __shared__ __align__(16) u16 Ws[128 * LDT];
  __shared__ __align__(16) u16 sU[(EPI == 2) ? 128 * 128 : 1];

  const int bz = blockIdx.z;
  const u16* Wz = W + (size_t)bz * wzs;

  const int tid = threadIdx.x;
  const int bm = blockIdx.x * 128;
  const int bn = blockIdx.y * 128;
  const int wave = tid >> 6;
  const int lane = tid & 63;
  const int wm = (wave & 1) * 64;
  const int wn = (wave >> 1) * 64;
  const int l15 = lane & 15;
  const int quad = lane >> 4;

  floatx4 acc[4][4];
#pragma unroll
  for (int i = 0; i < 4; ++i)
#pragma unroll
    for (int j = 0; j < 4; ++j) acc[i][j] = (floatx4){0.f, 0.f, 0.f, 0.f};

  const int r0 = tid >> 2;          // 0..63
  const int c0 = (tid & 3) * 8;     // 0,8,16,24

  const float* Af = (const float*)Av + (AMODE == 1 ? (size_t)bz * azs : 0);
  const u16*   Ab = (const u16*)Av + (AMODE == 0 ? (size_t)bz * azs : 0);

  float4 fa0, fb0, fa1, fb1;        // fp32 staging regs
  short8 ra0, ra1, rw0, rw1;        // bf16 staging regs

  // prologue: load tile 0
  if constexpr (AMODE == 1) {
    const float* p0 = Af + (size_t)(bm + r0) * lda + c0;
    const float* p1 = Af + (size_t)(bm + r0 + 64) * lda + c0;
    fa0 = *(const float4*)p0; fb0 = *(const float4*)(p0 + 4);
    fa1 = *(const float4*)p1; fb1 = *(const float4*)(p1 + 4);
  } else if constexpr (AMODE == 0) {
    ra0 = *(const short8*)(Ab + (size_t)(bm + r0)      * lda + c0);
    ra1 = *(const short8*)(Ab + (size_t)(bm + r0 + 64) * lda + c0);
  }
  rw0 = *(const short8*)(Wz + (size_t)(bn + r0)      * K + c0);
  rw1 = *(const short8*)(Wz + (size_t)(bn + r0 + 64) * K + c0);

  for (int k0 = 0; k0 < K; k0 += 32) {
    // stage -> LDS
    if constexpr (AMODE == 1) {
      short8 s0, s1;
      s0[0] = (short)f2bfu(fa0.x); s0[1] = (short)f2bfu(fa0.y);
      s0[2] = (short)f2bfu(fa0.z); s0[3] = (short)f2bfu(fa0.w);
      s0[4] = (short)f2bfu(fb0.x); s0[5] = (short)f2bfu(fb0.y);
      s0[6] = (short)f2bfu(fb0.z); s0[7] = (short)f2bfu(fb0.w);
      s1[0] = (short)f2bfu(fa1.x); s1[1] = (short)f2bfu(fa1.y);
      s1[2] = (short)f2bfu(fa1.z); s1[3] = (short)f2bfu(fa1.w);
      s1[4] = (short)f2bfu(fb1.x); s1[5] = (short)f2bfu(fb1.y);
      s1[6] = (short)f2bfu(fb1.z); s1[7] = (short)f2bfu(fb1.w);
      *(short8*)&As[r0 * LDT + c0] = s0;
      *(short8*)&As[(r0 + 64) * LDT + c0] = s1;
    } else if constexpr (AMODE == 0) {
      *(short8*)&As[r0 * LDT + c0] = ra0;
      *(short8*)&As[(r0 + 64) * LDT + c0] = ra1;
    } else {
      // AMODE==2: sum 4 fp32 partials (rows 64 floats wide), K==32 (one iter)
      const float* base = (const float*)Av;
#pragma unroll
      for (int h = 0; h < 2; ++h) {
        const float* p = base + (size_t)(bm + r0 + h * 64) * 64 + c0;
        float4 a = *(const float4*)p;
        float4 b = *(const float4*)(p + 4);
#pragma unroll
        for (int kc = 1; kc < 4; ++kc) {
          const float* q = p + (size_t)kc * azs;
          float4 va = *(const float4*)q, vb = *(const float4*)(q + 4);
          a.x += va.x; a.y += va.y; a.z += va.z; a.w += va.w;
          b.x += vb.x; b.y += vb.y; b.z += vb.z; b.w += vb.w;
        }
        short8 st;
        st[0] = (short)f2bfu(a.x); st[1] = (short)f2bfu(a.y);
        st[2] = (short)f2bfu(a.z); st[3] = (short)f2bfu(a.w);
        st[4] = (short)f2bfu(b.x); st[5] = (short)f2bfu(b.y);
        st[6] = (short)f2bfu(b.z); st[7] = (short)f2bfu(b.w);
        *(short8*)&As[(r0 + h * 64) * LDT + c0] = st;
      }
    }
    *(short8*)&Ws[r0 * LDT + c0] = rw0;
    *(short8*)&Ws[(r0 + 64) * LDT + c0] = rw1;
    __syncthreads();

    // issue next tile's global loads (overlap with ds_read + MFMA below)
    const int kn = k0 + 32;
    if (kn < K) {
      if constexpr (AMODE == 1) {
        const float* p0 = Af + (size_t)(bm + r0) * lda + kn + c0;
        const float* p1 = Af + (size_t)(bm + r0 + 64) * lda + kn + c0;
        fa0 = *(const float4*)p0; fb0 = *(const float4*)(p0 + 4);
        fa1 = *(const float4*)p1; fb1 = *(const float4*)(p1 + 4);
      } else if constexpr (AMODE == 0) {
        ra0 = *(const short8*)(Ab + (size_t)(bm + r0)      * lda + kn + c0);
        ra1 = *(const short8*)(Ab + (size_t)(bm + r0 + 64) * lda + kn + c0);
      }
      rw0 = *(const short8*)(Wz + (size_t)(bn + r0)      * K + kn + c0);
      rw1 = *(const short8*)(Wz + (size_t)(bn + r0 + 64) * K + kn + c0);
    }

    short8 af[4], bf[4];
#pragma unroll
    for (int i = 0; i < 4; ++i)
      af[i] = *(const short8*)&As[(wm + i * 16 + l15) * LDT + quad * 8];
#pragma unroll
    for (int j = 0; j < 4; ++j)
      bf[j] = *(const short8*)&Ws[(wn + j * 16 + l15) * LDT + quad * 8];
#pragma unroll
    for (int i = 0; i < 4; ++i)
#pragma unroll
      for (int j = 0; j < 4; ++j)
        acc[i][j] = __builtin_amdgcn_mfma_f32_16x16x32_bf16(
            af[i], bf[j], acc[i][j], 0, 0, 0);
    __syncthreads();
  }

  if constexpr (EPI == 2) {
    if (bn < cDIN) {
      // u-half tile: acc -> LDS (bf16), then per-column causal conv + SiLU
#pragma unroll
      for (int i = 0; i < 4; ++i) {
        const int mi = wm + i * 16 + quad * 4;
#pragma unroll
        for (int j = 0; j < 4; ++j) {
          const int nj = wn + j * 16 + l15;
#pragma unroll
          for (int r = 0; r < 4; ++r)
            sU[(mi + r) * 128 + nj] = f2bfu(acc[i][j][r]);
        }
      }
      __syncthreads();
      const int c = tid & 127;          // tile column
      const int s = tid >> 7;           // sequence 0/1 within tile
      const int b = (bm >> 6) + s;      // global batch
      const int d = bn + c;             // global channel
      const float w0 = cwp[d * 4 + 0], w1 = cwp[d * 4 + 1];
      const float w2 = cwp[d * 4 + 2], w3 = cwp[d * 4 + 3];
      const float cbias = cbp[d];
      u16* dst = ucp + (size_t)b * cNP * cDIN + d;
      float u0 = 0.f, u1 = 0.f, u2 = 0.f;
#pragma unroll 8
      for (int l = 0; l < cNP; ++l) {
        float u3 = bfu2f(sU[(s * 64 + l) * 128 + c]);
        float v = w0 * u0 + w1 * u1 + w2 * u2 + w3 * u3 + cbias;
        dst[(size_t)l * cDIN] = f2bfu(silu_f(v));
        u0 = u1; u1 = u2; u2 = u3;
      }
      return;
    }
  }

#pragma unroll
  for (int i = 0; i < 4; ++i) {
    const int m0 = bm + wm + i * 16 + quad * 4;
#pragma unroll
    for (int j = 0; j < 4; ++j) {
      const int n = bn + wn + j * 16 + l15;
      if constexpr (EPI == 1) {
        const float bs = bias[n];
#pragma unroll
        for (int r = 0; r < 4; ++r)
          Cb[(size_t)(m0 + r) * ldcb + n + bz * czs] =
              f2bfu(softplus_f(acc[i][j][r] + bs));
      } else {
        if (C) {
#pragma unroll
          for (int r = 0; r < 4; ++r)
            C[(size_t)(m0 + r) * ldc + n + bz * czs] = acc[i][j][r];
        }
        if (Cb) {
#pragma unroll
          for (int r = 0; r < 4; ++r)
            Cb[(size_t)(m0 + r) * ldcb + n + bz * czs] = f2bfu(acc[i][j][r]);
        }
      }
    }
  }
}

// ---------------------------------------------------------------------------
// K1b: per-row LayerNorm (512 elems), wave per row -> bf16 out.
// seg_b[n,d] added before stats (faithful to reference).
// ---------------------------------------------------------------------------
__global__ __launch_bounds__(256) void k_ln(
    const float* __restrict__ xs, const float* __restrict__ sb,
    const float* __restrict__ ln_g, const float* __restrict__ ln_b,
    u16* __restrict__ x0b)
{
  const int tid = threadIdx.x;
  const int r = blockIdx.x * 4 + (tid >> 6);   // row (b*64+n)
  const int lane = tid & 63;
  const int d = lane * 8;
  const int n = r & 63;

  const float* row = xs + (size_t)r * cDIM + d;
  float4 a = *(const float4*)row;
  float4 b = *(const float4*)(row + 4);
  const float* sbp = sb + n * cDIM + d;
  float4 s0 = *(const float4*)sbp;
  float4 s1 = *(const float4*)(sbp + 4);
  a.x += s0.x; a.y += s0.y; a.z += s0.z; a.w += s0.w;
  b.x += s1.x; b.y += s1.y; b.z += s1.z; b.w += s1.w;

  float s  = a.x + a.y + a.z + a.w + b.x + b.y + b.z + b.w;
  float s2 = a.x*a.x + a.y*a.y + a.z*a.z + a.w*a.w
           + b.x*b.x + b.y*b.y + b.z*b.z + b.w*b.w;
#pragma unroll
  for (int m = 1; m < 64; m <<= 1) {
    s  += __shfl_xor(s,  m, 64);
    s2 += __shfl_xor(s2, m, 64);
  }
  const float mu = s * (1.f / cDIM);
  const float var = s2 * (1.f / cDIM) - mu * mu;
  const float rstd = rsqrtf(var + 1e-5f);

  const float* g = ln_g + n * cDIM + d;
  const float* be = ln_b + n * cDIM + d;
  float4 g0 = *(const float4*)g, g1 = *(const float4*)(g + 4);
  float4 b0 = *(const float4*)be, b1 = *(const float4*)(be + 4);
  ushort4 o0, o1;
  o0.x = f2bfu((a.x - mu) * rstd * g0.x + b0.x);
  o0.y = f2bfu((a.y - mu) * rstd * g0.y + b0.y);
  o0.z = f2bfu((a.z - mu) * rstd * g0.z + b0.z);
  o0.w = f2bfu((a.w - mu) * rstd * g0.w + b0.w);
  o1.x = f2bfu((b.x - mu) * rstd * g1.x + b1.x);
  o1.y = f2bfu((b.y - mu) * rstd * g1.y + b1.y);
  o1.z = f2bfu((b.z - mu) * rstd * g1.z + b1.z);
  o1.w = f2bfu((b.w - mu) * rstd * g1.w + b1.w);
  *(ushort4*)(x0b + (size_t)r * cDIM + d) = o0;
  *(ushort4*)(x0b + (size_t)r * cDIM + d + 4) = o1;
}

// ---------------------------------------------------------------------------
// K4a: x_proj MFMA split-K, pipelined. grid (M/128, 4): K chunks of 256 ->
// xpart[kc][8192][64] fp32. BM=128, BN=64, 128 threads = 2 waves.
// ---------------------------------------------------------------------------
__global__ __launch_bounds__(128) void k_xproj(
    const u16* __restrict__ A, const u16* __restrict__ W,
    float* __restrict__ xpart)
{
  constexpr int LDT = 40;
  __shared__ __align__(16) u16 As[128 * LDT];
  __shared__ __align__(16) u16 Ws[64 * LDT];

  const int tid = threadIdx.x;
  const int bm = blockIdx.x * 128;
  const int kbase = blockIdx.y * 256;
  const int wave = tid >> 6;
  const int lane = tid & 63;
  const int wm = wave * 64;
  const int l15 = lane & 15;
  const int quad = lane >> 4;

  floatx4 acc[4][4];
#pragma unroll
  for (int i = 0; i < 4; ++i)
#pragma unroll
    for (int j = 0; j < 4; ++j) acc[i][j] = (floatx4){0.f, 0.f, 0.f, 0.f};

  short8 rA[4], rW[2];
#pragma unroll
  for (int it = 0; it < 4; ++it) {
    int idx = tid + it * 128, row = idx >> 2, cc = (idx & 3) * 8;
    rA[it] = *(const short8*)(A + (size_t)(bm + row) * cDIN + kbase + cc);
  }
#pragma unroll
  for (int it = 0; it < 2; ++it) {
    int idx = tid + it * 128, row = idx >> 2, cc = (idx & 3) * 8;
    rW[it] = *(const short8*)(W + (size_t)row * cDIN + kbase + cc);
  }

  for (int kk = 0; kk < 256; kk += 32) {
#pragma unroll
    for (int it = 0; it < 4; ++it) {
      int idx = tid + it * 128, row = idx >> 2, cc = (idx & 3) * 8;
      *(short8*)&As[row * LDT + cc] = rA[it];
    }
#pragma unroll
    for (int it = 0; it < 2; ++it) {
      int idx = tid + it * 128, row = idx >> 2, cc = (idx & 3) * 8;
      *(short8*)&Ws[row * LDT + cc] = rW[it];
    }
    __syncthreads();

    if (kk + 32 < 256) {
      const int k0 = kbase + kk + 32;
#pragma unroll
      for (int it = 0; it < 4; ++it) {
        int idx = tid + it * 128, row = idx >> 2, cc = (idx & 3) * 8;
        rA[it] = *(const short8*)(A + (size_t)(bm + row) * cDIN + k0 + cc);
      }
#pragma unroll
      for (int it = 0; it < 2; ++it) {
        int idx = tid + it * 128, row = idx >> 2, cc = (idx & 3) * 8;
        rW[it] = *(const short8*)(W + (size_t)row * cDIN + k0 + cc);
      }
    }

    short8 af[4], bf[4];
#pragma unroll
    for (int i = 0; i < 4; ++i)
      af[i] = *(const short8*)&As[(wm + i * 16 + l15) * LDT + quad * 8];
#pragma unroll
    for (int j = 0; j < 4; ++j)
      bf[j] = *(const short8*)&Ws[(j * 16 + l15) * LDT + quad * 8];
#pragma unroll
    for (int i = 0; i < 4; ++i)
#pragma unroll
      for (int j = 0; j < 4; ++j)
        acc[i][j] = __builtin_amdgcn_mfma_f32_16x16x32_bf16(
            af[i], bf[j], acc[i][j], 0, 0, 0);
    __syncthreads();
  }

  float* out = xpart + (size_t)blockIdx.y * cPSTR;
#pragma unroll
  for (int i = 0; i < 4; ++i) {
    const int m0 = bm + wm + i * 16 + quad * 4;
#pragma unroll
    for (int j = 0; j < 4; ++j) {
      const int n = j * 16 + l15;
#pragma unroll
      for (int r = 0; r < 4; ++r)
        out[(size_t)(m0 + r) * 64 + n] = acc[i][j][r];
    }
  }
}

// ---------------------------------------------------------------------------
// K6: selective scan + (y + uc*D) * silu(z). delta/z bf16 from xz16, uc bf16,
// y bf16 in place. B/C summed from the 4 xpart partials at staging (same
// order as the old xred -> bit-identical). grid (b, 4), chunked-by-8 loads.
// Geom fast path: A[n] = (n+1)A[0] (verified per channel) -> dA[n] = e1^(n+1)
// via a 4-chain power tree; y in 4 accumulators (short dep chains).
// ---------------------------------------------------------------------------
__global__ __launch_bounds__(256) void k_scan(
    const u16* __restrict__ xz16, u16* __restrict__ uc,
    const float* __restrict__ xpart, const float* __restrict__ A_log,
    const float* __restrict__ Dp)
{
  const int b = blockIdx.x;
  const int tid = threadIdx.x;      // 0..255
  const int d = blockIdx.y * 256 + tid;

  __shared__ float sBC[cNP][32];    // [l][0:16]=B, [16:32]=C
  {
    for (int i = tid; i < cNP * 8; i += 256) {
      int l = i >> 3, q = i & 7;
      const float* p = xpart + (size_t)(b * cNP + l) * 64 + 32 + q * 4;
      float4 s = *(const float4*)p;
#pragma unroll
      for (int kc = 1; kc < 4; ++kc) {
        float4 v = *(const float4*)(p + (size_t)kc * cPSTR);
        s.x += v.x; s.y += v.y; s.z += v.z; s.w += v.w;
      }
      *(float4*)&sBC[l][q * 4] = s;
    }
  }

  float A[cDST];
  {
    const float4* ap = (const float4*)(A_log + (size_t)d * cDST);
#pragma unroll
    for (int q = 0; q < 4; ++q) {
      float4 w = ap[q];
      A[q*4+0] = -__expf(w.x); A[q*4+1] = -__expf(w.y);
      A[q*4+2] = -__expf(w.z); A[q*4+3] = -__expf(w.w);
    }
  }
  const float a1 = A[0];
  bool geom = true;
#pragma unroll
  for (int n = 1; n < cDST; ++n)
    geom = geom && (fabsf(A[n] - (float)(n + 1) * a1) <= 1e-4f * fabsf(A[n]));

  float h[cDST];
#pragma unroll
  for (int n = 0; n < cDST; ++n) h[n] = 0.f;
  const float Dv = Dp[d];
  __syncthreads();

  const u16* dsrc = xz16 + d;            // delta at xz16[row*2048 + d]
  const u16* zsrc = xz16 + cDIN + d;     // z
  u16* usrc = uc + d;                    // uc / y (bf16)
  const size_t rb = (size_t)b * cNP;

  float dvc[8], zvc[8], uvc[8];
#pragma unroll
  for (int i = 0; i < 8; ++i) {
    dvc[i] = bfu2f(dsrc[(rb + i) * cXZ]);
    zvc[i] = bfu2f(zsrc[(rb + i) * cXZ]);
    uvc[i] = bfu2f(usrc[(rb + i) * cDIN]);
  }

  if (geom) {
    for (int c = 0; c < 8; ++c) {
      float dvn[8], zvn[8], uvn[8];
      if (c < 7) {
#pragma unroll
        for (int i = 0; i < 8; ++i) {
          const size_t row = rb + (c + 1) * 8 + i;
          dvn[i] = bfu2f(dsrc[row * cXZ]);
          zvn[i] = bfu2f(zsrc[row * cXZ]);
          uvn[i] = bfu2f(usrc[row * cDIN]);
        }
      }
      u16 yo[8];
#pragma unroll
      for (int i = 0; i < 8; ++i) {
        const int l = c * 8 + i;
        const float dv = dvc[i], zv = zvc[i], uv = uvc[i];
        const float du = dv * uv;
        const float e1 = __expf(dv * a1);
        const float e2 = e1 * e1;
        const float e4 = e2 * e2;
        float p0 = e1, p1 = e2, p2 = e2 * e1, p3 = e4;
        float y0 = 0.f, y1 = 0.f, y2 = 0.f, y3 = 0.f;
#pragma unroll
        for (int g = 0; g < 4; ++g) {
          const int n = g * 4;
          h[n+0] = p0 * h[n+0] + du * sBC[l][n+0];
          y0 += h[n+0] * sBC[l][16 + n+0];
          h[n+1] = p1 * h[n+1] + du * sBC[l][n+1];
          y1 += h[n+1] * sBC[l][16 + n+1];
          h[n+2] = p2 * h[n+2] + du * sBC[l][n+2];
          y2 += h[n+2] * sBC[l][16 + n+2];
          h[n+3] = p3 * h[n+3] + du * sBC[l][n+3];
          y3 += h[n+3] * sBC[l][16 + n+3];
          if (g < 3) { p0 *= e4; p1 *= e4; p2 *= e4; p3 *= e4; }
        }
        float y = (y0 + y1) + (y2 + y3);
        y = (y + uv * Dv) * silu_f(zv);
        yo[i] = f2bfu(y);
      }
#pragma unroll
      for (int i = 0; i < 8; ++i)
        usrc[(rb + c * 8 + i) * cDIN] = yo[i];
      if (c < 7) {
#pragma unroll
        for (int i = 0; i < 8; ++i) {
          dvc[i] = dvn[i]; zvc[i] = zvn[i]; uvc[i] = uvn[i];
        }
      }
    }
  } else {
    for (int c = 0; c < 8; ++c) {
      float dvn[8], zvn[8], uvn[8];
      if (c < 7) {
#pragma unroll
        for (int i = 0; i < 8; ++i) {
          const size_t row = rb + (c + 1) * 8 + i;
          dvn[i] = bfu2f(dsrc[row * cXZ]);
          zvn[i] = bfu2f(zsrc[row * cXZ]);
          uvn[i] = bfu2f(usrc[row * cDIN]);
        }
      }
      u16 yo[8];
#pragma unroll
      for (int i = 0; i < 8; ++i) {
        const int l = c * 8 + i;
        const float dv = dvc[i], zv = zvc[i], uv = uvc[i];
        const float du = dv * uv;
        float y0 = 0.f, y1 = 0.f, y2 = 0.f, y3 = 0.f;
#pragma unroll
        for (int n = 0; n < cDST; n += 4) {
          float dA0 = __expf(dv * A[n+0]);
          float dA1 = __expf(dv * A[n+1]);
          float dA2 = __expf(dv * A[n+2]);
          float dA3 = __expf(dv * A[n+3]);
          h[n+0] = dA0 * h[n+0] + du * sBC[l][n+0];
          y0 += h[n+0] * sBC[l][16 + n+0];
          h[n+1] = dA1 * h[n+1] + du * sBC[l][n+1];
          y1 += h[n+1] * sBC[l][16 + n+1];
          h[n+2] = dA2 * h[n+2] + du * sBC[l][n+2];
          y2 += h[n+2] * sBC[l][16 + n+2];
          h[n+3] = dA3 * h[n+3] + du * sBC[l][n+3];
          y3 += h[n+3] * sBC[l][16 + n+3];
        }
        float y = (y0 + y1) + (y2 + y3);
        y = (y + uv * Dv) * silu_f(zv);
        yo[i] = f2bfu(y);
      }
#pragma unroll
      for (int i = 0; i < 8; ++i)
        usrc[(rb + c * 8 + i) * cDIN] = yo[i];
      if (c < 7) {
#pragma unroll
        for (int i = 0; i < 8; ++i) {
          dvc[i] = dvn[i]; zvc[i] = zvn[i]; uvc[i] = uvn[i];
        }
      }
    }
  }
}

// ---------------------------------------------------------------------------
// K7a: head LN partial sums. grid (b, 8) -> pst[(b*8+chunk)*2 + {0,1}]
// ---------------------------------------------------------------------------
__global__ __launch_bounds__(256) void k_hstats1(
    const float* __restrict__ x, float* __restrict__ pst)
{
  const int b = blockIdx.x;
  const int chunk = blockIdx.y;
  const int tid = threadIdx.x;
  const float4* r4 = (const float4*)(x + (size_t)b * (cNP * cDIM) + chunk * 4096);
  float4 v = r4[tid];
  float4 w = r4[tid + 256];
  float4 u = r4[tid + 512];
  float4 t = r4[tid + 768];
  float s  = v.x + v.y + v.z + v.w + w.x + w.y + w.z + w.w
           + u.x + u.y + u.z + u.w + t.x + t.y + t.z + t.w;
  float s2 = v.x*v.x + v.y*v.y + v.z*v.z + v.w*v.w
           + w.x*w.x + w.y*w.y + w.z*w.z + w.w*w.w
           + u.x*u.x + u.y*u.y + u.z*u.z + u.w*u.w
           + t.x*t.x + t.y*t.y + t.z*t.z + t.w*t.w;
  __shared__ float red[512];
  red[tid] = s; red[256 + tid] = s2;
  __syncthreads();
  for (int st = 128; st > 0; st >>= 1) {
    if (tid < st) { red[tid] += red[tid + st]; red[256+tid] += red[256+tid+st]; }
    __syncthreads();
  }
  if (tid == 0) {
    pst[(b * 8 + chunk) * 2]     = red[0];
    pst[(b * 8 + chunk) * 2 + 1] = red[256];
  }
}

// K7b: finalize -> stats
__global__ __launch_bounds__(128) void k_hstats2(
    const float* __restrict__ pst, float* __restrict__ stats)
{
  const int b = threadIdx.x;
  float s = 0.f, s2 = 0.f;
#pragma unroll
  for (int c = 0; c < 8; ++c) {
    s  += pst[(b * 8 + c) * 2];
    s2 += pst[(b * 8 + c) * 2 + 1];
  }
  const float mu = s * (1.f / (cNP * cDIM));
  const float var = s2 * (1.f / (cNP * cDIM)) - mu * mu;
  stats[2 * b]     = mu;
  stats[2 * b + 1] = rsqrtf(var + 1e-5f);
}

// ---------------------------------------------------------------------------
// K8a: head split-K stage 1. grid (b, 16) -> hpart[(b*16+chunk)*32 + cls]
// ---------------------------------------------------------------------------
__global__ __launch_bounds__(256) void k_head1(
    const float* __restrict__ x, const float* __restrict__ stats,
    const float* __restrict__ hg, const float* __restrict__ hb,
    const u16* __restrict__ hwb, float* __restrict__ hpart)
{
  const int b = blockIdx.x;
  const int chunk = blockIdx.y;
  const int tid = threadIdx.x;
  const float mu = stats[2 * b], rstd = stats[2 * b + 1];
  const float* row = x + (size_t)b * (cNP * cDIM);
  const int k0 = chunk * 2048;

  float acc[cNCLS];
#pragma unroll
  for (int c = 0; c < cNCLS; ++c) acc[c] = 0.f;

#pragma unroll
  for (int it = 0; it < 4; ++it) {
    const int i0 = k0 + it * 512 + tid * 2;
    float xn0 = (row[i0]     - mu) * rstd * hg[i0]     + hb[i0];
    float xn1 = (row[i0 + 1] - mu) * rstd * hg[i0 + 1] + hb[i0 + 1];
#pragma unroll
    for (int c = 0; c < cNCLS; ++c) {
      u32 w2 = *(const u32*)(hwb + (size_t)c * (cNP * cDIM) + i0);
      acc[c] += xn0 * bfu2f((u16)(w2 & 0xffffu)) + xn1 * bfu2f((u16)(w2 >> 16));
    }
  }

  __shared__ float sred[cNCLS * 257];
#pragma unroll
  for (int c = 0; c < cNCLS; ++c) sred[c * 257 + tid] = acc[c];
  __syncthreads();
  if (tid < cNCLS * 8) {
    const int c = tid >> 3, p = tid & 7;
    float s = 0.f;
#pragma unroll
    for (int i = 0; i < 32; ++i) s += sred[c * 257 + p * 32 + i];
    s += __shfl_xor(s, 1, 64);
    s += __shfl_xor(s, 2, 64);
    s += __shfl_xor(s, 4, 64);
    if (p == 0) hpart[(size_t)(b * 16 + chunk) * cNCLS + c] = s;
  }
}

// K8b: head stage 2
__global__ __launch_bounds__(64) void k_head2(
    const float* __restrict__ hpart, const float* __restrict__ hbias,
    float* __restrict__ out)
{
  const int b = blockIdx.x;
  const int c = threadIdx.x;
  if (c < cNCLS) {
    float s = 0.f;
#pragma unroll
    for (int k = 0; k < 16; ++k)
      s += hpart[(size_t)(b * 16 + k) * cNCLS + c];
    out[b * cNCLS + c] = s + hbias[c];
  }
}

// ---------------------------------------------------------------------------
extern "C" void kernel_launch(void* const* d_in, const int* in_sizes, int n_in,
                              void* d_out, int out_size, void* d_ws, size_t ws_size,
                              hipStream_t stream)
{
  (void)in_sizes; (void)n_in; (void)out_size; (void)ws_size;

  const float* series    = (const float*)d_in[0];
  const float* seg_w     = (const float*)d_in[1];
  const float* seg_b     = (const float*)d_in[2];
  const float* ln_g      = (const float*)d_in[3];
  const float* ln_b      = (const float*)d_in[4];
  const float* in_proj_w = (const float*)d_in[5];
  const float* conv_w    = (const float*)d_in[6];
  const float* conv_b    = (const float*)d_in[7];
  const float* x_proj_w  = (const float*)d_in[8];
  const float* dt_proj_w = (const float*)d_in[9];
  const float* dt_proj_b = (const float*)d_in[10];
  const float* A_log     = (const float*)d_in[11];
  const float* Dp        = (const float*)d_in[12];
  const float* out_proj_w= (const float*)d_in[13];
  const float* head_ln_g = (const float*)d_in[14];
  const float* head_ln_b = (const float*)d_in[15];
  const float* head_w    = (const float*)d_in[16];
  const float* head_b    = (const float*)d_in[17];

  // workspace layout (~90 MB)
  u16*   xz16   = (u16*)d_ws;                          // [8192,2048] bf16 (delta | z)
  float* x0     = (float*)(xz16 + (size_t)cBL * cXZ);  // [8192,512] f32 (xsegf alias)
  float* xsegf  = x0;
  float* stats  = x0 + (size_t)cBL * cDIM;             // [256]
  float* pst    = stats + 256;                         // [2048]
  float* hpart  = pst + 128 * 8 * 2;                   // [65536]
  u16*   x0b    = (u16*)(hpart + 128 * 16 * 32);       // [8192,512]
  u16*   wib    = x0b + (size_t)cBL * cDIM;            // [2,2048,512]
  u16*   wob    = wib + (size_t)2 * (2*cDIN) * cDIM;   // [2,512,1024]
  u16*   wdtb   = wob + (size_t)2 * cDIM * cDIN;       // [2,1024,32]
  u16*   wxb    = wdtb + (size_t)2 * cDIN * cDTR;      // [2,64,1024]
  u16*   wsegT  = wxb + (size_t)2 * 64 * cDIN;         // [64,512,128]
  u16*   ucb16  = wsegT + (size_t)cNP * cDIM * cP;     // [8192,1024]
  u16*   hwb    = ucb16 + (size_t)cBL * cDIN;          // [32,32768]
  // xpart aliases x0b (dead between in_proj read and out_proj write;
  // 8192*512*2B == 4*8192*64*4B == 8.39 MB)
  float* xpart  = (float*)x0b;

  // merged weight conversions (counts in float4 units; total = 4288 * 256)
  k_f2bf_all<<<4288, 256, 0, stream>>>(
      in_proj_w,  wib,  (2 * (2*cDIN) * cDIM) / 4,
      out_proj_w, wob,  (2 * cDIM * cDIN) / 4,
      dt_proj_w,  wdtb, (2 * cDIN * cDTR) / 4,
      x_proj_w,   wxb,  (2 * 64 * cDIN) / 4,
      head_w,     hwb,  (cNCLS * cNP * cDIM) / 4);
  k_segT<<<dim3(cP/32, cDIM/32, cNP), 256, 0, stream>>>(seg_w, wsegT);

  // seg projection (batched MFMA over n) -> xsegf, then (+seg_b) LN -> x0b
  k_gemm_mfma<1,0><<<dim3(1, cDIM/128, cNP), 256, 0, stream>>>(
      series, cNP * cP, wsegT, xsegf, cNP * cDIM, (u16*)nullptr, 0,
      nullptr, cP, (long)cP, (long)cDIM * cP, (long)cDIM,
      nullptr, nullptr, nullptr);
  k_ln<<<cBL / 4, 256, 0, stream>>>(xsegf, seg_b, ln_g, ln_b, x0b);

  for (int dep = 0; dep < 2; ++dep) {
    const u16*   wi  = wib  + (size_t)dep * (2*cDIN) * cDIM;
    const u16*   wo  = wob  + (size_t)dep * cDIM * cDIN;
    const u16*   wdt = wdtb + (size_t)dep * cDIN * cDTR;
    const u16*   wx  = wxb  + (size_t)dep * 64 * cDIN;
    const float* cwd = conv_w     + (size_t)dep * cDIN * 4;
    const float* cbd = conv_b     + (size_t)dep * cDIN;
    const float* bdt = dt_proj_b  + (size_t)dep * cDIN;
    const float* Ald = A_log      + (size_t)dep * cDIN * cDST;
    const float* Dd  = Dp         + (size_t)dep * cDIN;

    // in_proj + fused conv/SiLU: u-tiles -> ucb16, z-tiles -> xz16
    k_gemm_mfma<0,2><<<dim3(cBL/128, (2*cDIN)/128), 256, 0, stream>>>(
        x0b, cDIM, wi, (float*)nullptr, 0, xz16, cXZ, nullptr, cDIM, 0, 0, 0,
        cwd, cbd, ucb16);
    // x_proj split-K: xpart = uc @ wx^T (4 K-chunks)
    k_xproj<<<dim3(cBL / 128, 4), 128, 0, stream>>>(ucb16, wx, xpart);
    // dt_proj + softplus (sums xpart partials in staging) -> delta into xz16
    k_gemm_mfma<2,1><<<dim3(cBL/128, cDIN/128), 256, 0, stream>>>(
        xpart, 64, wdt, (float*)nullptr, 0, xz16, cXZ, bdt, cDTR,
        cPSTR, 0, 0, nullptr, nullptr, nullptr);
    // scan + gate (B/C summed from xpart at staging) -> y bf16 into ucb16
    k_scan<<<dim3(cB, 4), 256, 0, stream>>>(xz16, ucb16, xpart, Ald, Dd);
    // out_proj: (dep0: bf16 x0b) (dep1: fp32 x0) = y @ wo^T
    k_gemm_mfma<0,0><<<dim3(cBL/128, cDIM/128), 256, 0, stream>>>(
        ucb16, cDIN, wo,
        dep ? x0 : (float*)nullptr, cDIM,
        dep ? (u16*)nullptr : x0b, cDIM,
        nullptr, cDIN, 0, 0, 0,
        nullptr, nullptr, nullptr);
  }

  k_hstats1<<<dim3(cB, 8), 256, 0, stream>>>(x0, pst);
  k_hstats2<<<1, 128, 0, stream>>>(pst, stats);
  k_head1<<<dim3(cB, 16), 256, 0, stream>>>(x0, stats, head_ln_g, head_ln_b,
                                            hwb, hpart);
  k_head2<<<cB, 64, 0, stream>>>(hpart, head_b, (float*)d_out);
}